// Round 1
// baseline (7074.892 us; speedup 1.0000x reference)
//
#include <hip/hip_runtime.h>
#include <math.h>

// ---- problem constants ----
static constexpr int cB   = 2;
static constexpr int cL   = 1024;
static constexpr int cLE  = 1024;
static constexpr int cNM  = 80;
static constexpr int cDM  = 512;
static constexpr int cLAYERS = 4;
static constexpr int cDS  = 16;
static constexpr int cKC  = 4;     // conv taps
static constexpr int cH   = 4;     // heads
static constexpr int cDI  = 1024;  // EXP*DM
static constexpr int cDTR = 32;
static constexpr int cHD  = 128;   // head dim

// =====================================================================
// Generic tiled GEMM:  C = act( A @ op(W) + bias ) + addv
//   TRANSB=true :  C[m,n] = sum_k A[m,k] * W[n,k]   (W row-major N x K)
//   TRANSB=false:  C[m,n] = sum_k A[m,k] * W[k,n]   (W row-major K x N)
//   ACT: 0=none, 1=softplus
// Batched via blockIdx.z: i1 = z/bdiv, i2 = z%bdiv; base += i1*s?1 + i2*s?2
// =====================================================================
template<bool TRANSB, int ACT>
__launch_bounds__(256)
__global__ void gemm_kernel(const float* __restrict__ A, const float* __restrict__ W,
                            const float* __restrict__ bias, const float* __restrict__ addv,
                            float* __restrict__ C,
                            int M, int N, int Kd, int lda, int ldw, int ldc, int ldadd,
                            int bdiv, long sA1, long sA2, long sW1, long sW2, long sC1, long sC2)
{
    int z = blockIdx.z;
    int i1 = z / bdiv, i2 = z % bdiv;
    A += i1 * sA1 + i2 * sA2;
    W += i1 * sW1 + i2 * sW2;
    C += i1 * sC1 + i2 * sC2;
    if (addv) addv += i1 * sC1 + i2 * sC2;

    const int bm = blockIdx.y * 64;
    const int bn = blockIdx.x * 64;
    const int tx = threadIdx.x, ty = threadIdx.y;   // 16 x 16
    const int tid = ty * 16 + tx;

    __shared__ float As[16][65];
    __shared__ float Ws[16][65];

    float acc[4][4] = {};

    for (int k0 = 0; k0 < Kd; k0 += 16) {
        // load A tile (64 rows x 16 k)
        {
            const int kk = tid & 15, r0 = tid >> 4;
#pragma unroll
            for (int i = 0; i < 4; i++) {
                const int r = r0 + i * 16;
                const int gm = bm + r, gk = k0 + kk;
                float v = 0.f;
                if (gm < M && gk < Kd) v = A[(long)gm * lda + gk];
                As[kk][r] = v;
            }
        }
        // load W tile (64 cols x 16 k)
        if (TRANSB) {
            const int kk = tid & 15, r0 = tid >> 4;
#pragma unroll
            for (int i = 0; i < 4; i++) {
                const int c = r0 + i * 16;
                const int gn = bn + c, gk = k0 + kk;
                float v = 0.f;
                if (gn < N && gk < Kd) v = W[(long)gn * ldw + gk];
                Ws[kk][c] = v;
            }
        } else {
            const int c = tid & 63, k4 = tid >> 6;
#pragma unroll
            for (int i = 0; i < 4; i++) {
                const int kk = k4 + i * 4;
                const int gn = bn + c, gk = k0 + kk;
                float v = 0.f;
                if (gn < N && gk < Kd) v = W[(long)gk * ldw + gn];
                Ws[kk][c] = v;
            }
        }
        __syncthreads();
#pragma unroll
        for (int kk = 0; kk < 16; kk++) {
            float a[4], bv[4];
#pragma unroll
            for (int i = 0; i < 4; i++) a[i] = As[kk][ty + i * 16];
#pragma unroll
            for (int j = 0; j < 4; j++) bv[j] = Ws[kk][tx + j * 16];
#pragma unroll
            for (int i = 0; i < 4; i++)
#pragma unroll
                for (int j = 0; j < 4; j++)
                    acc[i][j] += a[i] * bv[j];
        }
        __syncthreads();
    }

#pragma unroll
    for (int i = 0; i < 4; i++) {
        const int gm = bm + ty + i * 16;
        if (gm >= M) continue;
#pragma unroll
        for (int j = 0; j < 4; j++) {
            const int gn = bn + tx + j * 16;
            if (gn >= N) continue;
            float v = acc[i][j];
            if (bias) v += bias[gn];
            if (ACT == 1) v = (v > 20.f) ? v : log1pf(__expf(v));
            if (addv) v += addv[(long)gm * ldadd + gn];
            C[(long)gm * ldc + gn] = v;
        }
    }
}

// =====================================================================
// RMSNorm per row of Dm elements
// =====================================================================
__global__ void rmsnorm_kernel(const float* __restrict__ x, const float* __restrict__ w,
                               float* __restrict__ out, int Dm)
{
    const int row = blockIdx.x;
    const float* xr = x + (long)row * Dm;
    float s = 0.f;
    for (int i = threadIdx.x; i < Dm; i += 256) { float v = xr[i]; s += v * v; }
    __shared__ float red[5];
    const int lane = threadIdx.x & 63, wv = threadIdx.x >> 6;
#pragma unroll
    for (int off = 1; off < 64; off <<= 1) s += __shfl_xor(s, off);
    if (lane == 0) red[wv] = s;
    __syncthreads();
    if (threadIdx.x == 0) {
        float t = red[0] + red[1] + red[2] + red[3];
        red[4] = rsqrtf(t / Dm + 1e-5f);
    }
    __syncthreads();
    const float scale = red[4];
    for (int i = threadIdx.x; i < Dm; i += 256)
        out[(long)row * Dm + i] = xr[i] * scale * w[i];
}

// =====================================================================
// LayerNorm per row of Dm elements (with w, b)
// =====================================================================
__global__ void layernorm_kernel(const float* __restrict__ x, const float* __restrict__ w,
                                 const float* __restrict__ b, float* __restrict__ out, int Dm)
{
    const int row = blockIdx.x;
    const float* xr = x + (long)row * Dm;
    float s = 0.f, sq = 0.f;
    for (int i = threadIdx.x; i < Dm; i += 256) { float v = xr[i]; s += v; sq += v * v; }
    __shared__ float red[8];
    __shared__ float mv[2];
    const int lane = threadIdx.x & 63, wv = threadIdx.x >> 6;
#pragma unroll
    for (int off = 1; off < 64; off <<= 1) { s += __shfl_xor(s, off); sq += __shfl_xor(sq, off); }
    if (lane == 0) { red[wv] = s; red[4 + wv] = sq; }
    __syncthreads();
    if (threadIdx.x == 0) {
        float ts = red[0] + red[1] + red[2] + red[3];
        float tq = red[4] + red[5] + red[6] + red[7];
        float m = ts / Dm;
        float var = tq / Dm - m * m;
        mv[0] = m;
        mv[1] = rsqrtf(var + 1e-5f);
    }
    __syncthreads();
    const float m = mv[0], rs = mv[1];
    for (int i = threadIdx.x; i < Dm; i += 256)
        out[(long)row * Dm + i] = (xr[i] - m) * rs * w[i] + b[i];
}

// =====================================================================
// Causal depthwise conv (K=4) + bias + SiLU.  xm source = xr[..., 0:DI],
// row stride 2*DI.  Output xm (B,L,DI).
// =====================================================================
__global__ void conv_silu_kernel(const float* __restrict__ xr, const float* __restrict__ w,
                                 const float* __restrict__ bias, float* __restrict__ xm)
{
    const int idx = blockIdx.x * 256 + threadIdx.x;
    if (idx >= cB * cL * cDI) return;
    const int d = idx & (cDI - 1);
    const int l = (idx >> 10) & (cL - 1);
    const int b = idx >> 20;
    float s = bias[d];
#pragma unroll
    for (int j = 0; j < cKC; j++) {
        const int ls = l + j - (cKC - 1);
        if (ls >= 0) s += w[d * cKC + j] * xr[((long)(b * cL + ls)) * (2 * cDI) + d];
    }
    xm[(long)idx] = s / (1.f + __expf(-s));   // silu
}

// =====================================================================
// Selective scan.  One thread per (b, d, n).  Linear recurrence:
//   state = exp(delta*A)*state + delta*u*B;  y += state*C
// n reduced over 16 lanes via shfl_xor; epilogue adds u*D and gates by
// silu(res) where res = xr[..., DI + d].
// =====================================================================
__global__ void scan_kernel(const float* __restrict__ xm, const float* __restrict__ delta,
                            const float* __restrict__ xdbl, const float* __restrict__ Alog,
                            const float* __restrict__ Dv, const float* __restrict__ xr,
                            float* __restrict__ y)
{
    const int idx = blockIdx.x * 256 + threadIdx.x;   // cB*cDI*cDS total
    const int n = idx & (cDS - 1);
    const int d = (idx >> 4) & (cDI - 1);
    const int b = idx >> 14;
    const float A = -__expf(Alog[d * cDS + n]);
    const float Dval = Dv[d];
    float state = 0.f;
    for (int l = 0; l < cL; l++) {
        const long base = (long)(b * cL + l);
        const float dl = delta[base * cDI + d];
        const float u  = xm[base * cDI + d];
        const float Bv = xdbl[base * 64 + cDTR + n];
        const float Cv = xdbl[base * 64 + cDTR + cDS + n];
        state = __expf(dl * A) * state + dl * u * Bv;
        float contrib = state * Cv;
        contrib += __shfl_xor(contrib, 1);
        contrib += __shfl_xor(contrib, 2);
        contrib += __shfl_xor(contrib, 4);
        contrib += __shfl_xor(contrib, 8);
        if (n == 0) {
            const float res = xr[base * (2 * cDI) + cDI + d];
            const float sig = 1.f / (1.f + __expf(-res));
            y[base * cDI + d] = (contrib + u * Dval) * (res * sig);
        }
    }
}

// =====================================================================
// Row softmax with scale (rows of `cols` elements), in-place
// =====================================================================
__global__ void softmax_kernel(float* __restrict__ s, int cols, float scale)
{
    const long row = blockIdx.x;
    float* p = s + row * cols;
    float vals[4];
    float mx = -1e30f;
    int cnt = 0;
    for (int i = threadIdx.x; i < cols; i += 256, cnt++) {
        vals[cnt] = p[i] * scale;
        mx = fmaxf(mx, vals[cnt]);
    }
    __shared__ float red[5];
    const int lane = threadIdx.x & 63, wv = threadIdx.x >> 6;
#pragma unroll
    for (int off = 1; off < 64; off <<= 1) mx = fmaxf(mx, __shfl_xor(mx, off));
    if (lane == 0) red[wv] = mx;
    __syncthreads();
    if (threadIdx.x == 0) red[4] = fmaxf(fmaxf(red[0], red[1]), fmaxf(red[2], red[3]));
    __syncthreads();
    mx = red[4];
    __syncthreads();
    float sum = 0.f;
    for (int c = 0; c < cnt; c++) { vals[c] = __expf(vals[c] - mx); sum += vals[c]; }
#pragma unroll
    for (int off = 1; off < 64; off <<= 1) sum += __shfl_xor(sum, off);
    if (lane == 0) red[wv] = sum;
    __syncthreads();
    if (threadIdx.x == 0) red[4] = red[0] + red[1] + red[2] + red[3];
    __syncthreads();
    const float inv = 1.f / red[4];
    cnt = 0;
    for (int i = threadIdx.x; i < cols; i += 256, cnt++) p[i] = vals[cnt] * inv;
}

// =====================================================================
// host-side launch helpers
// =====================================================================
static inline void gemm_tn(const float* A, const float* W, const float* bias, const float* addv,
                           float* C, int M, int N, int Kd, int lda, int ldw, int ldc, int ldadd,
                           hipStream_t s)
{
    dim3 g((N + 63) / 64, (M + 63) / 64, 1), b(16, 16);
    gemm_kernel<true, 0><<<g, b, 0, s>>>(A, W, bias, addv, C, M, N, Kd, lda, ldw, ldc, ldadd,
                                         1, 0, 0, 0, 0, 0, 0);
}
static inline void gemm_tn_softplus(const float* A, const float* W, const float* bias,
                                    float* C, int M, int N, int Kd, int lda, int ldw, int ldc,
                                    hipStream_t s)
{
    dim3 g((N + 63) / 64, (M + 63) / 64, 1), b(16, 16);
    gemm_kernel<true, 1><<<g, b, 0, s>>>(A, W, bias, nullptr, C, M, N, Kd, lda, ldw, ldc, 0,
                                         1, 0, 0, 0, 0, 0, 0);
}

extern "C" void kernel_launch(void* const* d_in, const int* in_sizes, int n_in,
                              void* d_out, int out_size, void* d_ws, size_t ws_size,
                              hipStream_t stream)
{
    const float* x       = (const float*)d_in[0];
    const float* enc     = (const float*)d_in[1];
    const float* W_in    = (const float*)d_in[2];
    const float* b_in    = (const float*)d_in[3];
    const float* m_norm_w= (const float*)d_in[4];
    const float* m_in_w  = (const float*)d_in[5];
    const float* m_conv_w= (const float*)d_in[6];
    const float* m_conv_b= (const float*)d_in[7];
    const float* m_xproj = (const float*)d_in[8];
    const float* m_dt_w  = (const float*)d_in[9];
    const float* m_dt_b  = (const float*)d_in[10];
    const float* m_Alog  = (const float*)d_in[11];
    const float* m_D     = (const float*)d_in[12];
    const float* m_out_w = (const float*)d_in[13];
    const float* a_in_w  = (const float*)d_in[14];
    const float* a_in_b  = (const float*)d_in[15];
    const float* a_out_w = (const float*)d_in[16];
    const float* a_out_b = (const float*)d_in[17];
    const float* a_ln_w  = (const float*)d_in[18];
    const float* a_ln_b  = (const float*)d_in[19];
    const float* normf_w = (const float*)d_in[20];
    const float* W_out   = (const float*)d_in[21];
    float* out = (float*)d_out;

    float* ws = (float*)d_ws;
    const long M1 = 1024 * 1024;
    float* bufH    = ws;                 // 1M
    float* bufU    = ws + 1 * M1;        // 1M
    float* bufXR   = ws + 2 * M1;        // 4M
    float* bufXM   = ws + 6 * M1;        // 2M
    float* bufXDBL = ws + 8 * M1;        // 0.25M reserved
    float* bufDelta= ws + 8 * M1 + M1 / 4;  // 2M
    float* bufY    = ws + 10 * M1 + M1 / 4; // 2M
    float* bufQ    = ws + 12 * M1 + M1 / 4; // 1M
    float* bufK    = ws + 13 * M1 + M1 / 4; // 1M
    float* bufV    = ws + 14 * M1 + M1 / 4; // 1M
    float* bufO    = ws + 15 * M1 + M1 / 4; // 1M
    float* bufPre  = ws + 16 * M1 + M1 / 4; // 1M
    float* bufS    = ws + 2 * M1;        // 8M, overlays XR..Delta (free by attn time)

    const int Mrows = cB * cL;   // 2048

    // h = x @ W_in.T + b_in
    gemm_tn(x, W_in, b_in, nullptr, bufH, Mrows, cDM, cNM, cNM, cNM, cDM, 0, stream);

    for (int i = 0; i < cLAYERS; i++) {
        const float* norm_w = m_norm_w + (long)i * cDM;
        const float* in_w   = m_in_w   + (long)i * 2 * cDI * cDM;
        const float* conv_w = m_conv_w + (long)i * cDI * cKC;
        const float* conv_b = m_conv_b + (long)i * cDI;
        const float* xproj  = m_xproj  + (long)i * (cDTR + 2 * cDS) * cDI;
        const float* dt_w   = m_dt_w   + (long)i * cDI * cDTR;
        const float* dt_b   = m_dt_b   + (long)i * cDI;
        const float* Alog   = m_Alog   + (long)i * cDI * cDS;
        const float* Dv     = m_D      + (long)i * cDI;
        const float* out_w  = m_out_w  + (long)i * cDM * cDI;
        const float* ain_w  = a_in_w   + (long)i * 3 * cDM * cDM;
        const float* ain_b  = a_in_b   + (long)i * 3 * cDM;
        const float* aout_w = a_out_w  + (long)i * cDM * cDM;
        const float* aout_b = a_out_b  + (long)i * cDM;
        const float* ln_w   = a_ln_w   + (long)i * cDM;
        const float* ln_b   = a_ln_b   + (long)i * cDM;

        // ---- mamba block ----
        rmsnorm_kernel<<<Mrows, 256, 0, stream>>>(bufH, norm_w, bufU, cDM);
        // xr = u @ in_w.T   (M x 2048)
        gemm_tn(bufU, in_w, nullptr, nullptr, bufXR, Mrows, 2 * cDI, cDM, cDM, cDM, 2 * cDI, 0, stream);
        // conv + silu -> xm
        conv_silu_kernel<<<(cB * cL * cDI + 255) / 256, 256, 0, stream>>>(bufXR, conv_w, conv_b, bufXM);
        // x_dbl = xm @ xproj.T  (M x 64)
        gemm_tn(bufXM, xproj, nullptr, nullptr, bufXDBL, Mrows, cDTR + 2 * cDS, cDI, cDI, cDI, 64, 0, stream);
        // delta = softplus(dlt @ dt_w.T + dt_b)  (M x DI)
        gemm_tn_softplus(bufXDBL, dt_w, dt_b, bufDelta, Mrows, cDI, cDTR, 64, cDTR, cDI, stream);
        // scan -> y (gated)
        scan_kernel<<<(cB * cDI * cDS) / 256, 256, 0, stream>>>(bufXM, bufDelta, bufXDBL, Alog, Dv, bufXR, bufY);
        // h += y @ out_w.T
        gemm_tn(bufY, out_w, nullptr, bufH, bufH, Mrows, cDM, cDI, cDI, cDI, cDM, cDM, stream);

        // ---- cross attention ----
        gemm_tn(bufH, ain_w, ain_b, nullptr, bufQ, Mrows, cDM, cDM, cDM, cDM, cDM, 0, stream);
        gemm_tn(enc, ain_w + (long)cDM * cDM, ain_b + cDM, nullptr, bufK, cB * cLE, cDM, cDM, cDM, cDM, cDM, 0, stream);
        gemm_tn(enc, ain_w + 2L * cDM * cDM, ain_b + 2 * cDM, nullptr, bufV, cB * cLE, cDM, cDM, cDM, cDM, cDM, 0, stream);

        // scores[b,h] = q[b,:,h*HD:] @ k[b,:,h*HD:].T
        {
            dim3 g(cLE / 64, cL / 64, cB * cH), b(16, 16);
            gemm_kernel<true, 0><<<g, b, 0, stream>>>(
                bufQ, bufK, nullptr, nullptr, bufS,
                cL, cLE, cHD, cDM, cDM, cLE, 0,
                cH,
                (long)cL * cDM, (long)cHD,
                (long)cLE * cDM, (long)cHD,
                (long)cH * cL * cLE, (long)cL * cLE);
        }
        softmax_kernel<<<cB * cH * cL, 256, 0, stream>>>(bufS, cLE, 0.08838834764831845f);
        // o[b,:,h*HD:] = attn @ v[b,:,h*HD:]
        {
            dim3 g(cHD / 64, cL / 64, cB * cH), b(16, 16);
            gemm_kernel<false, 0><<<g, b, 0, stream>>>(
                bufS, bufV, nullptr, nullptr, bufO,
                cL, cHD, cLE, cLE, cDM, cDM, 0,
                cH,
                (long)cH * cL * cLE, (long)cL * cLE,
                (long)cLE * cDM, (long)cHD,
                (long)cL * cDM, (long)cHD);
        }
        // pre = o @ aout_w.T + aout_b + h ; h = LN(pre)
        gemm_tn(bufO, aout_w, aout_b, bufH, bufPre, Mrows, cDM, cDM, cDM, cDM, cDM, cDM, stream);
        layernorm_kernel<<<Mrows, 256, 0, stream>>>(bufPre, ln_w, ln_b, bufH, cDM);
    }

    // final: out = rmsnorm(h, normf_w) @ W_out.T
    rmsnorm_kernel<<<Mrows, 256, 0, stream>>>(bufH, normf_w, bufU, cDM);
    gemm_tn(bufU, W_out, nullptr, nullptr, out, Mrows, cNM, cDM, cDM, cDM, cNM, 0, stream);
}

// Round 2
// 4337.930 us; speedup vs baseline: 1.6309x; 1.6309x over previous
//
#include <hip/hip_runtime.h>
#include <math.h>

// ---- problem constants ----
static constexpr int cB   = 2;
static constexpr int cL   = 1024;
static constexpr int cLE  = 1024;
static constexpr int cNM  = 80;
static constexpr int cDM  = 512;
static constexpr int cLAYERS = 4;
static constexpr int cDS  = 16;
static constexpr int cKC  = 4;     // conv taps
static constexpr int cH   = 4;     // heads
static constexpr int cDI  = 1024;  // EXP*DM
static constexpr int cDTR = 32;
static constexpr int cHD  = 128;   // head dim

static constexpr int cNCH = 16;    // scan chunks
static constexpr int cCHL = cL / cNCH;  // 64 steps per chunk

// =====================================================================
// Generic tiled GEMM:  C = act( A @ op(W) + bias ) + addv
//   TRANSB=true :  C[m,n] = sum_k A[m,k] * W[n,k]   (W row-major N x K)
//   TRANSB=false:  C[m,n] = sum_k A[m,k] * W[k,n]   (W row-major K x N)
//   ACT: 0=none, 1=softplus
// Batched via blockIdx.z: i1 = z/bdiv, i2 = z%bdiv; base += i1*s?1 + i2*s?2
// =====================================================================
template<bool TRANSB, int ACT>
__launch_bounds__(256)
__global__ void gemm_kernel(const float* __restrict__ A, const float* __restrict__ W,
                            const float* __restrict__ bias, const float* __restrict__ addv,
                            float* __restrict__ C,
                            int M, int N, int Kd, int lda, int ldw, int ldc, int ldadd,
                            int bdiv, long sA1, long sA2, long sW1, long sW2, long sC1, long sC2)
{
    int z = blockIdx.z;
    int i1 = z / bdiv, i2 = z % bdiv;
    A += i1 * sA1 + i2 * sA2;
    W += i1 * sW1 + i2 * sW2;
    C += i1 * sC1 + i2 * sC2;
    if (addv) addv += i1 * sC1 + i2 * sC2;

    const int bm = blockIdx.y * 64;
    const int bn = blockIdx.x * 64;
    const int tx = threadIdx.x, ty = threadIdx.y;   // 16 x 16
    const int tid = ty * 16 + tx;

    __shared__ float As[16][65];
    __shared__ float Ws[16][65];

    float acc[4][4] = {};

    for (int k0 = 0; k0 < Kd; k0 += 16) {
        // load A tile (64 rows x 16 k)
        {
            const int kk = tid & 15, r0 = tid >> 4;
#pragma unroll
            for (int i = 0; i < 4; i++) {
                const int r = r0 + i * 16;
                const int gm = bm + r, gk = k0 + kk;
                float v = 0.f;
                if (gm < M && gk < Kd) v = A[(long)gm * lda + gk];
                As[kk][r] = v;
            }
        }
        // load W tile (64 cols x 16 k)
        if (TRANSB) {
            const int kk = tid & 15, r0 = tid >> 4;
#pragma unroll
            for (int i = 0; i < 4; i++) {
                const int c = r0 + i * 16;
                const int gn = bn + c, gk = k0 + kk;
                float v = 0.f;
                if (gn < N && gk < Kd) v = W[(long)gn * ldw + gk];
                Ws[kk][c] = v;
            }
        } else {
            const int c = tid & 63, k4 = tid >> 6;
#pragma unroll
            for (int i = 0; i < 4; i++) {
                const int kk = k4 + i * 4;
                const int gn = bn + c, gk = k0 + kk;
                float v = 0.f;
                if (gn < N && gk < Kd) v = W[(long)gk * ldw + gn];
                Ws[kk][c] = v;
            }
        }
        __syncthreads();
#pragma unroll
        for (int kk = 0; kk < 16; kk++) {
            float a[4], bv[4];
#pragma unroll
            for (int i = 0; i < 4; i++) a[i] = As[kk][ty + i * 16];
#pragma unroll
            for (int j = 0; j < 4; j++) bv[j] = Ws[kk][tx + j * 16];
#pragma unroll
            for (int i = 0; i < 4; i++)
#pragma unroll
                for (int j = 0; j < 4; j++)
                    acc[i][j] += a[i] * bv[j];
        }
        __syncthreads();
    }

#pragma unroll
    for (int i = 0; i < 4; i++) {
        const int gm = bm + ty + i * 16;
        if (gm >= M) continue;
#pragma unroll
        for (int j = 0; j < 4; j++) {
            const int gn = bn + tx + j * 16;
            if (gn >= N) continue;
            float v = acc[i][j];
            if (bias) v += bias[gn];
            if (ACT == 1) v = (v > 20.f) ? v : log1pf(__expf(v));
            if (addv) v += addv[(long)gm * ldadd + gn];
            C[(long)gm * ldc + gn] = v;
        }
    }
}

// =====================================================================
// RMSNorm per row of Dm elements
// =====================================================================
__global__ void rmsnorm_kernel(const float* __restrict__ x, const float* __restrict__ w,
                               float* __restrict__ out, int Dm)
{
    const int row = blockIdx.x;
    const float* xr = x + (long)row * Dm;
    float s = 0.f;
    for (int i = threadIdx.x; i < Dm; i += 256) { float v = xr[i]; s += v * v; }
    __shared__ float red[5];
    const int lane = threadIdx.x & 63, wv = threadIdx.x >> 6;
#pragma unroll
    for (int off = 1; off < 64; off <<= 1) s += __shfl_xor(s, off);
    if (lane == 0) red[wv] = s;
    __syncthreads();
    if (threadIdx.x == 0) {
        float t = red[0] + red[1] + red[2] + red[3];
        red[4] = rsqrtf(t / Dm + 1e-5f);
    }
    __syncthreads();
    const float scale = red[4];
    for (int i = threadIdx.x; i < Dm; i += 256)
        out[(long)row * Dm + i] = xr[i] * scale * w[i];
}

// =====================================================================
// LayerNorm per row of Dm elements (with w, b)
// =====================================================================
__global__ void layernorm_kernel(const float* __restrict__ x, const float* __restrict__ w,
                                 const float* __restrict__ b, float* __restrict__ out, int Dm)
{
    const int row = blockIdx.x;
    const float* xr = x + (long)row * Dm;
    float s = 0.f, sq = 0.f;
    for (int i = threadIdx.x; i < Dm; i += 256) { float v = xr[i]; s += v; sq += v * v; }
    __shared__ float red[8];
    __shared__ float mv[2];
    const int lane = threadIdx.x & 63, wv = threadIdx.x >> 6;
#pragma unroll
    for (int off = 1; off < 64; off <<= 1) { s += __shfl_xor(s, off); sq += __shfl_xor(sq, off); }
    if (lane == 0) { red[wv] = s; red[4 + wv] = sq; }
    __syncthreads();
    if (threadIdx.x == 0) {
        float ts = red[0] + red[1] + red[2] + red[3];
        float tq = red[4] + red[5] + red[6] + red[7];
        float m = ts / Dm;
        float var = tq / Dm - m * m;
        mv[0] = m;
        mv[1] = rsqrtf(var + 1e-5f);
    }
    __syncthreads();
    const float m = mv[0], rs = mv[1];
    for (int i = threadIdx.x; i < Dm; i += 256)
        out[(long)row * Dm + i] = (xr[i] - m) * rs * w[i] + b[i];
}

// =====================================================================
// Causal depthwise conv (K=4) + bias + SiLU.  xm source = xr[..., 0:DI],
// row stride 2*DI.  Output xm (B,L,DI).
// =====================================================================
__global__ void conv_silu_kernel(const float* __restrict__ xr, const float* __restrict__ w,
                                 const float* __restrict__ bias, float* __restrict__ xm)
{
    const int idx = blockIdx.x * 256 + threadIdx.x;
    if (idx >= cB * cL * cDI) return;
    const int d = idx & (cDI - 1);
    const int l = (idx >> 10) & (cL - 1);
    const int b = idx >> 20;
    float s = bias[d];
#pragma unroll
    for (int j = 0; j < cKC; j++) {
        const int ls = l + j - (cKC - 1);
        if (ls >= 0) s += w[d * cKC + j] * xr[((long)(b * cL + ls)) * (2 * cDI) + d];
    }
    xm[(long)idx] = s / (1.f + __expf(-s));   // silu
}

// =====================================================================
// Chunk-parallel selective scan.
// Recurrence per (b,d,n):  state = exp(delta*A)*state + delta*u*B;  y = <state,C>
// Split L into cNCH chunks of cCHL.
//  phase1: per (b,chunk,d,n) local scan from 0 -> send, plus decay prod -> aprod
//  phase2: per (b,d,n) sequential combine over chunks -> sinit per chunk
//  phase3: per (b,chunk,d,n) re-run recurrence from sinit, reduce over n,
//          epilogue u*D + silu(res) gating
// idx layout: (((b*cNCH + ch)*cDI + d)*cDS + n)
// =====================================================================
__global__ void scan_phase1(const float* __restrict__ xm, const float* __restrict__ delta,
                            const float* __restrict__ xdbl, const float* __restrict__ Alog,
                            float* __restrict__ aprod_out, float* __restrict__ send_out)
{
    const int idx = blockIdx.x * 256 + threadIdx.x;   // cB*cNCH*cDI*cDS
    const int n  = idx & (cDS - 1);
    const int d  = (idx >> 4) & (cDI - 1);
    const int ch = (idx >> 14) & (cNCH - 1);
    const int b  = idx >> 18;
    const float A = -__expf(Alog[d * cDS + n]);
    float state = 0.f, aprod = 1.f;
    const int l0 = ch * cCHL;
    for (int t = 0; t < cCHL; t++) {
        const long base = (long)(b * cL + l0 + t);
        const float dl = delta[base * cDI + d];
        const float u  = xm[base * cDI + d];
        const float Bv = xdbl[base * 64 + cDTR + n];
        const float a  = __expf(dl * A);
        state = a * state + dl * u * Bv;
        aprod *= a;
    }
    aprod_out[idx] = aprod;
    send_out[idx]  = state;
}

__global__ void scan_phase2(const float* __restrict__ aprod, const float* __restrict__ send,
                            float* __restrict__ sinit)
{
    const int j = blockIdx.x * 256 + threadIdx.x;   // cB*cDI*cDS
    const int n = j & (cDS - 1);
    const int d = (j >> 4) & (cDI - 1);
    const int b = j >> 14;
    float s = 0.f;
#pragma unroll
    for (int c = 0; c < cNCH; c++) {
        const long off = (((long)(b * cNCH + c) * cDI + d) * cDS) + n;
        sinit[off] = s;
        s = aprod[off] * s + send[off];
    }
}

__global__ void scan_phase3(const float* __restrict__ xm, const float* __restrict__ delta,
                            const float* __restrict__ xdbl, const float* __restrict__ Alog,
                            const float* __restrict__ Dv, const float* __restrict__ xr,
                            const float* __restrict__ sinit, float* __restrict__ y)
{
    const int idx = blockIdx.x * 256 + threadIdx.x;   // cB*cNCH*cDI*cDS
    const int n  = idx & (cDS - 1);
    const int d  = (idx >> 4) & (cDI - 1);
    const int ch = (idx >> 14) & (cNCH - 1);
    const int b  = idx >> 18;
    const float A = -__expf(Alog[d * cDS + n]);
    const float Dval = Dv[d];
    float state = sinit[idx];
    const int l0 = ch * cCHL;
    for (int t = 0; t < cCHL; t++) {
        const long base = (long)(b * cL + l0 + t);
        const float dl = delta[base * cDI + d];
        const float u  = xm[base * cDI + d];
        const float Bv = xdbl[base * 64 + cDTR + n];
        const float Cv = xdbl[base * 64 + cDTR + cDS + n];
        state = __expf(dl * A) * state + dl * u * Bv;
        float contrib = state * Cv;
        contrib += __shfl_xor(contrib, 1);
        contrib += __shfl_xor(contrib, 2);
        contrib += __shfl_xor(contrib, 4);
        contrib += __shfl_xor(contrib, 8);
        if (n == 0) {
            const float res = xr[base * (2 * cDI) + cDI + d];
            const float sig = 1.f / (1.f + __expf(-res));
            y[base * cDI + d] = (contrib + u * Dval) * (res * sig);
        }
    }
}

// =====================================================================
// Row softmax with scale (rows of `cols` elements), in-place
// =====================================================================
__global__ void softmax_kernel(float* __restrict__ s, int cols, float scale)
{
    const long row = blockIdx.x;
    float* p = s + row * cols;
    float vals[4];
    float mx = -1e30f;
    int cnt = 0;
    for (int i = threadIdx.x; i < cols; i += 256, cnt++) {
        vals[cnt] = p[i] * scale;
        mx = fmaxf(mx, vals[cnt]);
    }
    __shared__ float red[5];
    const int lane = threadIdx.x & 63, wv = threadIdx.x >> 6;
#pragma unroll
    for (int off = 1; off < 64; off <<= 1) mx = fmaxf(mx, __shfl_xor(mx, off));
    if (lane == 0) red[wv] = mx;
    __syncthreads();
    if (threadIdx.x == 0) red[4] = fmaxf(fmaxf(red[0], red[1]), fmaxf(red[2], red[3]));
    __syncthreads();
    mx = red[4];
    __syncthreads();
    float sum = 0.f;
    for (int c = 0; c < cnt; c++) { vals[c] = __expf(vals[c] - mx); sum += vals[c]; }
#pragma unroll
    for (int off = 1; off < 64; off <<= 1) sum += __shfl_xor(sum, off);
    if (lane == 0) red[wv] = sum;
    __syncthreads();
    if (threadIdx.x == 0) red[4] = red[0] + red[1] + red[2] + red[3];
    __syncthreads();
    const float inv = 1.f / red[4];
    cnt = 0;
    for (int i = threadIdx.x; i < cols; i += 256, cnt++) p[i] = vals[cnt] * inv;
}

// =====================================================================
// host-side launch helpers
// =====================================================================
static inline void gemm_tn(const float* A, const float* W, const float* bias, const float* addv,
                           float* C, int M, int N, int Kd, int lda, int ldw, int ldc, int ldadd,
                           hipStream_t s)
{
    dim3 g((N + 63) / 64, (M + 63) / 64, 1), b(16, 16);
    gemm_kernel<true, 0><<<g, b, 0, s>>>(A, W, bias, addv, C, M, N, Kd, lda, ldw, ldc, ldadd,
                                         1, 0, 0, 0, 0, 0, 0);
}
static inline void gemm_tn_softplus(const float* A, const float* W, const float* bias,
                                    float* C, int M, int N, int Kd, int lda, int ldw, int ldc,
                                    hipStream_t s)
{
    dim3 g((N + 63) / 64, (M + 63) / 64, 1), b(16, 16);
    gemm_kernel<true, 1><<<g, b, 0, s>>>(A, W, bias, nullptr, C, M, N, Kd, lda, ldw, ldc, 0,
                                         1, 0, 0, 0, 0, 0, 0);
}

extern "C" void kernel_launch(void* const* d_in, const int* in_sizes, int n_in,
                              void* d_out, int out_size, void* d_ws, size_t ws_size,
                              hipStream_t stream)
{
    const float* x       = (const float*)d_in[0];
    const float* enc     = (const float*)d_in[1];
    const float* W_in    = (const float*)d_in[2];
    const float* b_in    = (const float*)d_in[3];
    const float* m_norm_w= (const float*)d_in[4];
    const float* m_in_w  = (const float*)d_in[5];
    const float* m_conv_w= (const float*)d_in[6];
    const float* m_conv_b= (const float*)d_in[7];
    const float* m_xproj = (const float*)d_in[8];
    const float* m_dt_w  = (const float*)d_in[9];
    const float* m_dt_b  = (const float*)d_in[10];
    const float* m_Alog  = (const float*)d_in[11];
    const float* m_D     = (const float*)d_in[12];
    const float* m_out_w = (const float*)d_in[13];
    const float* a_in_w  = (const float*)d_in[14];
    const float* a_in_b  = (const float*)d_in[15];
    const float* a_out_w = (const float*)d_in[16];
    const float* a_out_b = (const float*)d_in[17];
    const float* a_ln_w  = (const float*)d_in[18];
    const float* a_ln_b  = (const float*)d_in[19];
    const float* normf_w = (const float*)d_in[20];
    const float* W_out   = (const float*)d_in[21];
    float* out = (float*)d_out;

    float* ws = (float*)d_ws;
    const long M1 = 1024 * 1024;
    float* bufH    = ws;                 // 1M
    float* bufU    = ws + 1 * M1;        // 1M
    float* bufXR   = ws + 2 * M1;        // 4M
    float* bufXM   = ws + 6 * M1;        // 2M
    float* bufXDBL = ws + 8 * M1;        // 0.25M reserved
    float* bufDelta= ws + 8 * M1 + M1 / 4;  // 2M
    float* bufY    = ws + 10 * M1 + M1 / 4; // 2M
    float* bufQ    = ws + 12 * M1 + M1 / 4; // 1M
    float* bufK    = ws + 13 * M1 + M1 / 4; // 1M
    float* bufV    = ws + 14 * M1 + M1 / 4; // 1M
    float* bufO    = ws + 15 * M1 + M1 / 4; // 1M
    float* bufPre  = ws + 16 * M1 + M1 / 4; // 1M
    float* bufS    = ws + 2 * M1;        // 8M, overlays XR..Delta (free by attn time)

    // scan chunk summaries overlay the attention Q/K buffers (dead during mamba)
    const long SUMSZ = (long)cB * cNCH * cDI * cDS;   // 524288 floats
    float* bufAP = bufQ;                // aprod
    float* bufSE = bufQ + SUMSZ;        // chunk-end states
    float* bufSI = bufK;                // chunk-initial states

    const int Mrows = cB * cL;   // 2048

    // h = x @ W_in.T + b_in
    gemm_tn(x, W_in, b_in, nullptr, bufH, Mrows, cDM, cNM, cNM, cNM, cDM, 0, stream);

    for (int i = 0; i < cLAYERS; i++) {
        const float* norm_w = m_norm_w + (long)i * cDM;
        const float* in_w   = m_in_w   + (long)i * 2 * cDI * cDM;
        const float* conv_w = m_conv_w + (long)i * cDI * cKC;
        const float* conv_b = m_conv_b + (long)i * cDI;
        const float* xproj  = m_xproj  + (long)i * (cDTR + 2 * cDS) * cDI;
        const float* dt_w   = m_dt_w   + (long)i * cDI * cDTR;
        const float* dt_b   = m_dt_b   + (long)i * cDI;
        const float* Alog   = m_Alog   + (long)i * cDI * cDS;
        const float* Dv     = m_D      + (long)i * cDI;
        const float* out_w  = m_out_w  + (long)i * cDM * cDI;
        const float* ain_w  = a_in_w   + (long)i * 3 * cDM * cDM;
        const float* ain_b  = a_in_b   + (long)i * 3 * cDM;
        const float* aout_w = a_out_w  + (long)i * cDM * cDM;
        const float* aout_b = a_out_b  + (long)i * cDM;
        const float* ln_w   = a_ln_w   + (long)i * cDM;
        const float* ln_b   = a_ln_b   + (long)i * cDM;

        // ---- mamba block ----
        rmsnorm_kernel<<<Mrows, 256, 0, stream>>>(bufH, norm_w, bufU, cDM);
        // xr = u @ in_w.T   (M x 2048)
        gemm_tn(bufU, in_w, nullptr, nullptr, bufXR, Mrows, 2 * cDI, cDM, cDM, cDM, 2 * cDI, 0, stream);
        // conv + silu -> xm
        conv_silu_kernel<<<(cB * cL * cDI + 255) / 256, 256, 0, stream>>>(bufXR, conv_w, conv_b, bufXM);
        // x_dbl = xm @ xproj.T  (M x 64)
        gemm_tn(bufXM, xproj, nullptr, nullptr, bufXDBL, Mrows, cDTR + 2 * cDS, cDI, cDI, cDI, 64, 0, stream);
        // delta = softplus(dlt @ dt_w.T + dt_b)  (M x DI)
        gemm_tn_softplus(bufXDBL, dt_w, dt_b, bufDelta, Mrows, cDI, cDTR, 64, cDTR, cDI, stream);
        // chunk-parallel scan -> y (gated)
        {
            const int nthr = (int)SUMSZ;   // 524288
            scan_phase1<<<nthr / 256, 256, 0, stream>>>(bufXM, bufDelta, bufXDBL, Alog, bufAP, bufSE);
            scan_phase2<<<(cB * cDI * cDS) / 256, 256, 0, stream>>>(bufAP, bufSE, bufSI);
            scan_phase3<<<nthr / 256, 256, 0, stream>>>(bufXM, bufDelta, bufXDBL, Alog, Dv, bufXR, bufSI, bufY);
        }
        // h += y @ out_w.T
        gemm_tn(bufY, out_w, nullptr, bufH, bufH, Mrows, cDM, cDI, cDI, cDI, cDM, cDM, stream);

        // ---- cross attention ----
        gemm_tn(bufH, ain_w, ain_b, nullptr, bufQ, Mrows, cDM, cDM, cDM, cDM, cDM, 0, stream);
        gemm_tn(enc, ain_w + (long)cDM * cDM, ain_b + cDM, nullptr, bufK, cB * cLE, cDM, cDM, cDM, cDM, cDM, 0, stream);
        gemm_tn(enc, ain_w + 2L * cDM * cDM, ain_b + 2 * cDM, nullptr, bufV, cB * cLE, cDM, cDM, cDM, cDM, cDM, 0, stream);

        // scores[b,h] = q[b,:,h*HD:] @ k[b,:,h*HD:].T
        {
            dim3 g(cLE / 64, cL / 64, cB * cH), b(16, 16);
            gemm_kernel<true, 0><<<g, b, 0, stream>>>(
                bufQ, bufK, nullptr, nullptr, bufS,
                cL, cLE, cHD, cDM, cDM, cLE, 0,
                cH,
                (long)cL * cDM, (long)cHD,
                (long)cLE * cDM, (long)cHD,
                (long)cH * cL * cLE, (long)cL * cLE);
        }
        softmax_kernel<<<cB * cH * cL, 256, 0, stream>>>(bufS, cLE, 0.08838834764831845f);
        // o[b,:,h*HD:] = attn @ v[b,:,h*HD:]
        {
            dim3 g(cHD / 64, cL / 64, cB * cH), b(16, 16);
            gemm_kernel<false, 0><<<g, b, 0, stream>>>(
                bufS, bufV, nullptr, nullptr, bufO,
                cL, cHD, cLE, cLE, cDM, cDM, 0,
                cH,
                (long)cH * cL * cLE, (long)cL * cLE,
                (long)cLE * cDM, (long)cHD,
                (long)cL * cDM, (long)cHD);
        }
        // pre = o @ aout_w.T + aout_b + h ; h = LN(pre)
        gemm_tn(bufO, aout_w, aout_b, bufH, bufPre, Mrows, cDM, cDM, cDM, cDM, cDM, cDM, stream);
        layernorm_kernel<<<Mrows, 256, 0, stream>>>(bufPre, ln_w, ln_b, bufH, cDM);
    }

    // final: out = rmsnorm(h, normf_w) @ W_out.T
    rmsnorm_kernel<<<Mrows, 256, 0, stream>>>(bufH, normf_w, bufU, cDM);
    gemm_tn(bufU, W_out, nullptr, nullptr, out, Mrows, cNM, cDM, cDM, cDM, cNM, 0, stream);
}

// Round 4
// 1680.874 us; speedup vs baseline: 4.2091x; 2.5808x over previous
//
#include <hip/hip_runtime.h>
#include <hip/hip_bf16.h>
#include <math.h>

typedef __hip_bfloat16 bf16;
typedef __attribute__((ext_vector_type(8))) short short8x;
typedef __attribute__((ext_vector_type(4))) float f32x4;

// ---- problem constants ----
static constexpr int cB   = 2;
static constexpr int cL   = 1024;
static constexpr int cLE  = 1024;
static constexpr int cNM  = 80;
static constexpr int cDM  = 512;
static constexpr int cLAYERS = 4;
static constexpr int cDS  = 16;
static constexpr int cKC  = 4;     // conv taps
static constexpr int cH   = 4;     // heads
static constexpr int cDI  = 1024;  // EXP*DM
static constexpr int cDTR = 32;
static constexpr int cHD  = 128;   // head dim

static constexpr int cNCH = 16;    // scan chunks
static constexpr int cCHL = cL / cNCH;  // 64 steps per chunk

// =====================================================================
// bf16 MFMA GEMM, 128x128 tile, 4 waves (2x2 of 64x64), K-step 32.
//   C = act( A @ W^T + bias ) + addv ; A: M x K bf16 (lda), W: N x K bf16 (ldw)
//   Writes f32 C (if Cf) and/or bf16 C (if Cb).
//   Batched over blockIdx.z: i1=z/bdiv, i2=z%bdiv.
//   Requires K % 32 == 0, M % 128 == 0 at the dims used here.
// =====================================================================
template<int ACT>
__global__ __launch_bounds__(256)
void bgemm_kernel(const bf16* __restrict__ A, const bf16* __restrict__ W,
                  const float* __restrict__ bias, const float* __restrict__ addv,
                  float* __restrict__ Cf, bf16* __restrict__ Cb,
                  int M, int N, int Kd, int lda, int ldw, int ldcf, int ldcb, int ldadd,
                  int bdiv, long sA1, long sA2, long sW1, long sW2,
                  long sCf1, long sCf2, long sCb1, long sCb2)
{
    const int z = blockIdx.z;
    const int i1 = z / bdiv, i2 = z % bdiv;
    A += i1 * sA1 + i2 * sA2;
    W += i1 * sW1 + i2 * sW2;

    const int bm = blockIdx.y * 128;
    const int bn = blockIdx.x * 128;
    const int tid = threadIdx.x;
    const int lane = tid & 63;
    const int wid = tid >> 6;              // 0..3
    const int wr = wid >> 1, wc = wid & 1; // 2x2 wave grid

    __shared__ bf16 As[128 * 32];
    __shared__ bf16 Bs[128 * 32];

    f32x4 acc[4][4] = {};

    const int r_in = lane >> 2;            // 0..15 (staging row within 16-row chunk)
    const int kb   = (lane & 3) * 8;       // staging k offset
    const int hi   = lane >> 4;            // 0..3
    const int rc   = lane & 15;

    for (int k0 = 0; k0 < Kd; k0 += 32) {
#pragma unroll
        for (int iss = 0; iss < 2; iss++) {
            int row = wid * 32 + iss * 16 + r_in;
            int gm = bm + row; if (gm >= M) gm = M - 1;
            const bf16* ga = A + (long)gm * lda + k0 + kb;
            __builtin_amdgcn_global_load_lds(
                (const __attribute__((address_space(1))) void*)ga,
                (__attribute__((address_space(3))) void*)(As + (wid * 32 + iss * 16) * 32),
                16, 0, 0);
            int gn = bn + row; if (gn >= N) gn = N - 1;
            const bf16* gb = W + (long)gn * ldw + k0 + kb;
            __builtin_amdgcn_global_load_lds(
                (const __attribute__((address_space(1))) void*)gb,
                (__attribute__((address_space(3))) void*)(Bs + (wid * 32 + iss * 16) * 32),
                16, 0, 0);
        }
        asm volatile("s_waitcnt vmcnt(0)" ::: "memory");
        __syncthreads();

        short8x af[4], bfv[4];
#pragma unroll
        for (int i = 0; i < 4; i++)
            af[i] = *(const short8x*)(As + (wr * 64 + i * 16 + rc) * 32 + hi * 8);
#pragma unroll
        for (int j = 0; j < 4; j++)
            bfv[j] = *(const short8x*)(Bs + (wc * 64 + j * 16 + rc) * 32 + hi * 8);
#pragma unroll
        for (int i = 0; i < 4; i++)
#pragma unroll
            for (int j = 0; j < 4; j++)
                acc[i][j] = __builtin_amdgcn_mfma_f32_16x16x32_bf16(af[i], bfv[j], acc[i][j], 0, 0, 0);
        __syncthreads();
    }

    // epilogue: C/D frag mapping col=lane&15, row=(lane>>4)*4+r  [m89-verified]
    const long cfo = i1 * sCf1 + i2 * sCf2;
    const long cbo = i1 * sCb1 + i2 * sCb2;
#pragma unroll
    for (int i = 0; i < 4; i++) {
#pragma unroll
        for (int r = 0; r < 4; r++) {
            const int gm = bm + wr * 64 + i * 16 + hi * 4 + r;
            if (gm >= M) continue;
#pragma unroll
            for (int j = 0; j < 4; j++) {
                const int gn = bn + wc * 64 + j * 16 + rc;
                if (gn >= N) continue;
                float v = acc[i][j][r];
                if (bias) v += bias[gn];
                if (ACT == 1) v = (v > 20.f) ? v : log1pf(__expf(v));
                if (addv) v += addv[cfo + (long)gm * ldadd + gn];
                if (Cf) Cf[cfo + (long)gm * ldcf + gn] = v;
                if (Cb) Cb[cbo + (long)gm * ldcb + gn] = __float2bfloat16(v);
            }
        }
    }
}

static inline void bgemm(int ACT, const bf16* A, const bf16* W, const float* bias,
                         const float* addv, float* Cf, bf16* Cb,
                         int M, int N, int Kd, int lda, int ldw, int ldcf, int ldcb, int ldadd,
                         int nz, int bdiv, long sA1, long sA2, long sW1, long sW2,
                         long sCf1, long sCf2, long sCb1, long sCb2, hipStream_t s)
{
    dim3 g((N + 127) / 128, (M + 127) / 128, nz), b(256);
    if (ACT == 1)
        bgemm_kernel<1><<<g, b, 0, s>>>(A, W, bias, addv, Cf, Cb, M, N, Kd, lda, ldw, ldcf, ldcb,
                                        ldadd, bdiv, sA1, sA2, sW1, sW2, sCf1, sCf2, sCb1, sCb2);
    else
        bgemm_kernel<0><<<g, b, 0, s>>>(A, W, bias, addv, Cf, Cb, M, N, Kd, lda, ldw, ldcf, ldcb,
                                        ldadd, bdiv, sA1, sA2, sW1, sW2, sCf1, sCf2, sCb1, sCb2);
}

static inline void bgemm_plain(int ACT, const bf16* A, const bf16* W, const float* bias,
                               const float* addv, float* Cf, bf16* Cb,
                               int M, int N, int Kd, int lda, int ldw, int ldcf, int ldcb,
                               int ldadd, hipStream_t s)
{
    bgemm(ACT, A, W, bias, addv, Cf, Cb, M, N, Kd, lda, ldw, ldcf, ldcb, ldadd,
          1, 1, 0, 0, 0, 0, 0, 0, 0, 0, s);
}

// =====================================================================
// f32 fallback GEMM (edge cases with K=80 / N=80):  C = A @ W^T + bias
// =====================================================================
__launch_bounds__(256)
__global__ void gemm_f32_kernel(const float* __restrict__ A, const float* __restrict__ W,
                                const float* __restrict__ bias, float* __restrict__ C,
                                int M, int N, int Kd, int lda, int ldw, int ldc)
{
    const int bm = blockIdx.y * 64;
    const int bn = blockIdx.x * 64;
    const int tx = threadIdx.x, ty = threadIdx.y;
    const int tid = ty * 16 + tx;

    __shared__ float As[16][65];
    __shared__ float Ws[16][65];
    float acc[4][4] = {};

    for (int k0 = 0; k0 < Kd; k0 += 16) {
        const int kk = tid & 15, r0 = tid >> 4;
#pragma unroll
        for (int i = 0; i < 4; i++) {
            const int r = r0 + i * 16;
            const int gm = bm + r, gk = k0 + kk;
            float v = 0.f;
            if (gm < M && gk < Kd) v = A[(long)gm * lda + gk];
            As[kk][r] = v;
            const int gn = bn + r;
            float w = 0.f;
            if (gn < N && gk < Kd) w = W[(long)gn * ldw + gk];
            Ws[kk][r] = w;
        }
        __syncthreads();
#pragma unroll
        for (int k2 = 0; k2 < 16; k2++) {
            float a[4], bv[4];
#pragma unroll
            for (int i = 0; i < 4; i++) a[i] = As[k2][ty + i * 16];
#pragma unroll
            for (int j = 0; j < 4; j++) bv[j] = Ws[k2][tx + j * 16];
#pragma unroll
            for (int i = 0; i < 4; i++)
#pragma unroll
                for (int j = 0; j < 4; j++)
                    acc[i][j] += a[i] * bv[j];
        }
        __syncthreads();
    }
#pragma unroll
    for (int i = 0; i < 4; i++) {
        const int gm = bm + ty + i * 16;
        if (gm >= M) continue;
#pragma unroll
        for (int j = 0; j < 4; j++) {
            const int gn = bn + tx + j * 16;
            if (gn >= N) continue;
            float v = acc[i][j];
            if (bias) v += bias[gn];
            C[(long)gm * ldc + gn] = v;
        }
    }
}

// =====================================================================
// f32 -> bf16 flat convert
// =====================================================================
__global__ void f32_to_bf16_kernel(const float* __restrict__ in, bf16* __restrict__ out, long n)
{
    long i = ((long)blockIdx.x * 256 + threadIdx.x) * 4;
    if (i + 3 < n) {
        float4 v = *(const float4*)(in + i);
        out[i]     = __float2bfloat16(v.x);
        out[i + 1] = __float2bfloat16(v.y);
        out[i + 2] = __float2bfloat16(v.z);
        out[i + 3] = __float2bfloat16(v.w);
    } else {
        for (; i < n; i++) out[i] = __float2bfloat16(in[i]);
    }
}
static inline void cvt(const float* in, bf16* out, long n, hipStream_t s)
{
    int blocks = (int)((n / 4 + 255) / 256);
    f32_to_bf16_kernel<<<blocks, 256, 0, s>>>(in, out, n);
}

// =====================================================================
// bf16 transpose per batch:  in (b*LE+le) x DM  ->  out b: DM x LE
// =====================================================================
__global__ void transpose_bf16_kernel(const bf16* __restrict__ in, bf16* __restrict__ out)
{
    __shared__ bf16 t[32][33];
    const int b = blockIdx.z;
    const int le0 = blockIdx.x * 32, d0 = blockIdx.y * 32;
    const int tid = threadIdx.x;
    const int c = tid & 31, r = tid >> 5;
    for (int i = r; i < 32; i += 8)
        t[i][c] = in[((long)b * cLE + le0 + i) * cDM + d0 + c];
    __syncthreads();
    for (int i = r; i < 32; i += 8)
        out[((long)b * cDM + d0 + i) * cLE + le0 + c] = t[c][i];
}

// =====================================================================
// RMSNorm per row (optional f32 and bf16 outputs)
// =====================================================================
__global__ void rmsnorm_kernel(const float* __restrict__ x, const float* __restrict__ w,
                               float* __restrict__ outf, bf16* __restrict__ outb, int Dm)
{
    const int row = blockIdx.x;
    const float* xr = x + (long)row * Dm;
    float s = 0.f;
    for (int i = threadIdx.x; i < Dm; i += 256) { float v = xr[i]; s += v * v; }
    __shared__ float red[5];
    const int lane = threadIdx.x & 63, wv = threadIdx.x >> 6;
#pragma unroll
    for (int off = 1; off < 64; off <<= 1) s += __shfl_xor(s, off);
    if (lane == 0) red[wv] = s;
    __syncthreads();
    if (threadIdx.x == 0) {
        float t = red[0] + red[1] + red[2] + red[3];
        red[4] = rsqrtf(t / Dm + 1e-5f);
    }
    __syncthreads();
    const float scale = red[4];
    for (int i = threadIdx.x; i < Dm; i += 256) {
        float v = xr[i] * scale * w[i];
        if (outf) outf[(long)row * Dm + i] = v;
        if (outb) outb[(long)row * Dm + i] = __float2bfloat16(v);
    }
}

// =====================================================================
// LayerNorm per row -> f32 + bf16 outputs
// =====================================================================
__global__ void layernorm_kernel(const float* __restrict__ x, const float* __restrict__ w,
                                 const float* __restrict__ b, float* __restrict__ outf,
                                 bf16* __restrict__ outb, int Dm)
{
    const int row = blockIdx.x;
    const float* xr = x + (long)row * Dm;
    float s = 0.f, sq = 0.f;
    for (int i = threadIdx.x; i < Dm; i += 256) { float v = xr[i]; s += v; sq += v * v; }
    __shared__ float red[8];
    __shared__ float mv[2];
    const int lane = threadIdx.x & 63, wv = threadIdx.x >> 6;
#pragma unroll
    for (int off = 1; off < 64; off <<= 1) { s += __shfl_xor(s, off); sq += __shfl_xor(sq, off); }
    if (lane == 0) { red[wv] = s; red[4 + wv] = sq; }
    __syncthreads();
    if (threadIdx.x == 0) {
        float ts = red[0] + red[1] + red[2] + red[3];
        float tq = red[4] + red[5] + red[6] + red[7];
        float m = ts / Dm;
        float var = tq / Dm - m * m;
        mv[0] = m;
        mv[1] = rsqrtf(var + 1e-5f);
    }
    __syncthreads();
    const float m = mv[0], rs = mv[1];
    for (int i = threadIdx.x; i < Dm; i += 256) {
        float v = (xr[i] - m) * rs * w[i] + b[i];
        outf[(long)row * Dm + i] = v;
        outb[(long)row * Dm + i] = __float2bfloat16(v);
    }
}

// =====================================================================
// Causal depthwise conv (K=4) + bias + SiLU -> xm f32 + bf16
// =====================================================================
__global__ void conv_silu_kernel(const float* __restrict__ xr, const float* __restrict__ w,
                                 const float* __restrict__ bias, float* __restrict__ xm,
                                 bf16* __restrict__ xmb)
{
    const int idx = blockIdx.x * 256 + threadIdx.x;
    if (idx >= cB * cL * cDI) return;
    const int d = idx & (cDI - 1);
    const int l = (idx >> 10) & (cL - 1);
    const int b = idx >> 20;
    float s = bias[d];
#pragma unroll
    for (int j = 0; j < cKC; j++) {
        const int ls = l + j - (cKC - 1);
        if (ls >= 0) s += w[d * cKC + j] * xr[((long)(b * cL + ls)) * (2 * cDI) + d];
    }
    s = s / (1.f + __expf(-s));
    xm[(long)idx] = s;
    xmb[(long)idx] = __float2bfloat16(s);
}

// =====================================================================
// Chunk-parallel selective scan (3 phases), y written bf16
// =====================================================================
__global__ void scan_phase1(const float* __restrict__ xm, const float* __restrict__ delta,
                            const float* __restrict__ xdbl, const float* __restrict__ Alog,
                            float* __restrict__ aprod_out, float* __restrict__ send_out)
{
    const int idx = blockIdx.x * 256 + threadIdx.x;
    const int n  = idx & (cDS - 1);
    const int d  = (idx >> 4) & (cDI - 1);
    const int ch = (idx >> 14) & (cNCH - 1);
    const int b  = idx >> 18;
    const float A = -__expf(Alog[d * cDS + n]);
    float state = 0.f, aprod = 1.f;
    const int l0 = ch * cCHL;
    for (int t = 0; t < cCHL; t++) {
        const long base = (long)(b * cL + l0 + t);
        const float dl = delta[base * cDI + d];
        const float u  = xm[base * cDI + d];
        const float Bv = xdbl[base * 64 + cDTR + n];
        const float a  = __expf(dl * A);
        state = a * state + dl * u * Bv;
        aprod *= a;
    }
    aprod_out[idx] = aprod;
    send_out[idx]  = state;
}

__global__ void scan_phase2(const float* __restrict__ aprod, const float* __restrict__ send,
                            float* __restrict__ sinit)
{
    const int j = blockIdx.x * 256 + threadIdx.x;
    const int n = j & (cDS - 1);
    const int d = (j >> 4) & (cDI - 1);
    const int b = j >> 14;
    float s = 0.f;
#pragma unroll
    for (int c = 0; c < cNCH; c++) {
        const long off = (((long)(b * cNCH + c) * cDI + d) * cDS) + n;
        sinit[off] = s;
        s = aprod[off] * s + send[off];
    }
}

__global__ void scan_phase3(const float* __restrict__ xm, const float* __restrict__ delta,
                            const float* __restrict__ xdbl, const float* __restrict__ Alog,
                            const float* __restrict__ Dv, const float* __restrict__ xr,
                            const float* __restrict__ sinit, bf16* __restrict__ y)
{
    const int idx = blockIdx.x * 256 + threadIdx.x;
    const int n  = idx & (cDS - 1);
    const int d  = (idx >> 4) & (cDI - 1);
    const int ch = (idx >> 14) & (cNCH - 1);
    const int b  = idx >> 18;
    const float A = -__expf(Alog[d * cDS + n]);
    const float Dval = Dv[d];
    float state = sinit[idx];
    const int l0 = ch * cCHL;
    for (int t = 0; t < cCHL; t++) {
        const long base = (long)(b * cL + l0 + t);
        const float dl = delta[base * cDI + d];
        const float u  = xm[base * cDI + d];
        const float Bv = xdbl[base * 64 + cDTR + n];
        const float Cv = xdbl[base * 64 + cDTR + cDS + n];
        state = __expf(dl * A) * state + dl * u * Bv;
        float contrib = state * Cv;
        contrib += __shfl_xor(contrib, 1);
        contrib += __shfl_xor(contrib, 2);
        contrib += __shfl_xor(contrib, 4);
        contrib += __shfl_xor(contrib, 8);
        if (n == 0) {
            const float res = xr[base * (2 * cDI) + cDI + d];
            const float sig = 1.f / (1.f + __expf(-res));
            y[base * cDI + d] = __float2bfloat16((contrib + u * Dval) * (res * sig));
        }
    }
}

// =====================================================================
// Row softmax with scale; reads f32 row, writes bf16 IN PLACE over the
// start of the same row (row pitch stays `cols` f32 = 2*cols bf16).
// =====================================================================
__global__ void softmax_kernel(float* __restrict__ s, int cols, float scale)
{
    const long row = blockIdx.x;
    float* p = s + row * cols;
    float vals[4];
    float mx = -1e30f;
    int cnt = 0;
    for (int i = threadIdx.x; i < cols; i += 256, cnt++) {
        vals[cnt] = p[i] * scale;
        mx = fmaxf(mx, vals[cnt]);
    }
    __shared__ float red[5];
    const int lane = threadIdx.x & 63, wv = threadIdx.x >> 6;
#pragma unroll
    for (int off = 1; off < 64; off <<= 1) mx = fmaxf(mx, __shfl_xor(mx, off));
    if (lane == 0) red[wv] = mx;
    __syncthreads();
    if (threadIdx.x == 0) red[4] = fmaxf(fmaxf(red[0], red[1]), fmaxf(red[2], red[3]));
    __syncthreads();
    mx = red[4];
    __syncthreads();
    float sum = 0.f;
    for (int c = 0; c < cnt; c++) { vals[c] = __expf(vals[c] - mx); sum += vals[c]; }
#pragma unroll
    for (int off = 1; off < 64; off <<= 1) sum += __shfl_xor(sum, off);
    if (lane == 0) red[wv] = sum;
    __syncthreads();
    if (threadIdx.x == 0) red[4] = red[0] + red[1] + red[2] + red[3];
    __syncthreads();
    const float inv = 1.f / red[4];
    bf16* pb = (bf16*)p;
    cnt = 0;
    for (int i = threadIdx.x; i < cols; i += 256, cnt++)
        pb[i] = __float2bfloat16(vals[cnt] * inv);
}

// =====================================================================
extern "C" void kernel_launch(void* const* d_in, const int* in_sizes, int n_in,
                              void* d_out, int out_size, void* d_ws, size_t ws_size,
                              hipStream_t stream)
{
    const float* x       = (const float*)d_in[0];
    const float* enc     = (const float*)d_in[1];
    const float* W_in    = (const float*)d_in[2];
    const float* b_in    = (const float*)d_in[3];
    const float* m_norm_w= (const float*)d_in[4];
    const float* m_in_w  = (const float*)d_in[5];
    const float* m_conv_w= (const float*)d_in[6];
    const float* m_conv_b= (const float*)d_in[7];
    const float* m_xproj = (const float*)d_in[8];
    const float* m_dt_w  = (const float*)d_in[9];
    const float* m_dt_b  = (const float*)d_in[10];
    const float* m_Alog  = (const float*)d_in[11];
    const float* m_D     = (const float*)d_in[12];
    const float* m_out_w = (const float*)d_in[13];
    const float* a_in_w  = (const float*)d_in[14];
    const float* a_in_b  = (const float*)d_in[15];
    const float* a_out_w = (const float*)d_in[16];
    const float* a_out_b = (const float*)d_in[17];
    const float* a_ln_w  = (const float*)d_in[18];
    const float* a_ln_b  = (const float*)d_in[19];
    const float* normf_w = (const float*)d_in[20];
    const float* W_out   = (const float*)d_in[21];
    float* out = (float*)d_out;

    float* ws = (float*)d_ws;
    long off = 0;
    auto allocf = [&](long n) { float* p = ws + off; off += n; return p; };

    const long M1 = 1 << 20;
    float* bufH    = allocf(M1);
    float* bufPre  = allocf(M1);         // also aprod+send during scan
    float* bufXR   = allocf(4 * M1);     // S (8M f32) overlays XR/XM/Delta during attn
    float* bufXM   = allocf(2 * M1);
    float* bufDelta= allocf(2 * M1);
    float* bufXDBL = allocf(M1 / 8);
    bf16* bufU    = (bf16*)allocf(M1 / 2);      // 1M bf16
    bf16* bufHb   = (bf16*)allocf(M1 / 2);
    bf16* bufXMb  = (bf16*)allocf(M1);          // 2M bf16
    bf16* bufXDBLb= (bf16*)allocf(M1 / 16);
    bf16* bufY    = (bf16*)allocf(M1);          // 2M bf16
    bf16* bufQ    = (bf16*)allocf(M1 / 2);      // also sinit (f32) during scan
    bf16* bufK    = (bf16*)allocf(M1 / 2);
    bf16* bufVb   = (bf16*)allocf(M1 / 2);
    bf16* bufVT   = (bf16*)allocf(M1 / 2);
    bf16* bufO    = (bf16*)allocf(M1 / 2);
    bf16* encb    = (bf16*)allocf(M1 / 2);
    bf16* w_in_b  = (bf16*)allocf(2 * M1);      // 4M params
    bf16* w_xp_b  = (bf16*)allocf(M1 / 8);      // 256K
    bf16* w_dt_b  = (bf16*)allocf(M1 / 16);     // 128K
    bf16* w_out_b = (bf16*)allocf(M1);          // 2M
    bf16* w_ain_b = (bf16*)allocf(3 * M1 / 2);  // 3M
    bf16* w_aout_b= (bf16*)allocf(M1 / 2);      // 1M

    float* bufS   = bufXR;                       // 8M f32 scores
    float* bufAP  = bufPre;                      // 512K
    float* bufSE  = bufPre + 524288;             // 512K
    float* bufSI  = (float*)bufQ;                // 512K f32

    const int Mrows = cB * cL;   // 2048
    const long SUMSZ = (long)cB * cNCH * cDI * cDS;

    // ---- one-time conversions (weights + enc) ----
    cvt(enc,      encb,    (long)cB * cLE * cDM, stream);
    cvt(m_in_w,   w_in_b,  (long)cLAYERS * 2 * cDI * cDM, stream);
    cvt(m_xproj,  w_xp_b,  (long)cLAYERS * 64 * cDI, stream);
    cvt(m_dt_w,   w_dt_b,  (long)cLAYERS * cDI * cDTR, stream);
    cvt(m_out_w,  w_out_b, (long)cLAYERS * cDM * cDI, stream);
    cvt(a_in_w,   w_ain_b, (long)cLAYERS * 3 * cDM * cDM, stream);
    cvt(a_out_w,  w_aout_b,(long)cLAYERS * cDM * cDM, stream);

    // h = x @ W_in.T + b_in   (K=80 edge: f32 path)
    {
        dim3 g((cDM + 63) / 64, (Mrows + 63) / 64), b(16, 16);
        gemm_f32_kernel<<<g, b, 0, stream>>>(x, W_in, b_in, bufH, Mrows, cDM, cNM, cNM, cNM, cDM);
    }

    for (int i = 0; i < cLAYERS; i++) {
        const float* norm_w = m_norm_w + (long)i * cDM;
        const bf16*  in_w   = w_in_b   + (long)i * 2 * cDI * cDM;
        const float* conv_w = m_conv_w + (long)i * cDI * cKC;
        const float* conv_b = m_conv_b + (long)i * cDI;
        const bf16*  xproj  = w_xp_b   + (long)i * 64 * cDI;
        const bf16*  dt_w   = w_dt_b   + (long)i * cDI * cDTR;
        const float* dt_b   = m_dt_b   + (long)i * cDI;
        const float* Alog   = m_Alog   + (long)i * cDI * cDS;
        const float* Dv     = m_D      + (long)i * cDI;
        const bf16*  out_w  = w_out_b  + (long)i * cDM * cDI;
        const bf16*  ain_w  = w_ain_b  + (long)i * 3 * cDM * cDM;
        const float* ain_b  = a_in_b   + (long)i * 3 * cDM;
        const bf16*  aout_w = w_aout_b + (long)i * cDM * cDM;
        const float* aout_b = a_out_b  + (long)i * cDM;
        const float* ln_w   = a_ln_w   + (long)i * cDM;
        const float* ln_b   = a_ln_b   + (long)i * cDM;

        // ---- mamba ----
        rmsnorm_kernel<<<Mrows, 256, 0, stream>>>(bufH, norm_w, nullptr, bufU, cDM);
        // xr = u @ in_w.T  (f32 out)
        bgemm_plain(0, bufU, in_w, nullptr, nullptr, bufXR, nullptr,
                    Mrows, 2 * cDI, cDM, cDM, cDM, 2 * cDI, 0, 0, stream);
        conv_silu_kernel<<<(cB * cL * cDI) / 256, 256, 0, stream>>>(bufXR, conv_w, conv_b, bufXM, bufXMb);
        // x_dbl = xm @ xproj.T  (f32 + bf16)
        bgemm_plain(0, bufXMb, xproj, nullptr, nullptr, bufXDBL, bufXDBLb,
                    Mrows, 64, cDI, cDI, cDI, 64, 64, 0, stream);
        // delta = softplus(dlt @ dt_w.T + dt_b)  (f32)
        bgemm_plain(1, bufXDBLb, dt_w, dt_b, nullptr, bufDelta, nullptr,
                    Mrows, cDI, cDTR, 64, cDTR, cDI, 0, 0, stream);
        // scan
        scan_phase1<<<(int)(SUMSZ / 256), 256, 0, stream>>>(bufXM, bufDelta, bufXDBL, Alog, bufAP, bufSE);
        scan_phase2<<<(cB * cDI * cDS) / 256, 256, 0, stream>>>(bufAP, bufSE, bufSI);
        scan_phase3<<<(int)(SUMSZ / 256), 256, 0, stream>>>(bufXM, bufDelta, bufXDBL, Alog, Dv, bufXR, bufSI, bufY);
        // h += y @ out_w.T  (f32 h + bf16 hb)
        bgemm_plain(0, bufY, out_w, nullptr, bufH, bufH, bufHb,
                    Mrows, cDM, cDI, cDI, cDI, cDM, cDM, cDM, stream);

        // ---- cross attention ----
        bgemm_plain(0, bufHb, ain_w, ain_b, nullptr, nullptr, bufQ,
                    Mrows, cDM, cDM, cDM, cDM, 0, cDM, 0, stream);
        bgemm_plain(0, encb, ain_w + (long)cDM * cDM, ain_b + cDM, nullptr, nullptr, bufK,
                    Mrows, cDM, cDM, cDM, cDM, 0, cDM, 0, stream);
        bgemm_plain(0, encb, ain_w + 2L * cDM * cDM, ain_b + 2 * cDM, nullptr, nullptr, bufVb,
                    Mrows, cDM, cDM, cDM, cDM, 0, cDM, 0, stream);
        {
            dim3 g(cLE / 32, cDM / 32, cB);
            transpose_bf16_kernel<<<g, 256, 0, stream>>>(bufVb, bufVT);
        }
        // scores[b,h] = q @ k.T  (f32)
        bgemm(0, bufQ, bufK, nullptr, nullptr, bufS, nullptr,
              cL, cLE, cHD, cDM, cDM, cLE, 0, 0,
              cB * cH, cH,
              (long)cL * cDM, (long)cHD,
              (long)cLE * cDM, (long)cHD,
              (long)cH * cL * cLE, (long)cL * cLE, 0, 0, stream);
        softmax_kernel<<<cB * cH * cL, 256, 0, stream>>>(bufS, cLE, 0.08838834764831845f);
        // o[b,:,h] = P @ V  via  P (bf16 in-place rows, pitch 2*LE) x VT
        bgemm(0, (const bf16*)bufS, bufVT, nullptr, nullptr, nullptr, bufO,
              cL, cHD, cLE, 2 * cLE, cLE, 0, cDM, 0,
              cB * cH, cH,
              (long)cH * cL * (2 * cLE), (long)cL * (2 * cLE),
              (long)cDM * cLE, (long)cHD * cLE,
              0, 0, (long)cL * cDM, (long)cHD, stream);
        // pre = o @ aout_w.T + aout_b + h ; h = LN(pre) (f32 + bf16)
        bgemm_plain(0, bufO, aout_w, aout_b, bufH, bufPre, nullptr,
                    Mrows, cDM, cDM, cDM, cDM, cDM, 0, cDM, stream);
        layernorm_kernel<<<Mrows, 256, 0, stream>>>(bufPre, ln_w, ln_b, bufH, bufHb, cDM);
    }

    // final: out = rmsnorm(h) @ W_out.T   (N=80 edge: f32 path)
    rmsnorm_kernel<<<Mrows, 256, 0, stream>>>(bufH, normf_w, bufXM, nullptr, cDM);
    {
        dim3 g((cNM + 63) / 64, (Mrows + 63) / 64), b(16, 16);
        gemm_f32_kernel<<<g, b, 0, stream>>>(bufXM, W_out, nullptr, out, Mrows, cNM, cDM, cDM, cDM, cNM);
    }
}

// Round 5
// 1461.629 us; speedup vs baseline: 4.8404x; 1.1500x over previous
//
#include <hip/hip_runtime.h>
#include <hip/hip_bf16.h>
#include <math.h>

typedef __hip_bfloat16 bf16;
typedef __attribute__((ext_vector_type(8))) short short8x;
typedef __attribute__((ext_vector_type(4))) float f32x4;

// ---- problem constants ----
static constexpr int cB   = 2;
static constexpr int cL   = 1024;
static constexpr int cLE  = 1024;
static constexpr int cNM  = 80;
static constexpr int cDM  = 512;
static constexpr int cLAYERS = 4;
static constexpr int cDS  = 16;
static constexpr int cKC  = 4;     // conv taps
static constexpr int cH   = 4;     // heads
static constexpr int cDI  = 1024;  // EXP*DM
static constexpr int cDTR = 32;
static constexpr int cHD  = 128;   // head dim

static constexpr int cNCH = 16;    // scan chunks
static constexpr int cCHL = cL / cNCH;  // 64 steps per chunk

// =====================================================================
// bf16 MFMA GEMM, BMxBN tile, 4 waves (2x2), K-step 32.
//   C = act( A @ W^T + bias ) + addv ; A: M x K bf16 (lda), W: N x K bf16 (ldw)
//   Writes f32 C (if Cf) and/or bf16 C (if Cb). Batched over blockIdx.z.
//   Requires K % 32 == 0 (pad), M >= BM handled by row clamp + epilogue guard.
// =====================================================================
template<int ACT, int BM, int BN>
__global__ __launch_bounds__(256)
void bgemm_kernel(const bf16* __restrict__ A, const bf16* __restrict__ W,
                  const float* __restrict__ bias, const float* __restrict__ addv,
                  float* __restrict__ Cf, bf16* __restrict__ Cb,
                  int M, int N, int Kd, int lda, int ldw, int ldcf, int ldcb, int ldadd,
                  int bdiv, long sA1, long sA2, long sW1, long sW2,
                  long sCf1, long sCf2, long sCb1, long sCb2)
{
    constexpr int RM = BM / 32;            // per-wave 16x frag repeats (rows)
    constexpr int RN = BN / 32;
    const int z = blockIdx.z;
    const int i1 = z / bdiv, i2 = z % bdiv;
    A += i1 * sA1 + i2 * sA2;
    W += i1 * sW1 + i2 * sW2;

    const int bm = blockIdx.y * BM;
    const int bn = blockIdx.x * BN;
    const int tid = threadIdx.x;
    const int lane = tid & 63;
    const int wid = tid >> 6;              // 0..3
    const int wr = wid >> 1, wc = wid & 1; // 2x2 wave grid

    __shared__ bf16 As[BM * 32];
    __shared__ bf16 Bs[BN * 32];

    f32x4 acc[RM][RN] = {};

    const int r_in = lane >> 2;            // 0..15
    const int kb   = (lane & 3) * 8;       // k offset for staging
    const int hi   = lane >> 4;            // 0..3
    const int rc   = lane & 15;

    for (int k0 = 0; k0 < Kd; k0 += 32) {
#pragma unroll
        for (int iss = 0; iss < BM / 64; iss++) {
            const int row = wid * (BM / 4) + iss * 16 + r_in;
            int gm = bm + row; if (gm >= M) gm = M - 1;
            const bf16* ga = A + (long)gm * lda + k0 + kb;
            __builtin_amdgcn_global_load_lds(
                (const __attribute__((address_space(1))) void*)ga,
                (__attribute__((address_space(3))) void*)(As + (wid * (BM / 4) + iss * 16) * 32),
                16, 0, 0);
        }
#pragma unroll
        for (int iss = 0; iss < BN / 64; iss++) {
            const int row = wid * (BN / 4) + iss * 16 + r_in;
            int gn = bn + row; if (gn >= N) gn = N - 1;
            const bf16* gb = W + (long)gn * ldw + k0 + kb;
            __builtin_amdgcn_global_load_lds(
                (const __attribute__((address_space(1))) void*)gb,
                (__attribute__((address_space(3))) void*)(Bs + (wid * (BN / 4) + iss * 16) * 32),
                16, 0, 0);
        }
        asm volatile("s_waitcnt vmcnt(0)" ::: "memory");
        __syncthreads();

        short8x af[RM], bfv[RN];
#pragma unroll
        for (int i = 0; i < RM; i++)
            af[i] = *(const short8x*)(As + (wr * (BM / 2) + i * 16 + rc) * 32 + hi * 8);
#pragma unroll
        for (int j = 0; j < RN; j++)
            bfv[j] = *(const short8x*)(Bs + (wc * (BN / 2) + j * 16 + rc) * 32 + hi * 8);
#pragma unroll
        for (int i = 0; i < RM; i++)
#pragma unroll
            for (int j = 0; j < RN; j++)
                acc[i][j] = __builtin_amdgcn_mfma_f32_16x16x32_bf16(af[i], bfv[j], acc[i][j], 0, 0, 0);
        __syncthreads();
    }

    // epilogue: C/D frag mapping col=lane&15, row=(lane>>4)*4+r  [m89-verified]
    const long cfo = i1 * sCf1 + i2 * sCf2;
    const long cbo = i1 * sCb1 + i2 * sCb2;
#pragma unroll
    for (int i = 0; i < RM; i++) {
#pragma unroll
        for (int r = 0; r < 4; r++) {
            const int gm = bm + wr * (BM / 2) + i * 16 + hi * 4 + r;
            if (gm >= M) continue;
#pragma unroll
            for (int j = 0; j < RN; j++) {
                const int gn = bn + wc * (BN / 2) + j * 16 + rc;
                if (gn >= N) continue;
                float v = acc[i][j][r];
                if (bias) v += bias[gn];
                if (ACT == 1) v = (v > 20.f) ? v : log1pf(__expf(v));
                if (addv) v += addv[cfo + (long)gm * ldadd + gn];
                if (Cf) Cf[cfo + (long)gm * ldcf + gn] = v;
                if (Cb) Cb[cbo + (long)gm * ldcb + gn] = __float2bfloat16(v);
            }
        }
    }
}

static inline void bgemm(int ACT, int TILE, const bf16* A, const bf16* W, const float* bias,
                         const float* addv, float* Cf, bf16* Cb,
                         int M, int N, int Kd, int lda, int ldw, int ldcf, int ldcb, int ldadd,
                         int nz, int bdiv, long sA1, long sA2, long sW1, long sW2,
                         long sCf1, long sCf2, long sCb1, long sCb2, hipStream_t s)
{
    dim3 g((N + TILE - 1) / TILE, (M + TILE - 1) / TILE, nz), b(256);
    if (TILE == 128) {
        if (ACT == 1)
            bgemm_kernel<1, 128, 128><<<g, b, 0, s>>>(A, W, bias, addv, Cf, Cb, M, N, Kd, lda, ldw,
                ldcf, ldcb, ldadd, bdiv, sA1, sA2, sW1, sW2, sCf1, sCf2, sCb1, sCb2);
        else
            bgemm_kernel<0, 128, 128><<<g, b, 0, s>>>(A, W, bias, addv, Cf, Cb, M, N, Kd, lda, ldw,
                ldcf, ldcb, ldadd, bdiv, sA1, sA2, sW1, sW2, sCf1, sCf2, sCb1, sCb2);
    } else {
        bgemm_kernel<0, 64, 64><<<g, b, 0, s>>>(A, W, bias, addv, Cf, Cb, M, N, Kd, lda, ldw,
            ldcf, ldcb, ldadd, bdiv, sA1, sA2, sW1, sW2, sCf1, sCf2, sCb1, sCb2);
    }
}

static inline void bgemm_plain(int ACT, int TILE, const bf16* A, const bf16* W, const float* bias,
                               const float* addv, float* Cf, bf16* Cb,
                               int M, int N, int Kd, int lda, int ldw, int ldcf, int ldcb,
                               int ldadd, hipStream_t s)
{
    bgemm(ACT, TILE, A, W, bias, addv, Cf, Cb, M, N, Kd, lda, ldw, ldcf, ldcb, ldadd,
          1, 1, 0, 0, 0, 0, 0, 0, 0, 0, s);
}

// =====================================================================
// f32 -> bf16 flat convert
// =====================================================================
__global__ void f32_to_bf16_kernel(const float* __restrict__ in, bf16* __restrict__ out, long n)
{
    long i = ((long)blockIdx.x * 256 + threadIdx.x) * 4;
    if (i + 3 < n) {
        float4 v = *(const float4*)(in + i);
        out[i]     = __float2bfloat16(v.x);
        out[i + 1] = __float2bfloat16(v.y);
        out[i + 2] = __float2bfloat16(v.z);
        out[i + 3] = __float2bfloat16(v.w);
    } else {
        for (; i < n; i++) out[i] = __float2bfloat16(in[i]);
    }
}
static inline void cvt(const float* in, bf16* out, long n, hipStream_t s)
{
    int blocks = (int)((n / 4 + 255) / 256);
    f32_to_bf16_kernel<<<blocks, 256, 0, s>>>(in, out, n);
}

// f32 (rows x kin) -> bf16 (rows x kout), zero-padded beyond kin
__global__ void cvt_pad_kernel(const float* __restrict__ in, bf16* __restrict__ out,
                               int rows, int kin, int kout)
{
    const int idx = blockIdx.x * 256 + threadIdx.x;
    if (idx >= rows * kout) return;
    const int r = idx / kout, k = idx - r * kout;
    out[idx] = __float2bfloat16(k < kin ? in[(long)r * kin + k] : 0.f);
}

// =====================================================================
// bf16 transpose per batch:  in rows (b*LE+le) x ldin, cols [col0, col0+DM)
//   -> out b: DM x LE
// =====================================================================
__global__ void transpose_bf16_kernel(const bf16* __restrict__ in, bf16* __restrict__ out,
                                      int ldin, int col0)
{
    __shared__ bf16 t[32][33];
    const int b = blockIdx.z;
    const int le0 = blockIdx.x * 32, d0 = blockIdx.y * 32;
    const int tid = threadIdx.x;
    const int c = tid & 31, r = tid >> 5;
    for (int i = r; i < 32; i += 8)
        t[i][c] = in[((long)b * cLE + le0 + i) * ldin + col0 + d0 + c];
    __syncthreads();
    for (int i = r; i < 32; i += 8)
        out[((long)b * cDM + d0 + i) * cLE + le0 + c] = t[c][i];
}

// =====================================================================
// RMSNorm per row (optional f32 and bf16 outputs)
// =====================================================================
__global__ void rmsnorm_kernel(const float* __restrict__ x, const float* __restrict__ w,
                               float* __restrict__ outf, bf16* __restrict__ outb, int Dm)
{
    const int row = blockIdx.x;
    const float* xr = x + (long)row * Dm;
    float s = 0.f;
    for (int i = threadIdx.x; i < Dm; i += 256) { float v = xr[i]; s += v * v; }
    __shared__ float red[5];
    const int lane = threadIdx.x & 63, wv = threadIdx.x >> 6;
#pragma unroll
    for (int off = 1; off < 64; off <<= 1) s += __shfl_xor(s, off);
    if (lane == 0) red[wv] = s;
    __syncthreads();
    if (threadIdx.x == 0) {
        float t = red[0] + red[1] + red[2] + red[3];
        red[4] = rsqrtf(t / Dm + 1e-5f);
    }
    __syncthreads();
    const float scale = red[4];
    for (int i = threadIdx.x; i < Dm; i += 256) {
        float v = xr[i] * scale * w[i];
        if (outf) outf[(long)row * Dm + i] = v;
        if (outb) outb[(long)row * Dm + i] = __float2bfloat16(v);
    }
}

// =====================================================================
// LayerNorm per row -> f32 + bf16 outputs
// =====================================================================
__global__ void layernorm_kernel(const float* __restrict__ x, const float* __restrict__ w,
                                 const float* __restrict__ b, float* __restrict__ outf,
                                 bf16* __restrict__ outb, int Dm)
{
    const int row = blockIdx.x;
    const float* xr = x + (long)row * Dm;
    float s = 0.f, sq = 0.f;
    for (int i = threadIdx.x; i < Dm; i += 256) { float v = xr[i]; s += v; sq += v * v; }
    __shared__ float red[8];
    __shared__ float mv[2];
    const int lane = threadIdx.x & 63, wv = threadIdx.x >> 6;
#pragma unroll
    for (int off = 1; off < 64; off <<= 1) { s += __shfl_xor(s, off); sq += __shfl_xor(sq, off); }
    if (lane == 0) { red[wv] = s; red[4 + wv] = sq; }
    __syncthreads();
    if (threadIdx.x == 0) {
        float ts = red[0] + red[1] + red[2] + red[3];
        float tq = red[4] + red[5] + red[6] + red[7];
        float m = ts / Dm;
        float var = tq / Dm - m * m;
        mv[0] = m;
        mv[1] = rsqrtf(var + 1e-5f);
    }
    __syncthreads();
    const float m = mv[0], rs = mv[1];
    for (int i = threadIdx.x; i < Dm; i += 256) {
        float v = (xr[i] - m) * rs * w[i] + b[i];
        outf[(long)row * Dm + i] = v;
        outb[(long)row * Dm + i] = __float2bfloat16(v);
    }
}

// =====================================================================
// Causal depthwise conv (K=4) + bias + SiLU -> xm f32 + bf16
// =====================================================================
__global__ void conv_silu_kernel(const float* __restrict__ xr, const float* __restrict__ w,
                                 const float* __restrict__ bias, float* __restrict__ xm,
                                 bf16* __restrict__ xmb)
{
    const int idx = blockIdx.x * 256 + threadIdx.x;
    if (idx >= cB * cL * cDI) return;
    const int d = idx & (cDI - 1);
    const int l = (idx >> 10) & (cL - 1);
    const int b = idx >> 20;
    float s = bias[d];
#pragma unroll
    for (int j = 0; j < cKC; j++) {
        const int ls = l + j - (cKC - 1);
        if (ls >= 0) s += w[d * cKC + j] * xr[((long)(b * cL + ls)) * (2 * cDI) + d];
    }
    s = s / (1.f + __expf(-s));
    xm[(long)idx] = s;
    xmb[(long)idx] = __float2bfloat16(s);
}

// =====================================================================
// Chunk-parallel selective scan (3 phases), y written bf16
// =====================================================================
__global__ void scan_phase1(const float* __restrict__ xm, const float* __restrict__ delta,
                            const float* __restrict__ xdbl, const float* __restrict__ Alog,
                            float* __restrict__ aprod_out, float* __restrict__ send_out)
{
    const int idx = blockIdx.x * 256 + threadIdx.x;
    const int n  = idx & (cDS - 1);
    const int d  = (idx >> 4) & (cDI - 1);
    const int ch = (idx >> 14) & (cNCH - 1);
    const int b  = idx >> 18;
    const float A = -__expf(Alog[d * cDS + n]);
    float state = 0.f, aprod = 1.f;
    const int l0 = ch * cCHL;
    for (int t = 0; t < cCHL; t++) {
        const long base = (long)(b * cL + l0 + t);
        const float dl = delta[base * cDI + d];
        const float u  = xm[base * cDI + d];
        const float Bv = xdbl[base * 64 + cDTR + n];
        const float a  = __expf(dl * A);
        state = a * state + dl * u * Bv;
        aprod *= a;
    }
    aprod_out[idx] = aprod;
    send_out[idx]  = state;
}

__global__ void scan_phase2(const float* __restrict__ aprod, const float* __restrict__ send,
                            float* __restrict__ sinit)
{
    const int j = blockIdx.x * 256 + threadIdx.x;
    const int n = j & (cDS - 1);
    const int d = (j >> 4) & (cDI - 1);
    const int b = j >> 14;
    float s = 0.f;
#pragma unroll
    for (int c = 0; c < cNCH; c++) {
        const long off = (((long)(b * cNCH + c) * cDI + d) * cDS) + n;
        sinit[off] = s;
        s = aprod[off] * s + send[off];
    }
}

__global__ void scan_phase3(const float* __restrict__ xm, const float* __restrict__ delta,
                            const float* __restrict__ xdbl, const float* __restrict__ Alog,
                            const float* __restrict__ Dv, const float* __restrict__ xr,
                            const float* __restrict__ sinit, bf16* __restrict__ y)
{
    const int idx = blockIdx.x * 256 + threadIdx.x;
    const int n  = idx & (cDS - 1);
    const int d  = (idx >> 4) & (cDI - 1);
    const int ch = (idx >> 14) & (cNCH - 1);
    const int b  = idx >> 18;
    const float A = -__expf(Alog[d * cDS + n]);
    const float Dval = Dv[d];
    float state = sinit[idx];
    const int l0 = ch * cCHL;
    for (int t = 0; t < cCHL; t++) {
        const long base = (long)(b * cL + l0 + t);
        const float dl = delta[base * cDI + d];
        const float u  = xm[base * cDI + d];
        const float Bv = xdbl[base * 64 + cDTR + n];
        const float Cv = xdbl[base * 64 + cDTR + cDS + n];
        state = __expf(dl * A) * state + dl * u * Bv;
        float contrib = state * Cv;
        contrib += __shfl_xor(contrib, 1);
        contrib += __shfl_xor(contrib, 2);
        contrib += __shfl_xor(contrib, 4);
        contrib += __shfl_xor(contrib, 8);
        if (n == 0) {
            const float res = xr[base * (2 * cDI) + cDI + d];
            const float sig = 1.f / (1.f + __expf(-res));
            y[base * cDI + d] = __float2bfloat16((contrib + u * Dval) * (res * sig));
        }
    }
}

// =====================================================================
// Row softmax (1024 cols, 256 threads, one float4/thread); reads f32 row,
// writes bf16 IN PLACE over the start of the same row (pitch stays 1024 f32).
// =====================================================================
__global__ void softmax_kernel(float* __restrict__ s, float scale)
{
    const long row = blockIdx.x;
    float* p = s + row * 1024;
    const int t = threadIdx.x;
    float4 v = ((const float4*)p)[t];
    v.x *= scale; v.y *= scale; v.z *= scale; v.w *= scale;
    float mx = fmaxf(fmaxf(v.x, v.y), fmaxf(v.z, v.w));
    __shared__ float red[8];
    const int lane = t & 63, wv = t >> 6;
#pragma unroll
    for (int off = 1; off < 64; off <<= 1) mx = fmaxf(mx, __shfl_xor(mx, off));
    if (lane == 0) red[wv] = mx;
    __syncthreads();
    mx = fmaxf(fmaxf(red[0], red[1]), fmaxf(red[2], red[3]));
    v.x = __expf(v.x - mx); v.y = __expf(v.y - mx);
    v.z = __expf(v.z - mx); v.w = __expf(v.w - mx);
    float sum = (v.x + v.y) + (v.z + v.w);
#pragma unroll
    for (int off = 1; off < 64; off <<= 1) sum += __shfl_xor(sum, off);
    if (lane == 0) red[4 + wv] = sum;
    __syncthreads();
    const float inv = 1.f / (red[4] + red[5] + red[6] + red[7]);
    bf16 b0 = __float2bfloat16(v.x * inv), b1 = __float2bfloat16(v.y * inv);
    bf16 b2 = __float2bfloat16(v.z * inv), b3 = __float2bfloat16(v.w * inv);
    short4 pk = { *(short*)&b0, *(short*)&b1, *(short*)&b2, *(short*)&b3 };
    ((short4*)p)[t] = pk;
}

// =====================================================================
extern "C" void kernel_launch(void* const* d_in, const int* in_sizes, int n_in,
                              void* d_out, int out_size, void* d_ws, size_t ws_size,
                              hipStream_t stream)
{
    const float* x       = (const float*)d_in[0];
    const float* enc     = (const float*)d_in[1];
    const float* W_in    = (const float*)d_in[2];
    const float* b_in    = (const float*)d_in[3];
    const float* m_norm_w= (const float*)d_in[4];
    const float* m_in_w  = (const float*)d_in[5];
    const float* m_conv_w= (const float*)d_in[6];
    const float* m_conv_b= (const float*)d_in[7];
    const float* m_xproj = (const float*)d_in[8];
    const float* m_dt_w  = (const float*)d_in[9];
    const float* m_dt_b  = (const float*)d_in[10];
    const float* m_Alog  = (const float*)d_in[11];
    const float* m_D     = (const float*)d_in[12];
    const float* m_out_w = (const float*)d_in[13];
    const float* a_in_w  = (const float*)d_in[14];
    const float* a_in_b  = (const float*)d_in[15];
    const float* a_out_w = (const float*)d_in[16];
    const float* a_out_b = (const float*)d_in[17];
    const float* a_ln_w  = (const float*)d_in[18];
    const float* a_ln_b  = (const float*)d_in[19];
    const float* normf_w = (const float*)d_in[20];
    const float* W_out   = (const float*)d_in[21];
    float* out = (float*)d_out;

    float* ws = (float*)d_ws;
    long off = 0;
    auto allocf = [&](long n) { float* p = ws + off; off += n; return p; };

    const long M1 = 1 << 20;
    float* bufH    = allocf(M1);
    float* bufPre  = allocf(M1);         // also aprod+send during scan
    float* bufXR   = allocf(4 * M1);     // S (8M f32) overlays XR/XM/Delta during attn
    float* bufXM   = allocf(2 * M1);
    float* bufDelta= allocf(2 * M1);
    float* bufXDBL = allocf(M1 / 8);
    bf16* bufU    = (bf16*)allocf(M1 / 2);      // 2048x512 bf16
    bf16* bufHb   = (bf16*)allocf(M1 / 2);
    bf16* bufXMb  = (bf16*)allocf(M1);          // 2048x1024 bf16
    bf16* bufXDBLb= (bf16*)allocf(M1 / 16);
    bf16* bufY    = (bf16*)allocf(M1);          // 2048x1024 bf16
    bf16* bufQ    = (bf16*)allocf(M1 / 2);      // also sinit (f32) during scan
    bf16* bufKV   = (bf16*)allocf(M1);          // 2048x1024 bf16: [K | V]
    bf16* bufVT   = (bf16*)allocf(M1 / 2);
    bf16* bufO    = (bf16*)allocf(M1 / 2);
    bf16* encb    = (bf16*)allocf(M1 / 2);
    bf16* w_in_b  = (bf16*)allocf(2 * M1);      // mamba in_w (4 layers)
    bf16* w_xp_b  = (bf16*)allocf(M1 / 8);
    bf16* w_dt_b  = (bf16*)allocf(M1 / 16);
    bf16* w_out_b = (bf16*)allocf(M1);
    bf16* w_ain_b = (bf16*)allocf(3 * M1 / 2);
    bf16* w_aout_b= (bf16*)allocf(M1 / 2);
    bf16* x_pad   = (bf16*)allocf(2048L * 96 / 2);   // x zero-padded K=96
    bf16* w_inp_b = (bf16*)allocf(512L * 96 / 2);    // W_in zero-padded K=96
    bf16* w_outf_b= (bf16*)allocf(80L * 512 / 2);    // W_out bf16

    float* bufS   = bufXR;                       // 8M f32 scores
    float* bufAP  = bufPre;                      // 512K
    float* bufSE  = bufPre + 524288;             // 512K
    float* bufSI  = (float*)bufQ;                // 512K f32

    const int Mrows = cB * cL;   // 2048
    const long SUMSZ = (long)cB * cNCH * cDI * cDS;

    // ---- one-time conversions (weights + enc + padded edges) ----
    cvt(enc,      encb,    (long)cB * cLE * cDM, stream);
    cvt(m_in_w,   w_in_b,  (long)cLAYERS * 2 * cDI * cDM, stream);
    cvt(m_xproj,  w_xp_b,  (long)cLAYERS * 64 * cDI, stream);
    cvt(m_dt_w,   w_dt_b,  (long)cLAYERS * cDI * cDTR, stream);
    cvt(m_out_w,  w_out_b, (long)cLAYERS * cDM * cDI, stream);
    cvt(a_in_w,   w_ain_b, (long)cLAYERS * 3 * cDM * cDM, stream);
    cvt(a_out_w,  w_aout_b,(long)cLAYERS * cDM * cDM, stream);
    cvt(W_out,    w_outf_b,(long)cNM * cDM, stream);
    cvt_pad_kernel<<<(Mrows * 96 + 255) / 256, 256, 0, stream>>>(x, x_pad, Mrows, cNM, 96);
    cvt_pad_kernel<<<(cDM * 96 + 255) / 256, 256, 0, stream>>>(W_in, w_inp_b, cDM, cNM, 96);

    // h = x @ W_in.T + b_in   (K padded 80->96, MFMA)
    bgemm_plain(0, 128, x_pad, w_inp_b, b_in, nullptr, bufH, nullptr,
                Mrows, cDM, 96, 96, 96, cDM, 0, 0, stream);

    for (int i = 0; i < cLAYERS; i++) {
        const float* norm_w = m_norm_w + (long)i * cDM;
        const bf16*  in_w   = w_in_b   + (long)i * 2 * cDI * cDM;
        const float* conv_w = m_conv_w + (long)i * cDI * cKC;
        const float* conv_b = m_conv_b + (long)i * cDI;
        const bf16*  xproj  = w_xp_b   + (long)i * 64 * cDI;
        const bf16*  dt_w   = w_dt_b   + (long)i * cDI * cDTR;
        const float* dt_b   = m_dt_b   + (long)i * cDI;
        const float* Alog   = m_Alog   + (long)i * cDI * cDS;
        const float* Dv     = m_D      + (long)i * cDI;
        const bf16*  out_w  = w_out_b  + (long)i * cDM * cDI;
        const bf16*  ain_w  = w_ain_b  + (long)i * 3 * cDM * cDM;
        const float* ain_b  = a_in_b   + (long)i * 3 * cDM;
        const bf16*  aout_w = w_aout_b + (long)i * cDM * cDM;
        const float* aout_b = a_out_b  + (long)i * cDM;
        const float* ln_w   = a_ln_w   + (long)i * cDM;
        const float* ln_b   = a_ln_b   + (long)i * cDM;

        // ---- mamba ----
        rmsnorm_kernel<<<Mrows, 256, 0, stream>>>(bufH, norm_w, nullptr, bufU, cDM);
        bgemm_plain(0, 128, bufU, in_w, nullptr, nullptr, bufXR, nullptr,
                    Mrows, 2 * cDI, cDM, cDM, cDM, 2 * cDI, 0, 0, stream);
        conv_silu_kernel<<<(cB * cL * cDI) / 256, 256, 0, stream>>>(bufXR, conv_w, conv_b, bufXM, bufXMb);
        bgemm_plain(0, 128, bufXMb, xproj, nullptr, nullptr, bufXDBL, bufXDBLb,
                    Mrows, 64, cDI, cDI, cDI, 64, 64, 0, stream);
        bgemm_plain(1, 128, bufXDBLb, dt_w, dt_b, nullptr, bufDelta, nullptr,
                    Mrows, cDI, cDTR, 64, cDTR, cDI, 0, 0, stream);
        scan_phase1<<<(int)(SUMSZ / 256), 256, 0, stream>>>(bufXM, bufDelta, bufXDBL, Alog, bufAP, bufSE);
        scan_phase2<<<(cB * cDI * cDS) / 256, 256, 0, stream>>>(bufAP, bufSE, bufSI);
        scan_phase3<<<(int)(SUMSZ / 256), 256, 0, stream>>>(bufXM, bufDelta, bufXDBL, Alog, Dv, bufXR, bufSI, bufY);
        bgemm_plain(0, 128, bufY, out_w, nullptr, bufH, bufH, bufHb,
                    Mrows, cDM, cDI, cDI, cDI, cDM, cDM, cDM, stream);

        // ---- cross attention ----
        bgemm_plain(0, 128, bufHb, ain_w, ain_b, nullptr, nullptr, bufQ,
                    Mrows, cDM, cDM, cDM, cDM, 0, cDM, 0, stream);
        // fused K|V projection from enc: N = 1024 (cols 0..511 = K, 512..1023 = V)
        bgemm_plain(0, 128, encb, ain_w + (long)cDM * cDM, ain_b + cDM, nullptr, nullptr, bufKV,
                    Mrows, 2 * cDM, cDM, cDM, cDM, 0, 2 * cDM, 0, stream);
        {
            dim3 g(cLE / 32, cDM / 32, cB);
            transpose_bf16_kernel<<<g, 256, 0, stream>>>(bufKV, bufVT, 2 * cDM, cDM);
        }
        // scores[b,h] = q @ k.T  (f32)
        bgemm(0, 128, bufQ, bufKV, nullptr, nullptr, bufS, nullptr,
              cL, cLE, cHD, cDM, 2 * cDM, cLE, 0, 0,
              cB * cH, cH,
              (long)cL * cDM, (long)cHD,
              (long)cLE * 2 * cDM, (long)cHD,
              (long)cH * cL * cLE, (long)cL * cLE, 0, 0, stream);
        softmax_kernel<<<cB * cH * cL, 256, 0, stream>>>(bufS, 0.08838834764831845f);
        // o[b,:,h] = P @ V  via  P (bf16 in-place rows, pitch 2*LE) x VT ; 64^2 tile
        bgemm(0, 64, (const bf16*)bufS, bufVT, nullptr, nullptr, nullptr, bufO,
              cL, cHD, cLE, 2 * cLE, cLE, 0, cDM, 0,
              cB * cH, cH,
              (long)cH * cL * (2 * cLE), (long)cL * (2 * cLE),
              (long)cDM * cLE, (long)cHD * cLE,
              0, 0, (long)cL * cDM, (long)cHD, stream);
        // pre = o @ aout_w.T + aout_b + h ; h = LN(pre) (f32 + bf16)
        bgemm_plain(0, 128, bufO, aout_w, aout_b, bufH, bufPre, nullptr,
                    Mrows, cDM, cDM, cDM, cDM, cDM, 0, cDM, stream);
        layernorm_kernel<<<Mrows, 256, 0, stream>>>(bufPre, ln_w, ln_b, bufH, bufHb, cDM);
    }

    // final: out = rmsnorm(h) @ W_out.T   (MFMA, 64^2 tile, N=80 edge-clamped)
    rmsnorm_kernel<<<Mrows, 256, 0, stream>>>(bufH, normf_w, nullptr, bufU, cDM);
    bgemm_plain(0, 64, bufU, w_outf_b, nullptr, nullptr, out, nullptr,
                Mrows, cNM, cDM, cDM, cDM, cNM, 0, 0, stream);
}

// Round 6
// 980.680 us; speedup vs baseline: 7.2143x; 1.4904x over previous
//
#include <hip/hip_runtime.h>
#include <hip/hip_bf16.h>
#include <math.h>

typedef __hip_bfloat16 bf16;
typedef __attribute__((ext_vector_type(8))) short short8x;
typedef __attribute__((ext_vector_type(4))) float f32x4;

// ---- problem constants ----
static constexpr int cB   = 2;
static constexpr int cL   = 1024;
static constexpr int cLE  = 1024;
static constexpr int cNM  = 80;
static constexpr int cDM  = 512;
static constexpr int cLAYERS = 4;
static constexpr int cDS  = 16;
static constexpr int cKC  = 4;     // conv taps
static constexpr int cH   = 4;     // heads
static constexpr int cDI  = 1024;  // EXP*DM
static constexpr int cDTR = 32;
static constexpr int cHD  = 128;   // head dim

static constexpr int cNCH = 16;    // scan chunks
static constexpr int cCHL = cL / cNCH;  // 64 steps per chunk

// =====================================================================
// bf16 MFMA GEMM, BMxBN tile, 4 waves (2x2), K-step 32.
//   C = act( A @ W^T + bias ) + addv ; A: M x K bf16 (lda), W: N x K bf16 (ldw)
//   Writes f32 C (if Cf) and/or bf16 C (if Cb). Batched over blockIdx.z.
// =====================================================================
template<int ACT, int BM, int BN>
__global__ __launch_bounds__(256)
void bgemm_kernel(const bf16* __restrict__ A, const bf16* __restrict__ W,
                  const float* __restrict__ bias, const float* __restrict__ addv,
                  float* __restrict__ Cf, bf16* __restrict__ Cb,
                  int M, int N, int Kd, int lda, int ldw, int ldcf, int ldcb, int ldadd,
                  int bdiv, long sA1, long sA2, long sW1, long sW2,
                  long sCf1, long sCf2, long sCb1, long sCb2)
{
    constexpr int RM = BM / 32;            // per-wave 16-row frag repeats
    constexpr int RN = BN / 32;
    const int z = blockIdx.z;
    const int i1 = z / bdiv, i2 = z % bdiv;
    A += i1 * sA1 + i2 * sA2;
    W += i1 * sW1 + i2 * sW2;

    const int bm = blockIdx.y * BM;
    const int bn = blockIdx.x * BN;
    const int tid = threadIdx.x;
    const int lane = tid & 63;
    const int wid = tid >> 6;              // 0..3
    const int wr = wid >> 1, wc = wid & 1; // 2x2 wave grid

    __shared__ bf16 As[BM * 32];
    __shared__ bf16 Bs[BN * 32];

    f32x4 acc[RM][RN] = {};

    const int r_in = lane >> 2;            // 0..15
    const int kb   = (lane & 3) * 8;       // k offset for staging
    const int hi   = lane >> 4;            // 0..3
    const int rc   = lane & 15;

    for (int k0 = 0; k0 < Kd; k0 += 32) {
#pragma unroll
        for (int iss = 0; iss < BM / 64; iss++) {
            const int row = wid * (BM / 4) + iss * 16 + r_in;
            int gm = bm + row; if (gm >= M) gm = M - 1;
            const bf16* ga = A + (long)gm * lda + k0 + kb;
            __builtin_amdgcn_global_load_lds(
                (const __attribute__((address_space(1))) void*)ga,
                (__attribute__((address_space(3))) void*)(As + (wid * (BM / 4) + iss * 16) * 32),
                16, 0, 0);
        }
#pragma unroll
        for (int iss = 0; iss < BN / 64; iss++) {
            const int row = wid * (BN / 4) + iss * 16 + r_in;
            int gn = bn + row; if (gn >= N) gn = N - 1;
            const bf16* gb = W + (long)gn * ldw + k0 + kb;
            __builtin_amdgcn_global_load_lds(
                (const __attribute__((address_space(1))) void*)gb,
                (__attribute__((address_space(3))) void*)(Bs + (wid * (BN / 4) + iss * 16) * 32),
                16, 0, 0);
        }
        asm volatile("s_waitcnt vmcnt(0)" ::: "memory");
        __syncthreads();

        short8x af[RM], bfv[RN];
#pragma unroll
        for (int i = 0; i < RM; i++)
            af[i] = *(const short8x*)(As + (wr * (BM / 2) + i * 16 + rc) * 32 + hi * 8);
#pragma unroll
        for (int j = 0; j < RN; j++)
            bfv[j] = *(const short8x*)(Bs + (wc * (BN / 2) + j * 16 + rc) * 32 + hi * 8);
#pragma unroll
        for (int i = 0; i < RM; i++)
#pragma unroll
            for (int j = 0; j < RN; j++)
                acc[i][j] = __builtin_amdgcn_mfma_f32_16x16x32_bf16(af[i], bfv[j], acc[i][j], 0, 0, 0);
        __syncthreads();
    }

    // epilogue: C/D frag mapping col=lane&15, row=(lane>>4)*4+r  [m89-verified]
    const long cfo = i1 * sCf1 + i2 * sCf2;
    const long cbo = i1 * sCb1 + i2 * sCb2;
#pragma unroll
    for (int i = 0; i < RM; i++) {
#pragma unroll
        for (int r = 0; r < 4; r++) {
            const int gm = bm + wr * (BM / 2) + i * 16 + hi * 4 + r;
            if (gm >= M) continue;
#pragma unroll
            for (int j = 0; j < RN; j++) {
                const int gn = bn + wc * (BN / 2) + j * 16 + rc;
                if (gn >= N) continue;
                float v = acc[i][j][r];
                if (bias) v += bias[gn];
                if (ACT == 1) v = (v > 20.f) ? v : log1pf(__expf(v));
                if (addv) v += addv[cfo + (long)gm * ldadd + gn];
                if (Cf) Cf[cfo + (long)gm * ldcf + gn] = v;
                if (Cb) Cb[cbo + (long)gm * ldcb + gn] = __float2bfloat16(v);
            }
        }
    }
}

static inline void bgemm(int ACT, int BM, int BN, const bf16* A, const bf16* W, const float* bias,
                         const float* addv, float* Cf, bf16* Cb,
                         int M, int N, int Kd, int lda, int ldw, int ldcf, int ldcb, int ldadd,
                         int nz, int bdiv, long sA1, long sA2, long sW1, long sW2,
                         long sCf1, long sCf2, long sCb1, long sCb2, hipStream_t s)
{
    dim3 g((N + BN - 1) / BN, (M + BM - 1) / BM, nz), b(256);
#define BG_ARGS A, W, bias, addv, Cf, Cb, M, N, Kd, lda, ldw, ldcf, ldcb, ldadd, \
                bdiv, sA1, sA2, sW1, sW2, sCf1, sCf2, sCb1, sCb2
    if (BM == 128) {
        if (ACT == 1) bgemm_kernel<1, 128, 128><<<g, b, 0, s>>>(BG_ARGS);
        else          bgemm_kernel<0, 128, 128><<<g, b, 0, s>>>(BG_ARGS);
    } else if (BN == 128) {
        if (ACT == 1) bgemm_kernel<1, 64, 128><<<g, b, 0, s>>>(BG_ARGS);
        else          bgemm_kernel<0, 64, 128><<<g, b, 0, s>>>(BG_ARGS);
    } else {
        bgemm_kernel<0, 64, 64><<<g, b, 0, s>>>(BG_ARGS);
    }
#undef BG_ARGS
}

static inline void bgemm_plain(int ACT, int BM, int BN, const bf16* A, const bf16* W,
                               const float* bias, const float* addv, float* Cf, bf16* Cb,
                               int M, int N, int Kd, int lda, int ldw, int ldcf, int ldcb,
                               int ldadd, hipStream_t s)
{
    bgemm(ACT, BM, BN, A, W, bias, addv, Cf, Cb, M, N, Kd, lda, ldw, ldcf, ldcb, ldadd,
          1, 1, 0, 0, 0, 0, 0, 0, 0, 0, s);
}

// =====================================================================
// split-K partial reduce:  out = sum_s parts[s]  (f32 + bf16 outputs)
// =====================================================================
__global__ void splitk_reduce_kernel(const float* __restrict__ parts, float* __restrict__ outf,
                                     bf16* __restrict__ outb, int n4, int sliceN4, int S)
{
    const int i = blockIdx.x * 256 + threadIdx.x;
    if (i >= n4) return;
    float4 a = ((const float4*)parts)[i];
    for (int s2 = 1; s2 < S; s2++) {
        float4 b2 = ((const float4*)parts)[i + (long)s2 * sliceN4];
        a.x += b2.x; a.y += b2.y; a.z += b2.z; a.w += b2.w;
    }
    ((float4*)outf)[i] = a;
    bf16 b0 = __float2bfloat16(a.x), b1 = __float2bfloat16(a.y);
    bf16 b2 = __float2bfloat16(a.z), b3 = __float2bfloat16(a.w);
    short4 pk = { *(short*)&b0, *(short*)&b1, *(short*)&b2, *(short*)&b3 };
    ((short4*)outb)[i] = pk;
}

// =====================================================================
// f32 -> bf16 flat convert
// =====================================================================
__global__ void f32_to_bf16_kernel(const float* __restrict__ in, bf16* __restrict__ out, long n)
{
    long i = ((long)blockIdx.x * 256 + threadIdx.x) * 4;
    if (i + 3 < n) {
        float4 v = *(const float4*)(in + i);
        out[i]     = __float2bfloat16(v.x);
        out[i + 1] = __float2bfloat16(v.y);
        out[i + 2] = __float2bfloat16(v.z);
        out[i + 3] = __float2bfloat16(v.w);
    } else {
        for (; i < n; i++) out[i] = __float2bfloat16(in[i]);
    }
}
static inline void cvt(const float* in, bf16* out, long n, hipStream_t s)
{
    int blocks = (int)((n / 4 + 255) / 256);
    f32_to_bf16_kernel<<<blocks, 256, 0, s>>>(in, out, n);
}

// f32 (rows x kin) -> bf16 (rows x kout), zero-padded beyond kin
__global__ void cvt_pad_kernel(const float* __restrict__ in, bf16* __restrict__ out,
                               int rows, int kin, int kout)
{
    const int idx = blockIdx.x * 256 + threadIdx.x;
    if (idx >= rows * kout) return;
    const int r = idx / kout, k = idx - r * kout;
    out[idx] = __float2bfloat16(k < kin ? in[(long)r * kin + k] : 0.f);
}

// =====================================================================
// bf16 transpose per batch:  in rows (b*LE+le) x ldin, cols [col0, col0+DM)
//   -> out b: DM x LE
// =====================================================================
__global__ void transpose_bf16_kernel(const bf16* __restrict__ in, bf16* __restrict__ out,
                                      int ldin, int col0)
{
    __shared__ bf16 t[32][33];
    const int b = blockIdx.z;
    const int le0 = blockIdx.x * 32, d0 = blockIdx.y * 32;
    const int tid = threadIdx.x;
    const int c = tid & 31, r = tid >> 5;
    for (int i = r; i < 32; i += 8)
        t[i][c] = in[((long)b * cLE + le0 + i) * ldin + col0 + d0 + c];
    __syncthreads();
    for (int i = r; i < 32; i += 8)
        out[((long)b * cDM + d0 + i) * cLE + le0 + c] = t[c][i];
}

// =====================================================================
// RMSNorm per row (optional f32 and bf16 outputs)
// =====================================================================
__global__ void rmsnorm_kernel(const float* __restrict__ x, const float* __restrict__ w,
                               float* __restrict__ outf, bf16* __restrict__ outb, int Dm)
{
    const int row = blockIdx.x;
    const float* xr = x + (long)row * Dm;
    float s = 0.f;
    for (int i = threadIdx.x; i < Dm; i += 256) { float v = xr[i]; s += v * v; }
    __shared__ float red[5];
    const int lane = threadIdx.x & 63, wv = threadIdx.x >> 6;
#pragma unroll
    for (int off = 1; off < 64; off <<= 1) s += __shfl_xor(s, off);
    if (lane == 0) red[wv] = s;
    __syncthreads();
    if (threadIdx.x == 0) {
        float t = red[0] + red[1] + red[2] + red[3];
        red[4] = rsqrtf(t / Dm + 1e-5f);
    }
    __syncthreads();
    const float scale = red[4];
    for (int i = threadIdx.x; i < Dm; i += 256) {
        float v = xr[i] * scale * w[i];
        if (outf) outf[(long)row * Dm + i] = v;
        if (outb) outb[(long)row * Dm + i] = __float2bfloat16(v);
    }
}

// =====================================================================
// LayerNorm per row -> f32 + bf16 outputs
// =====================================================================
__global__ void layernorm_kernel(const float* __restrict__ x, const float* __restrict__ w,
                                 const float* __restrict__ b, float* __restrict__ outf,
                                 bf16* __restrict__ outb, int Dm)
{
    const int row = blockIdx.x;
    const float* xr = x + (long)row * Dm;
    float s = 0.f, sq = 0.f;
    for (int i = threadIdx.x; i < Dm; i += 256) { float v = xr[i]; s += v; sq += v * v; }
    __shared__ float red[8];
    __shared__ float mv[2];
    const int lane = threadIdx.x & 63, wv = threadIdx.x >> 6;
#pragma unroll
    for (int off = 1; off < 64; off <<= 1) { s += __shfl_xor(s, off); sq += __shfl_xor(sq, off); }
    if (lane == 0) { red[wv] = s; red[4 + wv] = sq; }
    __syncthreads();
    if (threadIdx.x == 0) {
        float ts = red[0] + red[1] + red[2] + red[3];
        float tq = red[4] + red[5] + red[6] + red[7];
        float m = ts / Dm;
        float var = tq / Dm - m * m;
        mv[0] = m;
        mv[1] = rsqrtf(var + 1e-5f);
    }
    __syncthreads();
    const float m = mv[0], rs = mv[1];
    for (int i = threadIdx.x; i < Dm; i += 256) {
        float v = (xr[i] - m) * rs * w[i] + b[i];
        outf[(long)row * Dm + i] = v;
        outb[(long)row * Dm + i] = __float2bfloat16(v);
    }
}

// =====================================================================
// Causal depthwise conv (K=4) + bias + SiLU -> xm f32 + bf16
// =====================================================================
__global__ void conv_silu_kernel(const float* __restrict__ xr, const float* __restrict__ w,
                                 const float* __restrict__ bias, float* __restrict__ xm,
                                 bf16* __restrict__ xmb)
{
    const int idx = blockIdx.x * 256 + threadIdx.x;
    if (idx >= cB * cL * cDI) return;
    const int d = idx & (cDI - 1);
    const int l = (idx >> 10) & (cL - 1);
    const int b = idx >> 20;
    float s = bias[d];
#pragma unroll
    for (int j = 0; j < cKC; j++) {
        const int ls = l + j - (cKC - 1);
        if (ls >= 0) s += w[d * cKC + j] * xr[((long)(b * cL + ls)) * (2 * cDI) + d];
    }
    s = s / (1.f + __expf(-s));
    xm[(long)idx] = s;
    xmb[(long)idx] = __float2bfloat16(s);
}

// =====================================================================
// Chunk-parallel selective scan, 4 states (n) per thread.
// Memory layout of aprod/send/sinit unchanged: idx = ((b*NCH+ch)*DI+d)*DS+n
// Thread mapping: idx4 = (((b*NCH+ch)*DI+d)*4+ng), n = 4*ng..4*ng+3
// =====================================================================
__global__ void scan_phase1(const float* __restrict__ xm, const float* __restrict__ delta,
                            const float* __restrict__ xdbl, const float* __restrict__ Alog,
                            float* __restrict__ aprod_out, float* __restrict__ send_out)
{
    const int idx4 = blockIdx.x * 256 + threadIdx.x;   // cB*cNCH*cDI*4
    const int ng = idx4 & 3;
    const int d  = (idx4 >> 2) & (cDI - 1);
    const int ch = (idx4 >> 12) & (cNCH - 1);
    const int b  = idx4 >> 16;
    const float4 Al = *(const float4*)(Alog + d * cDS + 4 * ng);
    const float A0 = -__expf(Al.x), A1 = -__expf(Al.y), A2 = -__expf(Al.z), A3 = -__expf(Al.w);
    float s0 = 0.f, s1 = 0.f, s2 = 0.f, s3 = 0.f;
    float p0 = 1.f, p1 = 1.f, p2 = 1.f, p3 = 1.f;
    const int l0 = ch * cCHL;
    const float* dp = delta + (long)(b * cL + l0) * cDI + d;
    const float* up = xm    + (long)(b * cL + l0) * cDI + d;
    const float* xb = xdbl  + (long)(b * cL + l0) * 64 + cDTR + 4 * ng;
    for (int t = 0; t < cCHL; t++) {
        const float dl = dp[(long)t * cDI];
        const float du = dl * up[(long)t * cDI];
        const float4 Bv = *(const float4*)(xb + (long)t * 64);
        const float a0 = __expf(dl * A0), a1 = __expf(dl * A1);
        const float a2 = __expf(dl * A2), a3 = __expf(dl * A3);
        s0 = a0 * s0 + du * Bv.x; p0 *= a0;
        s1 = a1 * s1 + du * Bv.y; p1 *= a1;
        s2 = a2 * s2 + du * Bv.z; p2 *= a2;
        s3 = a3 * s3 + du * Bv.w; p3 *= a3;
    }
    const long base4 = (((long)(b * cNCH + ch) * cDI + d) * cDS) + 4 * ng;
    float4 pv = { p0, p1, p2, p3 };
    float4 sv = { s0, s1, s2, s3 };
    *(float4*)(aprod_out + base4) = pv;
    *(float4*)(send_out + base4)  = sv;
}

__global__ void scan_phase2(const float* __restrict__ aprod, const float* __restrict__ send,
                            float* __restrict__ sinit)
{
    const int j = blockIdx.x * 256 + threadIdx.x;
    const int n = j & (cDS - 1);
    const int d = (j >> 4) & (cDI - 1);
    const int b = j >> 14;
    float s = 0.f;
#pragma unroll
    for (int c = 0; c < cNCH; c++) {
        const long off = (((long)(b * cNCH + c) * cDI + d) * cDS) + n;
        sinit[off] = s;
        s = aprod[off] * s + send[off];
    }
}

__global__ void scan_phase3(const float* __restrict__ xm, const float* __restrict__ delta,
                            const float* __restrict__ xdbl, const float* __restrict__ Alog,
                            const float* __restrict__ Dv, const float* __restrict__ xr,
                            const float* __restrict__ sinit, bf16* __restrict__ y)
{
    const int idx4 = blockIdx.x * 256 + threadIdx.x;   // cB*cNCH*cDI*4
    const int ng = idx4 & 3;
    const int d  = (idx4 >> 2) & (cDI - 1);
    const int ch = (idx4 >> 12) & (cNCH - 1);
    const int b  = idx4 >> 16;
    const float4 Al = *(const float4*)(Alog + d * cDS + 4 * ng);
    const float A0 = -__expf(Al.x), A1 = -__expf(Al.y), A2 = -__expf(Al.z), A3 = -__expf(Al.w);
    const float Dval = Dv[d];
    const long base4 = (((long)(b * cNCH + ch) * cDI + d) * cDS) + 4 * ng;
    float4 st = *(const float4*)(sinit + base4);
    float s0 = st.x, s1 = st.y, s2 = st.z, s3 = st.w;
    const int l0 = ch * cCHL;
    const float* dp = delta + (long)(b * cL + l0) * cDI + d;
    const float* up = xm    + (long)(b * cL + l0) * cDI + d;
    const float* xb = xdbl  + (long)(b * cL + l0) * 64 + cDTR + 4 * ng;
    const float* xc = xb + cDS;
    const float* rp = xr + (long)(b * cL + l0) * (2 * cDI) + cDI + d;
    bf16* yp = y + (long)(b * cL + l0) * cDI + d;
    for (int t = 0; t < cCHL; t++) {
        const float dl = dp[(long)t * cDI];
        const float u  = up[(long)t * cDI];
        const float du = dl * u;
        const float4 Bv = *(const float4*)(xb + (long)t * 64);
        const float4 Cv = *(const float4*)(xc + (long)t * 64);
        const float a0 = __expf(dl * A0), a1 = __expf(dl * A1);
        const float a2 = __expf(dl * A2), a3 = __expf(dl * A3);
        s0 = a0 * s0 + du * Bv.x;
        s1 = a1 * s1 + du * Bv.y;
        s2 = a2 * s2 + du * Bv.z;
        s3 = a3 * s3 + du * Bv.w;
        float c = s0 * Cv.x;
        c = fmaf(s1, Cv.y, c);
        c = fmaf(s2, Cv.z, c);
        c = fmaf(s3, Cv.w, c);
        c += __shfl_xor(c, 1);
        c += __shfl_xor(c, 2);
        if (ng == 0) {
            const float res = rp[(long)t * 2 * cDI];
            const float sig = 1.f / (1.f + __expf(-res));
            yp[(long)t * cDI] = __float2bfloat16((c + u * Dval) * (res * sig));
        }
    }
}

// =====================================================================
// Row softmax (1024 cols, 256 threads, one float4/thread); reads f32 row,
// writes bf16 IN PLACE over the start of the same row (pitch stays 1024 f32).
// =====================================================================
__global__ void softmax_kernel(float* __restrict__ s, float scale)
{
    const long row = blockIdx.x;
    float* p = s + row * 1024;
    const int t = threadIdx.x;
    float4 v = ((const float4*)p)[t];
    v.x *= scale; v.y *= scale; v.z *= scale; v.w *= scale;
    float mx = fmaxf(fmaxf(v.x, v.y), fmaxf(v.z, v.w));
    __shared__ float red[8];
    const int lane = t & 63, wv = t >> 6;
#pragma unroll
    for (int off = 1; off < 64; off <<= 1) mx = fmaxf(mx, __shfl_xor(mx, off));
    if (lane == 0) red[wv] = mx;
    __syncthreads();
    mx = fmaxf(fmaxf(red[0], red[1]), fmaxf(red[2], red[3]));
    v.x = __expf(v.x - mx); v.y = __expf(v.y - mx);
    v.z = __expf(v.z - mx); v.w = __expf(v.w - mx);
    float sum = (v.x + v.y) + (v.z + v.w);
#pragma unroll
    for (int off = 1; off < 64; off <<= 1) sum += __shfl_xor(sum, off);
    if (lane == 0) red[4 + wv] = sum;
    __syncthreads();
    const float inv = 1.f / (red[4] + red[5] + red[6] + red[7]);
    bf16 b0 = __float2bfloat16(v.x * inv), b1 = __float2bfloat16(v.y * inv);
    bf16 b2 = __float2bfloat16(v.z * inv), b3 = __float2bfloat16(v.w * inv);
    short4 pk = { *(short*)&b0, *(short*)&b1, *(short*)&b2, *(short*)&b3 };
    ((short4*)p)[t] = pk;
}

// =====================================================================
extern "C" void kernel_launch(void* const* d_in, const int* in_sizes, int n_in,
                              void* d_out, int out_size, void* d_ws, size_t ws_size,
                              hipStream_t stream)
{
    const float* x       = (const float*)d_in[0];
    const float* enc     = (const float*)d_in[1];
    const float* W_in    = (const float*)d_in[2];
    const float* b_in    = (const float*)d_in[3];
    const float* m_norm_w= (const float*)d_in[4];
    const float* m_in_w  = (const float*)d_in[5];
    const float* m_conv_w= (const float*)d_in[6];
    const float* m_conv_b= (const float*)d_in[7];
    const float* m_xproj = (const float*)d_in[8];
    const float* m_dt_w  = (const float*)d_in[9];
    const float* m_dt_b  = (const float*)d_in[10];
    const float* m_Alog  = (const float*)d_in[11];
    const float* m_D     = (const float*)d_in[12];
    const float* m_out_w = (const float*)d_in[13];
    const float* a_in_w  = (const float*)d_in[14];
    const float* a_in_b  = (const float*)d_in[15];
    const float* a_out_w = (const float*)d_in[16];
    const float* a_out_b = (const float*)d_in[17];
    const float* a_ln_w  = (const float*)d_in[18];
    const float* a_ln_b  = (const float*)d_in[19];
    const float* normf_w = (const float*)d_in[20];
    const float* W_out   = (const float*)d_in[21];
    float* out = (float*)d_out;

    float* ws = (float*)d_ws;
    long off = 0;
    auto allocf = [&](long n) { float* p = ws + off; off += n; return p; };

    const long M1 = 1 << 20;
    float* bufH    = allocf(M1);
    float* bufPre  = allocf(M1);         // also xproj split-K partials / aprod+send
    float* bufXR   = allocf(4 * M1);     // S (8M f32) overlays XR/XM/Delta during attn
    float* bufXM   = allocf(2 * M1);
    float* bufDelta= allocf(2 * M1);
    float* bufXDBL = allocf(M1 / 8);
    bf16* bufU    = (bf16*)allocf(M1 / 2);      // 2048x512 bf16
    bf16* bufHb   = (bf16*)allocf(M1 / 2);
    bf16* bufXMb  = (bf16*)allocf(M1);          // 2048x1024 bf16
    bf16* bufXDBLb= (bf16*)allocf(M1 / 16);
    bf16* bufY    = (bf16*)allocf(M1);          // 2048x1024 bf16
    bf16* bufQ    = (bf16*)allocf(M1 / 2);      // also sinit (f32) during scan
    bf16* bufKV   = (bf16*)allocf(M1);          // 2048x1024 bf16: [K | V]
    bf16* bufVT   = (bf16*)allocf(M1 / 2);
    bf16* bufO    = (bf16*)allocf(M1 / 2);
    bf16* encb    = (bf16*)allocf(M1 / 2);
    bf16* w_in_b  = (bf16*)allocf(2 * M1);      // mamba in_w (4 layers)
    bf16* w_xp_b  = (bf16*)allocf(M1 / 8);
    bf16* w_dt_b  = (bf16*)allocf(M1 / 16);
    bf16* w_out_b = (bf16*)allocf(M1);
    bf16* w_ain_b = (bf16*)allocf(3 * M1 / 2);
    bf16* w_aout_b= (bf16*)allocf(M1 / 2);
    bf16* x_pad   = (bf16*)allocf(2048L * 96 / 2);   // x zero-padded K=96
    bf16* w_inp_b = (bf16*)allocf(512L * 96 / 2);    // W_in zero-padded K=96
    bf16* w_outf_b= (bf16*)allocf(80L * 512 / 2);    // W_out bf16

    float* bufS   = bufXR;                       // 8M f32 scores
    float* bufAP  = bufPre;                      // 512K floats
    float* bufSE  = bufPre + 524288;             // 512K floats
    float* bufSI  = (float*)bufQ;                // 512K f32

    const int Mrows = cB * cL;   // 2048
    const long SUMSZ4 = (long)cB * cNCH * cDI * 4;   // scan threads (4n each)

    // ---- one-time conversions (weights + enc + padded edges) ----
    cvt(enc,      encb,    (long)cB * cLE * cDM, stream);
    cvt(m_in_w,   w_in_b,  (long)cLAYERS * 2 * cDI * cDM, stream);
    cvt(m_xproj,  w_xp_b,  (long)cLAYERS * 64 * cDI, stream);
    cvt(m_dt_w,   w_dt_b,  (long)cLAYERS * cDI * cDTR, stream);
    cvt(m_out_w,  w_out_b, (long)cLAYERS * cDM * cDI, stream);
    cvt(a_in_w,   w_ain_b, (long)cLAYERS * 3 * cDM * cDM, stream);
    cvt(a_out_w,  w_aout_b,(long)cLAYERS * cDM * cDM, stream);
    cvt(W_out,    w_outf_b,(long)cNM * cDM, stream);
    cvt_pad_kernel<<<(Mrows * 96 + 255) / 256, 256, 0, stream>>>(x, x_pad, Mrows, cNM, 96);
    cvt_pad_kernel<<<(cDM * 96 + 255) / 256, 256, 0, stream>>>(W_in, w_inp_b, cDM, cNM, 96);

    // h = x @ W_in.T + b_in   (K padded 80->96, MFMA 64^2)
    bgemm_plain(0, 64, 64, x_pad, w_inp_b, b_in, nullptr, bufH, nullptr,
                Mrows, cDM, 96, 96, 96, cDM, 0, 0, stream);

    for (int i = 0; i < cLAYERS; i++) {
        const float* norm_w = m_norm_w + (long)i * cDM;
        const bf16*  in_w   = w_in_b   + (long)i * 2 * cDI * cDM;
        const float* conv_w = m_conv_w + (long)i * cDI * cKC;
        const float* conv_b = m_conv_b + (long)i * cDI;
        const bf16*  xproj  = w_xp_b   + (long)i * 64 * cDI;
        const bf16*  dt_w   = w_dt_b   + (long)i * cDI * cDTR;
        const float* dt_b   = m_dt_b   + (long)i * cDI;
        const float* Alog   = m_Alog   + (long)i * cDI * cDS;
        const float* Dv     = m_D      + (long)i * cDI;
        const bf16*  out_w  = w_out_b  + (long)i * cDM * cDI;
        const bf16*  ain_w  = w_ain_b  + (long)i * 3 * cDM * cDM;
        const float* ain_b  = a_in_b   + (long)i * 3 * cDM;
        const bf16*  aout_w = w_aout_b + (long)i * cDM * cDM;
        const float* aout_b = a_out_b  + (long)i * cDM;
        const float* ln_w   = a_ln_w   + (long)i * cDM;
        const float* ln_b   = a_ln_b   + (long)i * cDM;

        // ---- mamba ----
        rmsnorm_kernel<<<Mrows, 256, 0, stream>>>(bufH, norm_w, nullptr, bufU, cDM);
        // xr = u @ in_w.T  (64x128 tiles -> 512 blocks)
        bgemm_plain(0, 64, 128, bufU, in_w, nullptr, nullptr, bufXR, nullptr,
                    Mrows, 2 * cDI, cDM, cDM, cDM, 2 * cDI, 0, 0, stream);
        conv_silu_kernel<<<(cB * cL * cDI) / 256, 256, 0, stream>>>(bufXR, conv_w, conv_b, bufXM, bufXMb);
        // x_dbl = xm @ xproj.T : split-K x8 (N=64 too narrow otherwise)
        bgemm(0, 64, 64, bufXMb, xproj, nullptr, nullptr, bufPre, nullptr,
              Mrows, 64, cDI / 8, cDI, cDI, 64, 0, 0,
              8, 1, 128, 0, 128, 0, (long)Mrows * 64, 0, 0, 0, stream);
        splitk_reduce_kernel<<<(Mrows * 64 / 4 + 255) / 256, 256, 0, stream>>>(
            bufPre, bufXDBL, bufXDBLb, Mrows * 64 / 4, Mrows * 64 / 4, 8);
        // delta = softplus(dlt @ dt_w.T + dt_b)
        bgemm_plain(1, 64, 128, bufXDBLb, dt_w, dt_b, nullptr, bufDelta, nullptr,
                    Mrows, cDI, cDTR, 64, cDTR, cDI, 0, 0, stream);
        // chunk-parallel scan
        scan_phase1<<<(int)(SUMSZ4 / 256), 256, 0, stream>>>(bufXM, bufDelta, bufXDBL, Alog, bufAP, bufSE);
        scan_phase2<<<(cB * cDI * cDS) / 256, 256, 0, stream>>>(bufAP, bufSE, bufSI);
        scan_phase3<<<(int)(SUMSZ4 / 256), 256, 0, stream>>>(bufXM, bufDelta, bufXDBL, Alog, Dv, bufXR, bufSI, bufY);
        // h += y @ out_w.T
        bgemm_plain(0, 64, 64, bufY, out_w, nullptr, bufH, bufH, bufHb,
                    Mrows, cDM, cDI, cDI, cDI, cDM, cDM, cDM, stream);

        // ---- cross attention ----
        bgemm_plain(0, 64, 64, bufHb, ain_w, ain_b, nullptr, nullptr, bufQ,
                    Mrows, cDM, cDM, cDM, cDM, 0, cDM, 0, stream);
        // fused K|V projection from enc: N = 1024 (cols 0..511 = K, 512..1023 = V)
        bgemm_plain(0, 64, 128, encb, ain_w + (long)cDM * cDM, ain_b + cDM, nullptr, nullptr, bufKV,
                    Mrows, 2 * cDM, cDM, cDM, cDM, 0, 2 * cDM, 0, stream);
        {
            dim3 g(cLE / 32, cDM / 32, cB);
            transpose_bf16_kernel<<<g, 256, 0, stream>>>(bufKV, bufVT, 2 * cDM, cDM);
        }
        // scores[b,h] = q @ k.T  (f32)
        bgemm(0, 128, 128, bufQ, bufKV, nullptr, nullptr, bufS, nullptr,
              cL, cLE, cHD, cDM, 2 * cDM, cLE, 0, 0,
              cB * cH, cH,
              (long)cL * cDM, (long)cHD,
              (long)cLE * 2 * cDM, (long)cHD,
              (long)cH * cL * cLE, (long)cL * cLE, 0, 0, stream);
        softmax_kernel<<<cB * cH * cL, 256, 0, stream>>>(bufS, 0.08838834764831845f);
        // o[b,:,h] = P @ V  via  P (bf16 in-place rows, pitch 2*LE) x VT ; 64^2 tile
        bgemm(0, 64, 64, (const bf16*)bufS, bufVT, nullptr, nullptr, nullptr, bufO,
              cL, cHD, cLE, 2 * cLE, cLE, 0, cDM, 0,
              cB * cH, cH,
              (long)cH * cL * (2 * cLE), (long)cL * (2 * cLE),
              (long)cDM * cLE, (long)cHD * cLE,
              0, 0, (long)cL * cDM, (long)cHD, stream);
        // pre = o @ aout_w.T + aout_b + h ; h = LN(pre)
        bgemm_plain(0, 64, 64, bufO, aout_w, aout_b, bufH, bufPre, nullptr,
                    Mrows, cDM, cDM, cDM, cDM, cDM, 0, cDM, stream);
        layernorm_kernel<<<Mrows, 256, 0, stream>>>(bufPre, ln_w, ln_b, bufH, bufHb, cDM);
    }

    // final: out = rmsnorm(h) @ W_out.T   (MFMA, 64^2 tile, N=80 edge-clamped)
    rmsnorm_kernel<<<Mrows, 256, 0, stream>>>(bufH, normf_w, nullptr, bufU, cDM);
    bgemm_plain(0, 64, 64, bufU, w_outf_b, nullptr, nullptr, out, nullptr,
                Mrows, cNM, cDM, cDM, cDM, cNM, 0, 0, stream);
}

// Round 7
// 917.596 us; speedup vs baseline: 7.7102x; 1.0687x over previous
//
#include <hip/hip_runtime.h>
#include <hip/hip_bf16.h>
#include <math.h>

typedef __hip_bfloat16 bf16;
typedef __attribute__((ext_vector_type(8))) short short8x;
typedef __attribute__((ext_vector_type(4))) float f32x4;

// ---- problem constants ----
static constexpr int cB   = 2;
static constexpr int cL   = 1024;
static constexpr int cLE  = 1024;
static constexpr int cNM  = 80;
static constexpr int cDM  = 512;
static constexpr int cLAYERS = 4;
static constexpr int cDS  = 16;
static constexpr int cKC  = 4;     // conv taps
static constexpr int cH   = 4;     // heads
static constexpr int cDI  = 1024;  // EXP*DM
static constexpr int cDTR = 32;
static constexpr int cHD  = 128;   // head dim

static constexpr int cNCH = 32;    // scan chunks (power of 2; shifts below assume 32)
static constexpr int cCHL = cL / cNCH;  // 32 steps per chunk

// =====================================================================
// bf16 MFMA GEMM, BMxBN tile, 4 waves (2x2), K-step 32.
//   C = act( A @ W^T + bias ) + addv ; A: M x K bf16 (lda), W: N x K bf16 (ldw)
//   Writes f32 C (if Cf) and/or bf16 C (if Cb). Batched over blockIdx.z.
// =====================================================================
template<int ACT, int BM, int BN>
__global__ __launch_bounds__(256)
void bgemm_kernel(const bf16* __restrict__ A, const bf16* __restrict__ W,
                  const float* __restrict__ bias, const float* __restrict__ addv,
                  float* __restrict__ Cf, bf16* __restrict__ Cb,
                  int M, int N, int Kd, int lda, int ldw, int ldcf, int ldcb, int ldadd,
                  int bdiv, long sA1, long sA2, long sW1, long sW2,
                  long sCf1, long sCf2, long sCb1, long sCb2)
{
    constexpr int RM = BM / 32;            // per-wave 16-row frag repeats
    constexpr int RN = BN / 32;
    const int z = blockIdx.z;
    const int i1 = z / bdiv, i2 = z % bdiv;
    A += i1 * sA1 + i2 * sA2;
    W += i1 * sW1 + i2 * sW2;

    const int bm = blockIdx.y * BM;
    const int bn = blockIdx.x * BN;
    const int tid = threadIdx.x;
    const int lane = tid & 63;
    const int wid = tid >> 6;              // 0..3
    const int wr = wid >> 1, wc = wid & 1; // 2x2 wave grid

    __shared__ bf16 As[BM * 32];
    __shared__ bf16 Bs[BN * 32];

    f32x4 acc[RM][RN] = {};

    const int r_in = lane >> 2;            // 0..15
    const int kb   = (lane & 3) * 8;       // k offset for staging
    const int hi   = lane >> 4;            // 0..3
    const int rc   = lane & 15;

    for (int k0 = 0; k0 < Kd; k0 += 32) {
#pragma unroll
        for (int iss = 0; iss < BM / 64; iss++) {
            const int row = wid * (BM / 4) + iss * 16 + r_in;
            int gm = bm + row; if (gm >= M) gm = M - 1;
            const bf16* ga = A + (long)gm * lda + k0 + kb;
            __builtin_amdgcn_global_load_lds(
                (const __attribute__((address_space(1))) void*)ga,
                (__attribute__((address_space(3))) void*)(As + (wid * (BM / 4) + iss * 16) * 32),
                16, 0, 0);
        }
#pragma unroll
        for (int iss = 0; iss < BN / 64; iss++) {
            const int row = wid * (BN / 4) + iss * 16 + r_in;
            int gn = bn + row; if (gn >= N) gn = N - 1;
            const bf16* gb = W + (long)gn * ldw + k0 + kb;
            __builtin_amdgcn_global_load_lds(
                (const __attribute__((address_space(1))) void*)gb,
                (__attribute__((address_space(3))) void*)(Bs + (wid * (BN / 4) + iss * 16) * 32),
                16, 0, 0);
        }
        asm volatile("s_waitcnt vmcnt(0)" ::: "memory");
        __syncthreads();

        short8x af[RM], bfv[RN];
#pragma unroll
        for (int i = 0; i < RM; i++)
            af[i] = *(const short8x*)(As + (wr * (BM / 2) + i * 16 + rc) * 32 + hi * 8);
#pragma unroll
        for (int j = 0; j < RN; j++)
            bfv[j] = *(const short8x*)(Bs + (wc * (BN / 2) + j * 16 + rc) * 32 + hi * 8);
#pragma unroll
        for (int i = 0; i < RM; i++)
#pragma unroll
            for (int j = 0; j < RN; j++)
                acc[i][j] = __builtin_amdgcn_mfma_f32_16x16x32_bf16(af[i], bfv[j], acc[i][j], 0, 0, 0);
        __syncthreads();
    }

    // epilogue: C/D frag mapping col=lane&15, row=(lane>>4)*4+r  [m89-verified]
    const long cfo = i1 * sCf1 + i2 * sCf2;
    const long cbo = i1 * sCb1 + i2 * sCb2;
#pragma unroll
    for (int i = 0; i < RM; i++) {
#pragma unroll
        for (int r = 0; r < 4; r++) {
            const int gm = bm + wr * (BM / 2) + i * 16 + hi * 4 + r;
            if (gm >= M) continue;
#pragma unroll
            for (int j = 0; j < RN; j++) {
                const int gn = bn + wc * (BN / 2) + j * 16 + rc;
                if (gn >= N) continue;
                float v = acc[i][j][r];
                if (bias) v += bias[gn];
                if (ACT == 1) v = (v > 20.f) ? v : log1pf(__expf(v));
                if (addv) v += addv[cfo + (long)gm * ldadd + gn];
                if (Cf) Cf[cfo + (long)gm * ldcf + gn] = v;
                if (Cb) Cb[cbo + (long)gm * ldcb + gn] = __float2bfloat16(v);
            }
        }
    }
}

static inline void bgemm(int ACT, int BM, int BN, const bf16* A, const bf16* W, const float* bias,
                         const float* addv, float* Cf, bf16* Cb,
                         int M, int N, int Kd, int lda, int ldw, int ldcf, int ldcb, int ldadd,
                         int nz, int bdiv, long sA1, long sA2, long sW1, long sW2,
                         long sCf1, long sCf2, long sCb1, long sCb2, hipStream_t s)
{
    dim3 g((N + BN - 1) / BN, (M + BM - 1) / BM, nz), b(256);
#define BG_ARGS A, W, bias, addv, Cf, Cb, M, N, Kd, lda, ldw, ldcf, ldcb, ldadd, \
                bdiv, sA1, sA2, sW1, sW2, sCf1, sCf2, sCb1, sCb2
    if (BM == 128) {
        if (ACT == 1) bgemm_kernel<1, 128, 128><<<g, b, 0, s>>>(BG_ARGS);
        else          bgemm_kernel<0, 128, 128><<<g, b, 0, s>>>(BG_ARGS);
    } else if (BN == 128) {
        if (ACT == 1) bgemm_kernel<1, 64, 128><<<g, b, 0, s>>>(BG_ARGS);
        else          bgemm_kernel<0, 64, 128><<<g, b, 0, s>>>(BG_ARGS);
    } else {
        bgemm_kernel<0, 64, 64><<<g, b, 0, s>>>(BG_ARGS);
    }
#undef BG_ARGS
}

static inline void bgemm_plain(int ACT, int BM, int BN, const bf16* A, const bf16* W,
                               const float* bias, const float* addv, float* Cf, bf16* Cb,
                               int M, int N, int Kd, int lda, int ldw, int ldcf, int ldcb,
                               int ldadd, hipStream_t s)
{
    bgemm(ACT, BM, BN, A, W, bias, addv, Cf, Cb, M, N, Kd, lda, ldw, ldcf, ldcb, ldadd,
          1, 1, 0, 0, 0, 0, 0, 0, 0, 0, s);
}

// =====================================================================
// split-K partial reduce:  out = sum_s parts[s]  (f32 + bf16 outputs)
// =====================================================================
__global__ void splitk_reduce_kernel(const float* __restrict__ parts, float* __restrict__ outf,
                                     bf16* __restrict__ outb, int n4, int sliceN4, int S)
{
    const int i = blockIdx.x * 256 + threadIdx.x;
    if (i >= n4) return;
    float4 a = ((const float4*)parts)[i];
    for (int s2 = 1; s2 < S; s2++) {
        float4 b2 = ((const float4*)parts)[i + (long)s2 * sliceN4];
        a.x += b2.x; a.y += b2.y; a.z += b2.z; a.w += b2.w;
    }
    ((float4*)outf)[i] = a;
    bf16 b0 = __float2bfloat16(a.x), b1 = __float2bfloat16(a.y);
    bf16 b2 = __float2bfloat16(a.z), b3 = __float2bfloat16(a.w);
    short4 pk = { *(short*)&b0, *(short*)&b1, *(short*)&b2, *(short*)&b3 };
    ((short4*)outb)[i] = pk;
}

// =====================================================================
// f32 -> bf16 flat convert
// =====================================================================
__global__ void f32_to_bf16_kernel(const float* __restrict__ in, bf16* __restrict__ out, long n)
{
    long i = ((long)blockIdx.x * 256 + threadIdx.x) * 4;
    if (i + 3 < n) {
        float4 v = *(const float4*)(in + i);
        out[i]     = __float2bfloat16(v.x);
        out[i + 1] = __float2bfloat16(v.y);
        out[i + 2] = __float2bfloat16(v.z);
        out[i + 3] = __float2bfloat16(v.w);
    } else {
        for (; i < n; i++) out[i] = __float2bfloat16(in[i]);
    }
}
static inline void cvt(const float* in, bf16* out, long n, hipStream_t s)
{
    int blocks = (int)((n / 4 + 255) / 256);
    f32_to_bf16_kernel<<<blocks, 256, 0, s>>>(in, out, n);
}

// f32 (rows x kin) -> bf16 (rows x kout), zero-padded beyond kin
__global__ void cvt_pad_kernel(const float* __restrict__ in, bf16* __restrict__ out,
                               int rows, int kin, int kout)
{
    const int idx = blockIdx.x * 256 + threadIdx.x;
    if (idx >= rows * kout) return;
    const int r = idx / kout, k = idx - r * kout;
    out[idx] = __float2bfloat16(k < kin ? in[(long)r * kin + k] : 0.f);
}

// =====================================================================
// bf16 transpose per batch:  in rows (b*LE+le) x ldin, cols [col0, col0+DM)
//   -> out b: DM x LE
// =====================================================================
__global__ void transpose_bf16_kernel(const bf16* __restrict__ in, bf16* __restrict__ out,
                                      int ldin, int col0)
{
    __shared__ bf16 t[32][33];
    const int b = blockIdx.z;
    const int le0 = blockIdx.x * 32, d0 = blockIdx.y * 32;
    const int tid = threadIdx.x;
    const int c = tid & 31, r = tid >> 5;
    for (int i = r; i < 32; i += 8)
        t[i][c] = in[((long)b * cLE + le0 + i) * ldin + col0 + d0 + c];
    __syncthreads();
    for (int i = r; i < 32; i += 8)
        out[((long)b * cDM + d0 + i) * cLE + le0 + c] = t[c][i];
}

// =====================================================================
// RMSNorm per row (optional f32 and bf16 outputs)
// =====================================================================
__global__ void rmsnorm_kernel(const float* __restrict__ x, const float* __restrict__ w,
                               float* __restrict__ outf, bf16* __restrict__ outb, int Dm)
{
    const int row = blockIdx.x;
    const float* xr = x + (long)row * Dm;
    float s = 0.f;
    for (int i = threadIdx.x; i < Dm; i += 256) { float v = xr[i]; s += v * v; }
    __shared__ float red[5];
    const int lane = threadIdx.x & 63, wv = threadIdx.x >> 6;
#pragma unroll
    for (int off = 1; off < 64; off <<= 1) s += __shfl_xor(s, off);
    if (lane == 0) red[wv] = s;
    __syncthreads();
    if (threadIdx.x == 0) {
        float t = red[0] + red[1] + red[2] + red[3];
        red[4] = rsqrtf(t / Dm + 1e-5f);
    }
    __syncthreads();
    const float scale = red[4];
    for (int i = threadIdx.x; i < Dm; i += 256) {
        float v = xr[i] * scale * w[i];
        if (outf) outf[(long)row * Dm + i] = v;
        if (outb) outb[(long)row * Dm + i] = __float2bfloat16(v);
    }
}

// =====================================================================
// LayerNorm per row -> f32 + bf16 outputs
// =====================================================================
__global__ void layernorm_kernel(const float* __restrict__ x, const float* __restrict__ w,
                                 const float* __restrict__ b, float* __restrict__ outf,
                                 bf16* __restrict__ outb, int Dm)
{
    const int row = blockIdx.x;
    const float* xr = x + (long)row * Dm;
    float s = 0.f, sq = 0.f;
    for (int i = threadIdx.x; i < Dm; i += 256) { float v = xr[i]; s += v; sq += v * v; }
    __shared__ float red[8];
    __shared__ float mv[2];
    const int lane = threadIdx.x & 63, wv = threadIdx.x >> 6;
#pragma unroll
    for (int off = 1; off < 64; off <<= 1) { s += __shfl_xor(s, off); sq += __shfl_xor(sq, off); }
    if (lane == 0) { red[wv] = s; red[4 + wv] = sq; }
    __syncthreads();
    if (threadIdx.x == 0) {
        float ts = red[0] + red[1] + red[2] + red[3];
        float tq = red[4] + red[5] + red[6] + red[7];
        float m = ts / Dm;
        float var = tq / Dm - m * m;
        mv[0] = m;
        mv[1] = rsqrtf(var + 1e-5f);
    }
    __syncthreads();
    const float m = mv[0], rs = mv[1];
    for (int i = threadIdx.x; i < Dm; i += 256) {
        float v = (xr[i] - m) * rs * w[i] + b[i];
        outf[(long)row * Dm + i] = v;
        outb[(long)row * Dm + i] = __float2bfloat16(v);
    }
}

// =====================================================================
// Causal depthwise conv (K=4) + bias + SiLU -> xm f32 + bf16
// =====================================================================
__global__ void conv_silu_kernel(const float* __restrict__ xr, const float* __restrict__ w,
                                 const float* __restrict__ bias, float* __restrict__ xm,
                                 bf16* __restrict__ xmb)
{
    const int idx = blockIdx.x * 256 + threadIdx.x;
    if (idx >= cB * cL * cDI) return;
    const int d = idx & (cDI - 1);
    const int l = (idx >> 10) & (cL - 1);
    const int b = idx >> 20;
    float s = bias[d];
#pragma unroll
    for (int j = 0; j < cKC; j++) {
        const int ls = l + j - (cKC - 1);
        if (ls >= 0) s += w[d * cKC + j] * xr[((long)(b * cL + ls)) * (2 * cDI) + d];
    }
    s = s / (1.f + __expf(-s));
    xm[(long)idx] = s;
    xmb[(long)idx] = __float2bfloat16(s);
}

// =====================================================================
// Chunk-parallel selective scan, 4 states (n) per thread, NCH=32 chunks.
// Summary layout: idx = ((b*NCH+ch)*DI+d)*DS+n
// Thread mapping idx4 bits: ng[1:0], d[11:2], ch[16:12], b[17]
// =====================================================================
__global__ void scan_phase1(const float* __restrict__ xm, const float* __restrict__ delta,
                            const float* __restrict__ xdbl, const float* __restrict__ Alog,
                            float* __restrict__ aprod_out, float* __restrict__ send_out)
{
    const int idx4 = blockIdx.x * 256 + threadIdx.x;   // cB*cNCH*cDI*4
    const int ng = idx4 & 3;
    const int d  = (idx4 >> 2) & (cDI - 1);
    const int ch = (idx4 >> 12) & (cNCH - 1);
    const int b  = idx4 >> 17;
    const float4 Al = *(const float4*)(Alog + d * cDS + 4 * ng);
    const float A0 = -__expf(Al.x), A1 = -__expf(Al.y), A2 = -__expf(Al.z), A3 = -__expf(Al.w);
    float s0 = 0.f, s1 = 0.f, s2 = 0.f, s3 = 0.f;
    float p0 = 1.f, p1 = 1.f, p2 = 1.f, p3 = 1.f;
    const int l0 = ch * cCHL;
    const float* dp = delta + (long)(b * cL + l0) * cDI + d;
    const float* up = xm    + (long)(b * cL + l0) * cDI + d;
    const float* xb = xdbl  + (long)(b * cL + l0) * 64 + cDTR + 4 * ng;
    for (int t = 0; t < cCHL; t++) {
        const float dl = dp[(long)t * cDI];
        const float du = dl * up[(long)t * cDI];
        const float4 Bv = *(const float4*)(xb + (long)t * 64);
        const float a0 = __expf(dl * A0), a1 = __expf(dl * A1);
        const float a2 = __expf(dl * A2), a3 = __expf(dl * A3);
        s0 = a0 * s0 + du * Bv.x; p0 *= a0;
        s1 = a1 * s1 + du * Bv.y; p1 *= a1;
        s2 = a2 * s2 + du * Bv.z; p2 *= a2;
        s3 = a3 * s3 + du * Bv.w; p3 *= a3;
    }
    const long base4 = (((long)(b * cNCH + ch) * cDI + d) * cDS) + 4 * ng;
    float4 pv = { p0, p1, p2, p3 };
    float4 sv = { s0, s1, s2, s3 };
    *(float4*)(aprod_out + base4) = pv;
    *(float4*)(send_out + base4)  = sv;
}

__global__ void scan_phase2(const float* __restrict__ aprod, const float* __restrict__ send,
                            float* __restrict__ sinit)
{
    const int j = blockIdx.x * 256 + threadIdx.x;
    const int n = j & (cDS - 1);
    const int d = (j >> 4) & (cDI - 1);
    const int b = j >> 14;
    float s = 0.f;
#pragma unroll
    for (int c = 0; c < cNCH; c++) {
        const long off = (((long)(b * cNCH + c) * cDI + d) * cDS) + n;
        sinit[off] = s;
        s = aprod[off] * s + send[off];
    }
}

__global__ void scan_phase3(const float* __restrict__ xm, const float* __restrict__ delta,
                            const float* __restrict__ xdbl, const float* __restrict__ Alog,
                            const float* __restrict__ Dv, const float* __restrict__ xr,
                            const float* __restrict__ sinit, bf16* __restrict__ y)
{
    const int idx4 = blockIdx.x * 256 + threadIdx.x;   // cB*cNCH*cDI*4
    const int ng = idx4 & 3;
    const int d  = (idx4 >> 2) & (cDI - 1);
    const int ch = (idx4 >> 12) & (cNCH - 1);
    const int b  = idx4 >> 17;
    const float4 Al = *(const float4*)(Alog + d * cDS + 4 * ng);
    const float A0 = -__expf(Al.x), A1 = -__expf(Al.y), A2 = -__expf(Al.z), A3 = -__expf(Al.w);
    const float Dval = Dv[d];
    const long base4 = (((long)(b * cNCH + ch) * cDI + d) * cDS) + 4 * ng;
    float4 st = *(const float4*)(sinit + base4);
    float s0 = st.x, s1 = st.y, s2 = st.z, s3 = st.w;
    const int l0 = ch * cCHL;
    const float* dp = delta + (long)(b * cL + l0) * cDI + d;
    const float* up = xm    + (long)(b * cL + l0) * cDI + d;
    const float* xb = xdbl  + (long)(b * cL + l0) * 64 + cDTR + 4 * ng;
    const float* xc = xb + cDS;
    const float* rp = xr + (long)(b * cL + l0) * (2 * cDI) + cDI + d;
    bf16* yp = y + (long)(b * cL + l0) * cDI + d;
    for (int t = 0; t < cCHL; t++) {
        const float dl = dp[(long)t * cDI];
        const float u  = up[(long)t * cDI];
        const float du = dl * u;
        const float4 Bv = *(const float4*)(xb + (long)t * 64);
        const float4 Cv = *(const float4*)(xc + (long)t * 64);
        const float a0 = __expf(dl * A0), a1 = __expf(dl * A1);
        const float a2 = __expf(dl * A2), a3 = __expf(dl * A3);
        s0 = a0 * s0 + du * Bv.x;
        s1 = a1 * s1 + du * Bv.y;
        s2 = a2 * s2 + du * Bv.z;
        s3 = a3 * s3 + du * Bv.w;
        float c = s0 * Cv.x;
        c = fmaf(s1, Cv.y, c);
        c = fmaf(s2, Cv.z, c);
        c = fmaf(s3, Cv.w, c);
        c += __shfl_xor(c, 1);
        c += __shfl_xor(c, 2);
        if (ng == 0) {
            const float res = rp[(long)t * 2 * cDI];
            const float sig = 1.f / (1.f + __expf(-res));
            yp[(long)t * cDI] = __float2bfloat16((c + u * Dval) * (res * sig));
        }
    }
}

// =====================================================================
// Row softmax (1024 cols, 256 threads, one float4/thread); reads f32 row,
// writes bf16 IN PLACE over the start of the same row (pitch stays 1024 f32).
// =====================================================================
__global__ void softmax_kernel(float* __restrict__ s, float scale)
{
    const long row = blockIdx.x;
    float* p = s + row * 1024;
    const int t = threadIdx.x;
    float4 v = ((const float4*)p)[t];
    v.x *= scale; v.y *= scale; v.z *= scale; v.w *= scale;
    float mx = fmaxf(fmaxf(v.x, v.y), fmaxf(v.z, v.w));
    __shared__ float red[8];
    const int lane = t & 63, wv = t >> 6;
#pragma unroll
    for (int off = 1; off < 64; off <<= 1) mx = fmaxf(mx, __shfl_xor(mx, off));
    if (lane == 0) red[wv] = mx;
    __syncthreads();
    mx = fmaxf(fmaxf(red[0], red[1]), fmaxf(red[2], red[3]));
    v.x = __expf(v.x - mx); v.y = __expf(v.y - mx);
    v.z = __expf(v.z - mx); v.w = __expf(v.w - mx);
    float sum = (v.x + v.y) + (v.z + v.w);
#pragma unroll
    for (int off = 1; off < 64; off <<= 1) sum += __shfl_xor(sum, off);
    if (lane == 0) red[4 + wv] = sum;
    __syncthreads();
    const float inv = 1.f / (red[4] + red[5] + red[6] + red[7]);
    bf16 b0 = __float2bfloat16(v.x * inv), b1 = __float2bfloat16(v.y * inv);
    bf16 b2 = __float2bfloat16(v.z * inv), b3 = __float2bfloat16(v.w * inv);
    short4 pk = { *(short*)&b0, *(short*)&b1, *(short*)&b2, *(short*)&b3 };
    ((short4*)p)[t] = pk;
}

// =====================================================================
extern "C" void kernel_launch(void* const* d_in, const int* in_sizes, int n_in,
                              void* d_out, int out_size, void* d_ws, size_t ws_size,
                              hipStream_t stream)
{
    const float* x       = (const float*)d_in[0];
    const float* enc     = (const float*)d_in[1];
    const float* W_in    = (const float*)d_in[2];
    const float* b_in    = (const float*)d_in[3];
    const float* m_norm_w= (const float*)d_in[4];
    const float* m_in_w  = (const float*)d_in[5];
    const float* m_conv_w= (const float*)d_in[6];
    const float* m_conv_b= (const float*)d_in[7];
    const float* m_xproj = (const float*)d_in[8];
    const float* m_dt_w  = (const float*)d_in[9];
    const float* m_dt_b  = (const float*)d_in[10];
    const float* m_Alog  = (const float*)d_in[11];
    const float* m_D     = (const float*)d_in[12];
    const float* m_out_w = (const float*)d_in[13];
    const float* a_in_w  = (const float*)d_in[14];
    const float* a_in_b  = (const float*)d_in[15];
    const float* a_out_w = (const float*)d_in[16];
    const float* a_out_b = (const float*)d_in[17];
    const float* a_ln_w  = (const float*)d_in[18];
    const float* a_ln_b  = (const float*)d_in[19];
    const float* normf_w = (const float*)d_in[20];
    const float* W_out   = (const float*)d_in[21];
    float* out = (float*)d_out;

    float* ws = (float*)d_ws;
    long off = 0;
    auto allocf = [&](long n) { float* p = ws + off; off += n; return p; };

    const long M1 = 1 << 20;
    float* bufH    = allocf(M1);
    float* bufPre  = allocf(M1);         // also xproj split-K partials
    float* bufXR   = allocf(4 * M1);     // S (8M f32) overlays XR/XM/Delta during attn
    float* bufXM   = allocf(2 * M1);
    float* bufDelta= allocf(2 * M1);
    float* bufXDBL = allocf(M1 / 8);
    bf16* bufU    = (bf16*)allocf(M1 / 2);      // 2048x512 bf16
    bf16* bufHb   = (bf16*)allocf(M1 / 2);
    bf16* bufXMb  = (bf16*)allocf(M1);          // 2048x1024 bf16
    bf16* bufXDBLb= (bf16*)allocf(M1 / 16);
    bf16* bufY    = (bf16*)allocf(M1);          // 2048x1024 bf16; send (f32) during scan
    bf16* bufQ    = (bf16*)allocf(M1 / 2);
    bf16* bufKV   = (bf16*)allocf(M1);          // [K | V]; aprod (f32) during scan
    bf16* bufVT   = (bf16*)allocf(M1 / 2);      // sinit (f32, spans VT+O) during scan
    bf16* bufO    = (bf16*)allocf(M1 / 2);
    bf16* encb    = (bf16*)allocf(M1 / 2);
    bf16* w_in_b  = (bf16*)allocf(2 * M1);      // mamba in_w (4 layers)
    bf16* w_xp_b  = (bf16*)allocf(M1 / 8);
    bf16* w_dt_b  = (bf16*)allocf(M1 / 16);
    bf16* w_out_b = (bf16*)allocf(M1);
    bf16* w_ain_b = (bf16*)allocf(3 * M1 / 2);
    bf16* w_aout_b= (bf16*)allocf(M1 / 2);
    bf16* x_pad   = (bf16*)allocf(2048L * 96 / 2);   // x zero-padded K=96
    bf16* w_inp_b = (bf16*)allocf(512L * 96 / 2);    // W_in zero-padded K=96
    bf16* w_outf_b= (bf16*)allocf(80L * 512 / 2);    // W_out bf16

    float* bufS   = bufXR;                       // 8M f32 scores
    // scan summaries at NCH=32: B*NCH*DI*DS = 1M floats each, overlaid on
    // regions dead during the mamba half (sequential-stream safe):
    float* bufAP  = (float*)bufKV;               // aprod: 1M floats
    float* bufSE  = (float*)bufY;                // send:  1M floats (Y written later by phase3)
    float* bufSI  = (float*)bufVT;               // sinit: 1M floats (spans VT+O)

    const int Mrows = cB * cL;   // 2048
    const long SUMSZ4 = (long)cB * cNCH * cDI * 4;   // scan threads (4 n each) = 262144

    // ---- one-time conversions (weights + enc + padded edges) ----
    cvt(enc,      encb,    (long)cB * cLE * cDM, stream);
    cvt(m_in_w,   w_in_b,  (long)cLAYERS * 2 * cDI * cDM, stream);
    cvt(m_xproj,  w_xp_b,  (long)cLAYERS * 64 * cDI, stream);
    cvt(m_dt_w,   w_dt_b,  (long)cLAYERS * cDI * cDTR, stream);
    cvt(m_out_w,  w_out_b, (long)cLAYERS * cDM * cDI, stream);
    cvt(a_in_w,   w_ain_b, (long)cLAYERS * 3 * cDM * cDM, stream);
    cvt(a_out_w,  w_aout_b,(long)cLAYERS * cDM * cDM, stream);
    cvt(W_out,    w_outf_b,(long)cNM * cDM, stream);
    cvt_pad_kernel<<<(Mrows * 96 + 255) / 256, 256, 0, stream>>>(x, x_pad, Mrows, cNM, 96);
    cvt_pad_kernel<<<(cDM * 96 + 255) / 256, 256, 0, stream>>>(W_in, w_inp_b, cDM, cNM, 96);

    // h = x @ W_in.T + b_in   (K padded 80->96, MFMA 64^2)
    bgemm_plain(0, 64, 64, x_pad, w_inp_b, b_in, nullptr, bufH, nullptr,
                Mrows, cDM, 96, 96, 96, cDM, 0, 0, stream);

    for (int i = 0; i < cLAYERS; i++) {
        const float* norm_w = m_norm_w + (long)i * cDM;
        const bf16*  in_w   = w_in_b   + (long)i * 2 * cDI * cDM;
        const float* conv_w = m_conv_w + (long)i * cDI * cKC;
        const float* conv_b = m_conv_b + (long)i * cDI;
        const bf16*  xproj  = w_xp_b   + (long)i * 64 * cDI;
        const bf16*  dt_w   = w_dt_b   + (long)i * cDI * cDTR;
        const float* dt_b   = m_dt_b   + (long)i * cDI;
        const float* Alog   = m_Alog   + (long)i * cDI * cDS;
        const float* Dv     = m_D      + (long)i * cDI;
        const bf16*  out_w  = w_out_b  + (long)i * cDM * cDI;
        const bf16*  ain_w  = w_ain_b  + (long)i * 3 * cDM * cDM;
        const float* ain_b  = a_in_b   + (long)i * 3 * cDM;
        const bf16*  aout_w = w_aout_b + (long)i * cDM * cDM;
        const float* aout_b = a_out_b  + (long)i * cDM;
        const float* ln_w   = a_ln_w   + (long)i * cDM;
        const float* ln_b   = a_ln_b   + (long)i * cDM;

        // ---- mamba ----
        rmsnorm_kernel<<<Mrows, 256, 0, stream>>>(bufH, norm_w, nullptr, bufU, cDM);
        // xr = u @ in_w.T  (64x128 tiles -> 512 blocks)
        bgemm_plain(0, 64, 128, bufU, in_w, nullptr, nullptr, bufXR, nullptr,
                    Mrows, 2 * cDI, cDM, cDM, cDM, 2 * cDI, 0, 0, stream);
        conv_silu_kernel<<<(cB * cL * cDI) / 256, 256, 0, stream>>>(bufXR, conv_w, conv_b, bufXM, bufXMb);
        // x_dbl = xm @ xproj.T : split-K x8 (N=64 too narrow otherwise)
        bgemm(0, 64, 64, bufXMb, xproj, nullptr, nullptr, bufPre, nullptr,
              Mrows, 64, cDI / 8, cDI, cDI, 64, 0, 0,
              8, 1, 128, 0, 128, 0, (long)Mrows * 64, 0, 0, 0, stream);
        splitk_reduce_kernel<<<(Mrows * 64 / 4 + 255) / 256, 256, 0, stream>>>(
            bufPre, bufXDBL, bufXDBLb, Mrows * 64 / 4, Mrows * 64 / 4, 8);
        // delta = softplus(dlt @ dt_w.T + dt_b)
        bgemm_plain(1, 64, 128, bufXDBLb, dt_w, dt_b, nullptr, bufDelta, nullptr,
                    Mrows, cDI, cDTR, 64, cDTR, cDI, 0, 0, stream);
        // chunk-parallel scan (NCH=32 -> 1024 blocks/phase)
        scan_phase1<<<(int)(SUMSZ4 / 256), 256, 0, stream>>>(bufXM, bufDelta, bufXDBL, Alog, bufAP, bufSE);
        scan_phase2<<<(cB * cDI * cDS) / 256, 256, 0, stream>>>(bufAP, bufSE, bufSI);
        scan_phase3<<<(int)(SUMSZ4 / 256), 256, 0, stream>>>(bufXM, bufDelta, bufXDBL, Alog, Dv, bufXR, bufSI, bufY);
        // h += y @ out_w.T
        bgemm_plain(0, 64, 64, bufY, out_w, nullptr, bufH, bufH, bufHb,
                    Mrows, cDM, cDI, cDI, cDI, cDM, cDM, cDM, stream);

        // ---- cross attention ----
        bgemm_plain(0, 64, 64, bufHb, ain_w, ain_b, nullptr, nullptr, bufQ,
                    Mrows, cDM, cDM, cDM, cDM, 0, cDM, 0, stream);
        // fused K|V projection from enc: N = 1024 (cols 0..511 = K, 512..1023 = V)
        bgemm_plain(0, 64, 128, encb, ain_w + (long)cDM * cDM, ain_b + cDM, nullptr, nullptr, bufKV,
                    Mrows, 2 * cDM, cDM, cDM, cDM, 0, 2 * cDM, 0, stream);
        {
            dim3 g(cLE / 32, cDM / 32, cB);
            transpose_bf16_kernel<<<g, 256, 0, stream>>>(bufKV, bufVT, 2 * cDM, cDM);
        }
        // scores[b,h] = q @ k.T  (f32)
        bgemm(0, 128, 128, bufQ, bufKV, nullptr, nullptr, bufS, nullptr,
              cL, cLE, cHD, cDM, 2 * cDM, cLE, 0, 0,
              cB * cH, cH,
              (long)cL * cDM, (long)cHD,
              (long)cLE * 2 * cDM, (long)cHD,
              (long)cH * cL * cLE, (long)cL * cLE, 0, 0, stream);
        softmax_kernel<<<cB * cH * cL, 256, 0, stream>>>(bufS, 0.08838834764831845f);
        // o[b,:,h] = P @ V  via  P (bf16 in-place rows, pitch 2*LE) x VT ; 64^2 tile
        bgemm(0, 64, 64, (const bf16*)bufS, bufVT, nullptr, nullptr, nullptr, bufO,
              cL, cHD, cLE, 2 * cLE, cLE, 0, cDM, 0,
              cB * cH, cH,
              (long)cH * cL * (2 * cLE), (long)cL * (2 * cLE),
              (long)cDM * cLE, (long)cHD * cLE,
              0, 0, (long)cL * cDM, (long)cHD, stream);
        // pre = o @ aout_w.T + aout_b + h ; h = LN(pre)
        bgemm_plain(0, 64, 64, bufO, aout_w, aout_b, bufH, bufPre, nullptr,
                    Mrows, cDM, cDM, cDM, cDM, cDM, 0, cDM, stream);
        layernorm_kernel<<<Mrows, 256, 0, stream>>>(bufPre, ln_w, ln_b, bufH, bufHb, cDM);
    }

    // final: out = rmsnorm(h) @ W_out.T   (MFMA, 64^2 tile, N=80 edge-clamped)
    rmsnorm_kernel<<<Mrows, 256, 0, stream>>>(bufH, normf_w, nullptr, bufU, cDM);
    bgemm_plain(0, 64, 64, bufU, w_outf_b, nullptr, nullptr, out, nullptr,
                Mrows, cNM, cDM, cDM, cDM, cNM, 0, 0, stream);
}

// Round 8
// 870.863 us; speedup vs baseline: 8.1240x; 1.0537x over previous
//
#include <hip/hip_runtime.h>
#include <hip/hip_bf16.h>
#include <math.h>

typedef __hip_bfloat16 bf16;
typedef __attribute__((ext_vector_type(8))) short short8x;
typedef __attribute__((ext_vector_type(4))) float f32x4;

// ---- problem constants ----
static constexpr int cB   = 2;
static constexpr int cL   = 1024;
static constexpr int cLE  = 1024;
static constexpr int cNM  = 80;
static constexpr int cDM  = 512;
static constexpr int cLAYERS = 4;
static constexpr int cDS  = 16;
static constexpr int cKC  = 4;     // conv taps
static constexpr int cH   = 4;     // heads
static constexpr int cDI  = 1024;  // EXP*DM
static constexpr int cDTR = 32;
static constexpr int cHD  = 128;   // head dim

static constexpr int cNCH = 32;    // scan chunks
static constexpr int cCHL = cL / cNCH;  // 32 steps per chunk

#define GLL16(g, l) __builtin_amdgcn_global_load_lds( \
    (const __attribute__((address_space(1))) void*)(g), \
    (__attribute__((address_space(3))) void*)(l), 16, 0, 0)

// =====================================================================
// bf16 MFMA GEMM, BMxBN tile, 4 waves (2x2), K-step 32.
//   C = act( A @ W^T + bias ) + addv ; A: M x K bf16 (lda), W: N x K bf16 (ldw)
//   Writes f32 C (if Cf) and/or bf16 C (if Cb). Batched over blockIdx.z.
// =====================================================================
template<int ACT, int BM, int BN>
__global__ __launch_bounds__(256)
void bgemm_kernel(const bf16* __restrict__ A, const bf16* __restrict__ W,
                  const float* __restrict__ bias, const float* __restrict__ addv,
                  float* __restrict__ Cf, bf16* __restrict__ Cb,
                  int M, int N, int Kd, int lda, int ldw, int ldcf, int ldcb, int ldadd,
                  int bdiv, long sA1, long sA2, long sW1, long sW2,
                  long sCf1, long sCf2, long sCb1, long sCb2)
{
    constexpr int RM = BM / 32;            // per-wave 16-row frag repeats
    constexpr int RN = BN / 32;
    const int z = blockIdx.z;
    const int i1 = z / bdiv, i2 = z % bdiv;
    A += i1 * sA1 + i2 * sA2;
    W += i1 * sW1 + i2 * sW2;

    const int bm = blockIdx.y * BM;
    const int bn = blockIdx.x * BN;
    const int tid = threadIdx.x;
    const int lane = tid & 63;
    const int wid = tid >> 6;              // 0..3
    const int wr = wid >> 1, wc = wid & 1; // 2x2 wave grid

    __shared__ bf16 As[BM * 32];
    __shared__ bf16 Bs[BN * 32];

    f32x4 acc[RM][RN] = {};

    const int r_in = lane >> 2;            // 0..15
    const int kb   = (lane & 3) * 8;       // k offset for staging
    const int hi   = lane >> 4;            // 0..3
    const int rc   = lane & 15;

    for (int k0 = 0; k0 < Kd; k0 += 32) {
#pragma unroll
        for (int iss = 0; iss < BM / 64; iss++) {
            const int row = wid * (BM / 4) + iss * 16 + r_in;
            int gm = bm + row; if (gm >= M) gm = M - 1;
            const bf16* ga = A + (long)gm * lda + k0 + kb;
            GLL16(ga, As + (wid * (BM / 4) + iss * 16) * 32);
        }
#pragma unroll
        for (int iss = 0; iss < BN / 64; iss++) {
            const int row = wid * (BN / 4) + iss * 16 + r_in;
            int gn = bn + row; if (gn >= N) gn = N - 1;
            const bf16* gb = W + (long)gn * ldw + k0 + kb;
            GLL16(gb, Bs + (wid * (BN / 4) + iss * 16) * 32);
        }
        asm volatile("s_waitcnt vmcnt(0)" ::: "memory");
        __syncthreads();

        short8x af[RM], bfv[RN];
#pragma unroll
        for (int i = 0; i < RM; i++)
            af[i] = *(const short8x*)(As + (wr * (BM / 2) + i * 16 + rc) * 32 + hi * 8);
#pragma unroll
        for (int j = 0; j < RN; j++)
            bfv[j] = *(const short8x*)(Bs + (wc * (BN / 2) + j * 16 + rc) * 32 + hi * 8);
#pragma unroll
        for (int i = 0; i < RM; i++)
#pragma unroll
            for (int j = 0; j < RN; j++)
                acc[i][j] = __builtin_amdgcn_mfma_f32_16x16x32_bf16(af[i], bfv[j], acc[i][j], 0, 0, 0);
        __syncthreads();
    }

    // epilogue: C/D frag mapping col=lane&15, row=(lane>>4)*4+r  [m89-verified]
    const long cfo = i1 * sCf1 + i2 * sCf2;
    const long cbo = i1 * sCb1 + i2 * sCb2;
#pragma unroll
    for (int i = 0; i < RM; i++) {
#pragma unroll
        for (int r = 0; r < 4; r++) {
            const int gm = bm + wr * (BM / 2) + i * 16 + hi * 4 + r;
            if (gm >= M) continue;
#pragma unroll
            for (int j = 0; j < RN; j++) {
                const int gn = bn + wc * (BN / 2) + j * 16 + rc;
                if (gn >= N) continue;
                float v = acc[i][j][r];
                if (bias) v += bias[gn];
                if (ACT == 1) v = (v > 20.f) ? v : log1pf(__expf(v));
                if (addv) v += addv[cfo + (long)gm * ldadd + gn];
                if (Cf) Cf[cfo + (long)gm * ldcf + gn] = v;
                if (Cb) Cb[cbo + (long)gm * ldcb + gn] = __float2bfloat16(v);
            }
        }
    }
}

static inline void bgemm(int ACT, int BM, int BN, const bf16* A, const bf16* W, const float* bias,
                         const float* addv, float* Cf, bf16* Cb,
                         int M, int N, int Kd, int lda, int ldw, int ldcf, int ldcb, int ldadd,
                         int nz, int bdiv, long sA1, long sA2, long sW1, long sW2,
                         long sCf1, long sCf2, long sCb1, long sCb2, hipStream_t s)
{
    dim3 g((N + BN - 1) / BN, (M + BM - 1) / BM, nz), b(256);
#define BG_ARGS A, W, bias, addv, Cf, Cb, M, N, Kd, lda, ldw, ldcf, ldcb, ldadd, \
                bdiv, sA1, sA2, sW1, sW2, sCf1, sCf2, sCb1, sCb2
    if (BM == 128) {
        if (ACT == 1) bgemm_kernel<1, 128, 128><<<g, b, 0, s>>>(BG_ARGS);
        else          bgemm_kernel<0, 128, 128><<<g, b, 0, s>>>(BG_ARGS);
    } else if (BN == 128) {
        if (ACT == 1) bgemm_kernel<1, 64, 128><<<g, b, 0, s>>>(BG_ARGS);
        else          bgemm_kernel<0, 64, 128><<<g, b, 0, s>>>(BG_ARGS);
    } else {
        bgemm_kernel<0, 64, 64><<<g, b, 0, s>>>(BG_ARGS);
    }
#undef BG_ARGS
}

static inline void bgemm_plain(int ACT, int BM, int BN, const bf16* A, const bf16* W,
                               const float* bias, const float* addv, float* Cf, bf16* Cb,
                               int M, int N, int Kd, int lda, int ldw, int ldcf, int ldcb,
                               int ldadd, hipStream_t s)
{
    bgemm(ACT, BM, BN, A, W, bias, addv, Cf, Cb, M, N, Kd, lda, ldw, ldcf, ldcb, ldadd,
          1, 1, 0, 0, 0, 0, 0, 0, 0, 0, s);
}

// =====================================================================
// Fused flash cross-attention.  Per block: 32 q-rows of one (b,h);
// iterates 16 KV tiles of 64.  2 waves x 16 q-rows.
//   Q: [B*L][DM] bf16 (head at col h*HD);  K: bufKV [B*LE][2*DM] (K cols 0..511)
//   VT: [B*DM][LE] bf16;  O: [B*L][DM] bf16.
// LDS tiles are 16B-chunk XOR-swizzled (chunk ^= row&7) via pre-swizzled
// global source (rule #21): linear gload_lds dst + swizzled reads.
// =====================================================================
__global__ __launch_bounds__(128)
void flash_attn_kernel(const bf16* __restrict__ Qp, const bf16* __restrict__ Kp,
                       const bf16* __restrict__ VTp, bf16* __restrict__ Op, float scale)
{
    const int qt = blockIdx.x;            // 0..31
    const int bh = blockIdx.y;            // b*H + h
    const int b = bh >> 2, h = bh & 3;
    const int tid = threadIdx.x;
    const int w = tid >> 6;               // 0..1
    const int lane = tid & 63;
    const int rc = lane & 15, hi = lane >> 4;
    const int rlo = rc & 7;

    __shared__ bf16 Qs[32 * 128];
    __shared__ bf16 Ks[64 * 128];
    __shared__ bf16 Vs[128 * 64];
    __shared__ bf16 Ps[32 * 64];

    // ---- Q tile (32x128), once ----
    {
        const bf16* qb = Qp + ((long)(b * cL + qt * 32)) * cDM + h * cHD;
#pragma unroll
        for (int c = 0; c < 4; c++) {
            const int row = w * 16 + c * 4 + (lane >> 4);
            const int gc = (lane & 15) ^ (row & 7);
            GLL16(qb + (long)row * cDM + gc * 8, Qs + (w * 16 + c * 4) * 128);
        }
    }
    asm volatile("s_waitcnt vmcnt(0)" ::: "memory");
    __syncthreads();

    // hoist Q A-fragments
    short8x aq[4];
#pragma unroll
    for (int kk = 0; kk < 4; kk++) {
        const int sc = (kk * 4 + hi) ^ rlo;
        aq[kk] = *(const short8x*)(Qs + (w * 16 + rc) * 128 + sc * 8);
    }

    float m_r[4], l_r[4];
#pragma unroll
    for (int r = 0; r < 4; r++) { m_r[r] = -1e30f; l_r[r] = 0.f; }
    f32x4 oacc[8] = {};

    const bf16* kb0 = Kp + ((long)(b * cLE)) * (2 * cDM) + h * cHD;
    const bf16* vb0 = VTp + ((long)(b * cDM + h * cHD)) * cLE;

    for (int kt = 0; kt < 16; kt++) {
        __syncthreads();                          // prev iter readers done
        // K tile 64x128
#pragma unroll
        for (int c = 0; c < 8; c++) {
            const int row = w * 32 + c * 4 + (lane >> 4);
            const int gc = (lane & 15) ^ (row & 7);
            GLL16(kb0 + ((long)(kt * 64 + row)) * (2 * cDM) + gc * 8,
                  Ks + (w * 32 + c * 4) * 128);
        }
        // V tile via VT: 128 d-rows x 64 kv
#pragma unroll
        for (int c = 0; c < 8; c++) {
            const int row = w * 64 + c * 8 + (lane >> 3);
            const int gc = (lane & 7) ^ (row & 7);
            GLL16(vb0 + (long)row * cLE + kt * 64 + gc * 8,
                  Vs + (w * 64 + c * 8) * 64);
        }
        asm volatile("s_waitcnt vmcnt(0)" ::: "memory");
        __syncthreads();

        // S = Q @ K^T  (16 q-rows x 64 kv per wave)
        f32x4 s[4] = {};
#pragma unroll
        for (int kk = 0; kk < 4; kk++) {
            const int sc = (kk * 4 + hi) ^ rlo;
#pragma unroll
            for (int j = 0; j < 4; j++) {
                short8x bk = *(const short8x*)(Ks + (j * 16 + rc) * 128 + sc * 8);
                s[j] = __builtin_amdgcn_mfma_f32_16x16x32_bf16(aq[kk], bk, s[j], 0, 0, 0);
            }
        }

        // online softmax over this lane's 4 rows (q = w*16 + hi*4 + r)
        float p[4][4];
        float esc[4];
#pragma unroll
        for (int r = 0; r < 4; r++) {
            const float v0 = s[0][r] * scale, v1 = s[1][r] * scale;
            const float v2 = s[2][r] * scale, v3 = s[3][r] * scale;
            float mx = fmaxf(fmaxf(v0, v1), fmaxf(v2, v3));
            mx = fmaxf(mx, __shfl_xor(mx, 1));
            mx = fmaxf(mx, __shfl_xor(mx, 2));
            mx = fmaxf(mx, __shfl_xor(mx, 4));
            mx = fmaxf(mx, __shfl_xor(mx, 8));
            const float mn = fmaxf(m_r[r], mx);
            p[0][r] = __expf(v0 - mn);
            p[1][r] = __expf(v1 - mn);
            p[2][r] = __expf(v2 - mn);
            p[3][r] = __expf(v3 - mn);
            float rs = (p[0][r] + p[1][r]) + (p[2][r] + p[3][r]);
            rs += __shfl_xor(rs, 1);
            rs += __shfl_xor(rs, 2);
            rs += __shfl_xor(rs, 4);
            rs += __shfl_xor(rs, 8);
            esc[r] = __expf(m_r[r] - mn);
            l_r[r] = l_r[r] * esc[r] + rs;
            m_r[r] = mn;
        }
#pragma unroll
        for (int j2 = 0; j2 < 8; j2++)
#pragma unroll
            for (int r = 0; r < 4; r++)
                oacc[j2][r] *= esc[r];
        // write P tile (32x64 bf16, swizzled)
#pragma unroll
        for (int j = 0; j < 4; j++)
#pragma unroll
            for (int r = 0; r < 4; r++) {
                const int q = w * 16 + hi * 4 + r;
                const int cp = (j * 2 + (rc >> 3)) ^ (q & 7);
                Ps[q * 64 + cp * 8 + (rc & 7)] = __float2bfloat16(p[j][r]);
            }
        __syncthreads();                          // P visible
        // O += P @ V
#pragma unroll
        for (int ks = 0; ks < 2; ks++) {
            const int sc = (ks * 4 + hi) ^ rlo;
            short8x ap = *(const short8x*)(Ps + (w * 16 + rc) * 64 + sc * 8);
#pragma unroll
            for (int j2 = 0; j2 < 8; j2++) {
                short8x bv = *(const short8x*)(Vs + (j2 * 16 + rc) * 64 + sc * 8);
                oacc[j2] = __builtin_amdgcn_mfma_f32_16x16x32_bf16(ap, bv, oacc[j2], 0, 0, 0);
            }
        }
    }

    // epilogue: O /= l
    float inv[4];
#pragma unroll
    for (int r = 0; r < 4; r++) inv[r] = 1.f / l_r[r];
    bf16* ob = Op + ((long)(b * cL + qt * 32)) * cDM + h * cHD;
#pragma unroll
    for (int j2 = 0; j2 < 8; j2++)
#pragma unroll
        for (int r = 0; r < 4; r++)
            ob[(long)(w * 16 + hi * 4 + r) * cDM + j2 * 16 + rc] =
                __float2bfloat16(oacc[j2][r] * inv[r]);
}

// =====================================================================
// split-K partial reduce:  out = sum_s parts[s]  (f32 + bf16 outputs)
// =====================================================================
__global__ void splitk_reduce_kernel(const float* __restrict__ parts, float* __restrict__ outf,
                                     bf16* __restrict__ outb, int n4, int sliceN4, int S)
{
    const int i = blockIdx.x * 256 + threadIdx.x;
    if (i >= n4) return;
    float4 a = ((const float4*)parts)[i];
    for (int s2 = 1; s2 < S; s2++) {
        float4 b2 = ((const float4*)parts)[i + (long)s2 * sliceN4];
        a.x += b2.x; a.y += b2.y; a.z += b2.z; a.w += b2.w;
    }
    ((float4*)outf)[i] = a;
    bf16 b0 = __float2bfloat16(a.x), b1 = __float2bfloat16(a.y);
    bf16 b2 = __float2bfloat16(a.z), b3 = __float2bfloat16(a.w);
    short4 pk = { *(short*)&b0, *(short*)&b1, *(short*)&b2, *(short*)&b3 };
    ((short4*)outb)[i] = pk;
}

// =====================================================================
// f32 -> bf16 flat convert
// =====================================================================
__global__ void f32_to_bf16_kernel(const float* __restrict__ in, bf16* __restrict__ out, long n)
{
    long i = ((long)blockIdx.x * 256 + threadIdx.x) * 4;
    if (i + 3 < n) {
        float4 v = *(const float4*)(in + i);
        out[i]     = __float2bfloat16(v.x);
        out[i + 1] = __float2bfloat16(v.y);
        out[i + 2] = __float2bfloat16(v.z);
        out[i + 3] = __float2bfloat16(v.w);
    } else {
        for (; i < n; i++) out[i] = __float2bfloat16(in[i]);
    }
}
static inline void cvt(const float* in, bf16* out, long n, hipStream_t s)
{
    int blocks = (int)((n / 4 + 255) / 256);
    f32_to_bf16_kernel<<<blocks, 256, 0, s>>>(in, out, n);
}

// f32 (rows x kin) -> bf16 (rows x kout), zero-padded beyond kin
__global__ void cvt_pad_kernel(const float* __restrict__ in, bf16* __restrict__ out,
                               int rows, int kin, int kout)
{
    const int idx = blockIdx.x * 256 + threadIdx.x;
    if (idx >= rows * kout) return;
    const int r = idx / kout, k = idx - r * kout;
    out[idx] = __float2bfloat16(k < kin ? in[(long)r * kin + k] : 0.f);
}

// =====================================================================
// bf16 transpose per batch:  in rows (b*LE+le) x ldin, cols [col0, col0+DM)
//   -> out b: DM x LE
// =====================================================================
__global__ void transpose_bf16_kernel(const bf16* __restrict__ in, bf16* __restrict__ out,
                                      int ldin, int col0)
{
    __shared__ bf16 t[32][33];
    const int b = blockIdx.z;
    const int le0 = blockIdx.x * 32, d0 = blockIdx.y * 32;
    const int tid = threadIdx.x;
    const int c = tid & 31, r = tid >> 5;
    for (int i = r; i < 32; i += 8)
        t[i][c] = in[((long)b * cLE + le0 + i) * ldin + col0 + d0 + c];
    __syncthreads();
    for (int i = r; i < 32; i += 8)
        out[((long)b * cDM + d0 + i) * cLE + le0 + c] = t[c][i];
}

// =====================================================================
// RMSNorm per row (optional f32 and bf16 outputs)
// =====================================================================
__global__ void rmsnorm_kernel(const float* __restrict__ x, const float* __restrict__ w,
                               float* __restrict__ outf, bf16* __restrict__ outb, int Dm)
{
    const int row = blockIdx.x;
    const float* xr = x + (long)row * Dm;
    float s = 0.f;
    for (int i = threadIdx.x; i < Dm; i += 256) { float v = xr[i]; s += v * v; }
    __shared__ float red[5];
    const int lane = threadIdx.x & 63, wv = threadIdx.x >> 6;
#pragma unroll
    for (int off = 1; off < 64; off <<= 1) s += __shfl_xor(s, off);
    if (lane == 0) red[wv] = s;
    __syncthreads();
    if (threadIdx.x == 0) {
        float t = red[0] + red[1] + red[2] + red[3];
        red[4] = rsqrtf(t / Dm + 1e-5f);
    }
    __syncthreads();
    const float scale = red[4];
    for (int i = threadIdx.x; i < Dm; i += 256) {
        float v = xr[i] * scale * w[i];
        if (outf) outf[(long)row * Dm + i] = v;
        if (outb) outb[(long)row * Dm + i] = __float2bfloat16(v);
    }
}

// =====================================================================
// LayerNorm per row -> f32 + bf16 outputs
// =====================================================================
__global__ void layernorm_kernel(const float* __restrict__ x, const float* __restrict__ w,
                                 const float* __restrict__ b, float* __restrict__ outf,
                                 bf16* __restrict__ outb, int Dm)
{
    const int row = blockIdx.x;
    const float* xr = x + (long)row * Dm;
    float s = 0.f, sq = 0.f;
    for (int i = threadIdx.x; i < Dm; i += 256) { float v = xr[i]; s += v; sq += v * v; }
    __shared__ float red[8];
    __shared__ float mv[2];
    const int lane = threadIdx.x & 63, wv = threadIdx.x >> 6;
#pragma unroll
    for (int off = 1; off < 64; off <<= 1) { s += __shfl_xor(s, off); sq += __shfl_xor(sq, off); }
    if (lane == 0) { red[wv] = s; red[4 + wv] = sq; }
    __syncthreads();
    if (threadIdx.x == 0) {
        float ts = red[0] + red[1] + red[2] + red[3];
        float tq = red[4] + red[5] + red[6] + red[7];
        float m = ts / Dm;
        float var = tq / Dm - m * m;
        mv[0] = m;
        mv[1] = rsqrtf(var + 1e-5f);
    }
    __syncthreads();
    const float m = mv[0], rs = mv[1];
    for (int i = threadIdx.x; i < Dm; i += 256) {
        float v = (xr[i] - m) * rs * w[i] + b[i];
        outf[(long)row * Dm + i] = v;
        outb[(long)row * Dm + i] = __float2bfloat16(v);
    }
}

// =====================================================================
// Causal depthwise conv (K=4) + bias + SiLU -> xm f32 + bf16
// =====================================================================
__global__ void conv_silu_kernel(const float* __restrict__ xr, const float* __restrict__ w,
                                 const float* __restrict__ bias, float* __restrict__ xm,
                                 bf16* __restrict__ xmb)
{
    const int idx = blockIdx.x * 256 + threadIdx.x;
    if (idx >= cB * cL * cDI) return;
    const int d = idx & (cDI - 1);
    const int l = (idx >> 10) & (cL - 1);
    const int b = idx >> 20;
    float s = bias[d];
#pragma unroll
    for (int j = 0; j < cKC; j++) {
        const int ls = l + j - (cKC - 1);
        if (ls >= 0) s += w[d * cKC + j] * xr[((long)(b * cL + ls)) * (2 * cDI) + d];
    }
    s = s / (1.f + __expf(-s));
    xm[(long)idx] = s;
    xmb[(long)idx] = __float2bfloat16(s);
}

// =====================================================================
// Chunk-parallel selective scan, 4 states (n) per thread, NCH=32 chunks.
// Summary layout: idx = ((b*NCH+ch)*DI+d)*DS+n
// Thread mapping idx4 bits: ng[1:0], d[11:2], ch[16:12], b[17]
// =====================================================================
__global__ void scan_phase1(const float* __restrict__ xm, const float* __restrict__ delta,
                            const float* __restrict__ xdbl, const float* __restrict__ Alog,
                            float* __restrict__ aprod_out, float* __restrict__ send_out)
{
    const int idx4 = blockIdx.x * 256 + threadIdx.x;   // cB*cNCH*cDI*4
    const int ng = idx4 & 3;
    const int d  = (idx4 >> 2) & (cDI - 1);
    const int ch = (idx4 >> 12) & (cNCH - 1);
    const int b  = idx4 >> 17;
    const float4 Al = *(const float4*)(Alog + d * cDS + 4 * ng);
    const float A0 = -__expf(Al.x), A1 = -__expf(Al.y), A2 = -__expf(Al.z), A3 = -__expf(Al.w);
    float s0 = 0.f, s1 = 0.f, s2 = 0.f, s3 = 0.f;
    float p0 = 1.f, p1 = 1.f, p2 = 1.f, p3 = 1.f;
    const int l0 = ch * cCHL;
    const float* dp = delta + (long)(b * cL + l0) * cDI + d;
    const float* up = xm    + (long)(b * cL + l0) * cDI + d;
    const float* xb = xdbl  + (long)(b * cL + l0) * 64 + cDTR + 4 * ng;
    for (int t = 0; t < cCHL; t++) {
        const float dl = dp[(long)t * cDI];
        const float du = dl * up[(long)t * cDI];
        const float4 Bv = *(const float4*)(xb + (long)t * 64);
        const float a0 = __expf(dl * A0), a1 = __expf(dl * A1);
        const float a2 = __expf(dl * A2), a3 = __expf(dl * A3);
        s0 = a0 * s0 + du * Bv.x; p0 *= a0;
        s1 = a1 * s1 + du * Bv.y; p1 *= a1;
        s2 = a2 * s2 + du * Bv.z; p2 *= a2;
        s3 = a3 * s3 + du * Bv.w; p3 *= a3;
    }
    const long base4 = (((long)(b * cNCH + ch) * cDI + d) * cDS) + 4 * ng;
    float4 pv = { p0, p1, p2, p3 };
    float4 sv = { s0, s1, s2, s3 };
    *(float4*)(aprod_out + base4) = pv;
    *(float4*)(send_out + base4)  = sv;
}

__global__ void scan_phase2(const float* __restrict__ aprod, const float* __restrict__ send,
                            float* __restrict__ sinit)
{
    const int j = blockIdx.x * 256 + threadIdx.x;
    const int n = j & (cDS - 1);
    const int d = (j >> 4) & (cDI - 1);
    const int b = j >> 14;
    float s = 0.f;
#pragma unroll
    for (int c = 0; c < cNCH; c++) {
        const long off = (((long)(b * cNCH + c) * cDI + d) * cDS) + n;
        sinit[off] = s;
        s = aprod[off] * s + send[off];
    }
}

__global__ void scan_phase3(const float* __restrict__ xm, const float* __restrict__ delta,
                            const float* __restrict__ xdbl, const float* __restrict__ Alog,
                            const float* __restrict__ Dv, const float* __restrict__ xr,
                            const float* __restrict__ sinit, bf16* __restrict__ y)
{
    const int idx4 = blockIdx.x * 256 + threadIdx.x;   // cB*cNCH*cDI*4
    const int ng = idx4 & 3;
    const int d  = (idx4 >> 2) & (cDI - 1);
    const int ch = (idx4 >> 12) & (cNCH - 1);
    const int b  = idx4 >> 17;
    const float4 Al = *(const float4*)(Alog + d * cDS + 4 * ng);
    const float A0 = -__expf(Al.x), A1 = -__expf(Al.y), A2 = -__expf(Al.z), A3 = -__expf(Al.w);
    const float Dval = Dv[d];
    const long base4 = (((long)(b * cNCH + ch) * cDI + d) * cDS) + 4 * ng;
    float4 st = *(const float4*)(sinit + base4);
    float s0 = st.x, s1 = st.y, s2 = st.z, s3 = st.w;
    const int l0 = ch * cCHL;
    const float* dp = delta + (long)(b * cL + l0) * cDI + d;
    const float* up = xm    + (long)(b * cL + l0) * cDI + d;
    const float* xb = xdbl  + (long)(b * cL + l0) * 64 + cDTR + 4 * ng;
    const float* xc = xb + cDS;
    const float* rp = xr + (long)(b * cL + l0) * (2 * cDI) + cDI + d;
    bf16* yp = y + (long)(b * cL + l0) * cDI + d;
    for (int t = 0; t < cCHL; t++) {
        const float dl = dp[(long)t * cDI];
        const float u  = up[(long)t * cDI];
        const float du = dl * u;
        const float4 Bv = *(const float4*)(xb + (long)t * 64);
        const float4 Cv = *(const float4*)(xc + (long)t * 64);
        const float a0 = __expf(dl * A0), a1 = __expf(dl * A1);
        const float a2 = __expf(dl * A2), a3 = __expf(dl * A3);
        s0 = a0 * s0 + du * Bv.x;
        s1 = a1 * s1 + du * Bv.y;
        s2 = a2 * s2 + du * Bv.z;
        s3 = a3 * s3 + du * Bv.w;
        float c = s0 * Cv.x;
        c = fmaf(s1, Cv.y, c);
        c = fmaf(s2, Cv.z, c);
        c = fmaf(s3, Cv.w, c);
        c += __shfl_xor(c, 1);
        c += __shfl_xor(c, 2);
        if (ng == 0) {
            const float res = rp[(long)t * 2 * cDI];
            const float sig = 1.f / (1.f + __expf(-res));
            yp[(long)t * cDI] = __float2bfloat16((c + u * Dval) * (res * sig));
        }
    }
}

// =====================================================================
extern "C" void kernel_launch(void* const* d_in, const int* in_sizes, int n_in,
                              void* d_out, int out_size, void* d_ws, size_t ws_size,
                              hipStream_t stream)
{
    const float* x       = (const float*)d_in[0];
    const float* enc     = (const float*)d_in[1];
    const float* W_in    = (const float*)d_in[2];
    const float* b_in    = (const float*)d_in[3];
    const float* m_norm_w= (const float*)d_in[4];
    const float* m_in_w  = (const float*)d_in[5];
    const float* m_conv_w= (const float*)d_in[6];
    const float* m_conv_b= (const float*)d_in[7];
    const float* m_xproj = (const float*)d_in[8];
    const float* m_dt_w  = (const float*)d_in[9];
    const float* m_dt_b  = (const float*)d_in[10];
    const float* m_Alog  = (const float*)d_in[11];
    const float* m_D     = (const float*)d_in[12];
    const float* m_out_w = (const float*)d_in[13];
    const float* a_in_w  = (const float*)d_in[14];
    const float* a_in_b  = (const float*)d_in[15];
    const float* a_out_w = (const float*)d_in[16];
    const float* a_out_b = (const float*)d_in[17];
    const float* a_ln_w  = (const float*)d_in[18];
    const float* a_ln_b  = (const float*)d_in[19];
    const float* normf_w = (const float*)d_in[20];
    const float* W_out   = (const float*)d_in[21];
    float* out = (float*)d_out;

    float* ws = (float*)d_ws;
    long off = 0;
    auto allocf = [&](long n) { float* p = ws + off; off += n; return p; };

    const long M1 = 1 << 20;
    float* bufH    = allocf(M1);
    float* bufPre  = allocf(M1);         // also xproj split-K partials
    float* bufXR   = allocf(4 * M1);
    float* bufXM   = allocf(2 * M1);
    float* bufDelta= allocf(2 * M1);
    float* bufXDBL = allocf(M1 / 8);
    bf16* bufU    = (bf16*)allocf(M1 / 2);      // 2048x512 bf16
    bf16* bufHb   = (bf16*)allocf(M1 / 2);
    bf16* bufXMb  = (bf16*)allocf(M1);          // 2048x1024 bf16
    bf16* bufXDBLb= (bf16*)allocf(M1 / 16);
    bf16* bufY    = (bf16*)allocf(M1);          // 2048x1024 bf16; send (f32) during scan
    bf16* bufQ    = (bf16*)allocf(M1 / 2);
    bf16* bufKV   = (bf16*)allocf(M1);          // [K | V]; aprod (f32) during scan
    bf16* bufVT   = (bf16*)allocf(M1 / 2);      // sinit (f32, spans VT+O) during scan
    bf16* bufO    = (bf16*)allocf(M1 / 2);
    bf16* encb    = (bf16*)allocf(M1 / 2);
    bf16* w_in_b  = (bf16*)allocf(2 * M1);      // mamba in_w (4 layers)
    bf16* w_xp_b  = (bf16*)allocf(M1 / 8);
    bf16* w_dt_b  = (bf16*)allocf(M1 / 16);
    bf16* w_out_b = (bf16*)allocf(M1);
    bf16* w_ain_b = (bf16*)allocf(3 * M1 / 2);
    bf16* w_aout_b= (bf16*)allocf(M1 / 2);
    bf16* x_pad   = (bf16*)allocf(2048L * 96 / 2);   // x zero-padded K=96
    bf16* w_inp_b = (bf16*)allocf(512L * 96 / 2);    // W_in zero-padded K=96
    bf16* w_outf_b= (bf16*)allocf(80L * 512 / 2);    // W_out bf16

    // scan summaries at NCH=32: B*NCH*DI*DS = 1M floats each, overlaid on
    // regions dead during the mamba half (sequential-stream safe):
    float* bufAP  = (float*)bufKV;               // aprod: 1M floats
    float* bufSE  = (float*)bufY;                // send:  1M floats
    float* bufSI  = (float*)bufVT;               // sinit: 1M floats (spans VT+O)

    const int Mrows = cB * cL;   // 2048
    const long SUMSZ4 = (long)cB * cNCH * cDI * 4;   // scan threads (4 n each) = 262144

    // ---- one-time conversions (weights + enc + padded edges) ----
    cvt(enc,      encb,    (long)cB * cLE * cDM, stream);
    cvt(m_in_w,   w_in_b,  (long)cLAYERS * 2 * cDI * cDM, stream);
    cvt(m_xproj,  w_xp_b,  (long)cLAYERS * 64 * cDI, stream);
    cvt(m_dt_w,   w_dt_b,  (long)cLAYERS * cDI * cDTR, stream);
    cvt(m_out_w,  w_out_b, (long)cLAYERS * cDM * cDI, stream);
    cvt(a_in_w,   w_ain_b, (long)cLAYERS * 3 * cDM * cDM, stream);
    cvt(a_out_w,  w_aout_b,(long)cLAYERS * cDM * cDM, stream);
    cvt(W_out,    w_outf_b,(long)cNM * cDM, stream);
    cvt_pad_kernel<<<(Mrows * 96 + 255) / 256, 256, 0, stream>>>(x, x_pad, Mrows, cNM, 96);
    cvt_pad_kernel<<<(cDM * 96 + 255) / 256, 256, 0, stream>>>(W_in, w_inp_b, cDM, cNM, 96);

    // h = x @ W_in.T + b_in   (K padded 80->96, MFMA 64^2)
    bgemm_plain(0, 64, 64, x_pad, w_inp_b, b_in, nullptr, bufH, nullptr,
                Mrows, cDM, 96, 96, 96, cDM, 0, 0, stream);

    for (int i = 0; i < cLAYERS; i++) {
        const float* norm_w = m_norm_w + (long)i * cDM;
        const bf16*  in_w   = w_in_b   + (long)i * 2 * cDI * cDM;
        const float* conv_w = m_conv_w + (long)i * cDI * cKC;
        const float* conv_b = m_conv_b + (long)i * cDI;
        const bf16*  xproj  = w_xp_b   + (long)i * 64 * cDI;
        const bf16*  dt_w   = w_dt_b   + (long)i * cDI * cDTR;
        const float* dt_b   = m_dt_b   + (long)i * cDI;
        const float* Alog   = m_Alog   + (long)i * cDI * cDS;
        const float* Dv     = m_D      + (long)i * cDI;
        const bf16*  out_w  = w_out_b  + (long)i * cDM * cDI;
        const bf16*  ain_w  = w_ain_b  + (long)i * 3 * cDM * cDM;
        const float* ain_b  = a_in_b   + (long)i * 3 * cDM;
        const bf16*  aout_w = w_aout_b + (long)i * cDM * cDM;
        const float* aout_b = a_out_b  + (long)i * cDM;
        const float* ln_w   = a_ln_w   + (long)i * cDM;
        const float* ln_b   = a_ln_b   + (long)i * cDM;

        // ---- mamba ----
        rmsnorm_kernel<<<Mrows, 256, 0, stream>>>(bufH, norm_w, nullptr, bufU, cDM);
        bgemm_plain(0, 64, 128, bufU, in_w, nullptr, nullptr, bufXR, nullptr,
                    Mrows, 2 * cDI, cDM, cDM, cDM, 2 * cDI, 0, 0, stream);
        conv_silu_kernel<<<(cB * cL * cDI) / 256, 256, 0, stream>>>(bufXR, conv_w, conv_b, bufXM, bufXMb);
        // x_dbl = xm @ xproj.T : split-K x8
        bgemm(0, 64, 64, bufXMb, xproj, nullptr, nullptr, bufPre, nullptr,
              Mrows, 64, cDI / 8, cDI, cDI, 64, 0, 0,
              8, 1, 128, 0, 128, 0, (long)Mrows * 64, 0, 0, 0, stream);
        splitk_reduce_kernel<<<(Mrows * 64 / 4 + 255) / 256, 256, 0, stream>>>(
            bufPre, bufXDBL, bufXDBLb, Mrows * 64 / 4, Mrows * 64 / 4, 8);
        bgemm_plain(1, 64, 128, bufXDBLb, dt_w, dt_b, nullptr, bufDelta, nullptr,
                    Mrows, cDI, cDTR, 64, cDTR, cDI, 0, 0, stream);
        scan_phase1<<<(int)(SUMSZ4 / 256), 256, 0, stream>>>(bufXM, bufDelta, bufXDBL, Alog, bufAP, bufSE);
        scan_phase2<<<(cB * cDI * cDS) / 256, 256, 0, stream>>>(bufAP, bufSE, bufSI);
        scan_phase3<<<(int)(SUMSZ4 / 256), 256, 0, stream>>>(bufXM, bufDelta, bufXDBL, Alog, Dv, bufXR, bufSI, bufY);
        bgemm_plain(0, 64, 64, bufY, out_w, nullptr, bufH, bufH, bufHb,
                    Mrows, cDM, cDI, cDI, cDI, cDM, cDM, cDM, stream);

        // ---- cross attention ----
        bgemm_plain(0, 64, 64, bufHb, ain_w, ain_b, nullptr, nullptr, bufQ,
                    Mrows, cDM, cDM, cDM, cDM, 0, cDM, 0, stream);
        bgemm_plain(0, 64, 128, encb, ain_w + (long)cDM * cDM, ain_b + cDM, nullptr, nullptr, bufKV,
                    Mrows, 2 * cDM, cDM, cDM, cDM, 0, 2 * cDM, 0, stream);
        {
            dim3 g(cLE / 32, cDM / 32, cB);
            transpose_bf16_kernel<<<g, 256, 0, stream>>>(bufKV, bufVT, 2 * cDM, cDM);
        }
        // fused flash attention: Q x K -> online softmax -> x V
        {
            dim3 g(cL / 32, cB * cH);
            flash_attn_kernel<<<g, 128, 0, stream>>>(bufQ, bufKV, bufVT, bufO,
                                                     0.08838834764831845f);
        }
        // pre = o @ aout_w.T + aout_b + h ; h = LN(pre)
        bgemm_plain(0, 64, 64, bufO, aout_w, aout_b, bufH, bufPre, nullptr,
                    Mrows, cDM, cDM, cDM, cDM, cDM, 0, cDM, stream);
        layernorm_kernel<<<Mrows, 256, 0, stream>>>(bufPre, ln_w, ln_b, bufH, bufHb, cDM);
    }

    // final: out = rmsnorm(h) @ W_out.T   (MFMA, 64^2 tile, N=80 edge-clamped)
    rmsnorm_kernel<<<Mrows, 256, 0, stream>>>(bufH, normf_w, nullptr, bufU, cDM);
    bgemm_plain(0, 64, 64, bufU, w_outf_b, nullptr, nullptr, out, nullptr,
                Mrows, cNM, cDM, cDM, cDM, cNM, 0, 0, stream);
}

// Round 9
// 858.690 us; speedup vs baseline: 8.2392x; 1.0142x over previous
//
#include <hip/hip_runtime.h>
#include <hip/hip_bf16.h>
#include <math.h>

typedef __hip_bfloat16 bf16;
typedef __attribute__((ext_vector_type(8))) short short8x;
typedef __attribute__((ext_vector_type(4))) float f32x4;

// ---- problem constants ----
static constexpr int cB   = 2;
static constexpr int cL   = 1024;
static constexpr int cLE  = 1024;
static constexpr int cNM  = 80;
static constexpr int cDM  = 512;
static constexpr int cLAYERS = 4;
static constexpr int cDS  = 16;
static constexpr int cKC  = 4;     // conv taps
static constexpr int cH   = 4;     // heads
static constexpr int cDI  = 1024;  // EXP*DM
static constexpr int cDTR = 32;
static constexpr int cHD  = 128;   // head dim

static constexpr int cNCH = 64;    // scan chunks (bit extraction below assumes 64)
static constexpr int cCHL = cL / cNCH;  // 16 steps per chunk

#define GLL16(g, l) __builtin_amdgcn_global_load_lds( \
    (const __attribute__((address_space(1))) void*)(g), \
    (__attribute__((address_space(3))) void*)(l), 16, 0, 0)

// =====================================================================
// bf16 MFMA GEMM, BMxBN tile, 4 waves (2x2), K-step 32.
//   C = act( A @ W^T + bias ) + addv ; A: M x K bf16 (lda), W: N x K bf16 (ldw)
//   Writes f32 C (if Cf) and/or bf16 C (if Cb). Batched over blockIdx.z.
// =====================================================================
template<int ACT, int BM, int BN>
__global__ __launch_bounds__(256)
void bgemm_kernel(const bf16* __restrict__ A, const bf16* __restrict__ W,
                  const float* __restrict__ bias, const float* __restrict__ addv,
                  float* __restrict__ Cf, bf16* __restrict__ Cb,
                  int M, int N, int Kd, int lda, int ldw, int ldcf, int ldcb, int ldadd,
                  int bdiv, long sA1, long sA2, long sW1, long sW2,
                  long sCf1, long sCf2, long sCb1, long sCb2)
{
    constexpr int RM = BM / 32;            // per-wave 16-row frag repeats
    constexpr int RN = BN / 32;
    const int z = blockIdx.z;
    const int i1 = z / bdiv, i2 = z % bdiv;
    A += i1 * sA1 + i2 * sA2;
    W += i1 * sW1 + i2 * sW2;

    const int bm = blockIdx.y * BM;
    const int bn = blockIdx.x * BN;
    const int tid = threadIdx.x;
    const int lane = tid & 63;
    const int wid = tid >> 6;              // 0..3
    const int wr = wid >> 1, wc = wid & 1; // 2x2 wave grid

    __shared__ bf16 As[BM * 32];
    __shared__ bf16 Bs[BN * 32];

    f32x4 acc[RM][RN] = {};

    const int r_in = lane >> 2;            // 0..15
    const int kb   = (lane & 3) * 8;       // k offset for staging
    const int hi   = lane >> 4;            // 0..3
    const int rc   = lane & 15;

    for (int k0 = 0; k0 < Kd; k0 += 32) {
#pragma unroll
        for (int iss = 0; iss < BM / 64; iss++) {
            const int row = wid * (BM / 4) + iss * 16 + r_in;
            int gm = bm + row; if (gm >= M) gm = M - 1;
            const bf16* ga = A + (long)gm * lda + k0 + kb;
            GLL16(ga, As + (wid * (BM / 4) + iss * 16) * 32);
        }
#pragma unroll
        for (int iss = 0; iss < BN / 64; iss++) {
            const int row = wid * (BN / 4) + iss * 16 + r_in;
            int gn = bn + row; if (gn >= N) gn = N - 1;
            const bf16* gb = W + (long)gn * ldw + k0 + kb;
            GLL16(gb, Bs + (wid * (BN / 4) + iss * 16) * 32);
        }
        asm volatile("s_waitcnt vmcnt(0)" ::: "memory");
        __syncthreads();

        short8x af[RM], bfv[RN];
#pragma unroll
        for (int i = 0; i < RM; i++)
            af[i] = *(const short8x*)(As + (wr * (BM / 2) + i * 16 + rc) * 32 + hi * 8);
#pragma unroll
        for (int j = 0; j < RN; j++)
            bfv[j] = *(const short8x*)(Bs + (wc * (BN / 2) + j * 16 + rc) * 32 + hi * 8);
#pragma unroll
        for (int i = 0; i < RM; i++)
#pragma unroll
            for (int j = 0; j < RN; j++)
                acc[i][j] = __builtin_amdgcn_mfma_f32_16x16x32_bf16(af[i], bfv[j], acc[i][j], 0, 0, 0);
        __syncthreads();
    }

    // epilogue: C/D frag mapping col=lane&15, row=(lane>>4)*4+r  [m89-verified]
    const long cfo = i1 * sCf1 + i2 * sCf2;
    const long cbo = i1 * sCb1 + i2 * sCb2;
#pragma unroll
    for (int i = 0; i < RM; i++) {
#pragma unroll
        for (int r = 0; r < 4; r++) {
            const int gm = bm + wr * (BM / 2) + i * 16 + hi * 4 + r;
            if (gm >= M) continue;
#pragma unroll
            for (int j = 0; j < RN; j++) {
                const int gn = bn + wc * (BN / 2) + j * 16 + rc;
                if (gn >= N) continue;
                float v = acc[i][j][r];
                if (bias) v += bias[gn];
                if (ACT == 1) v = (v > 20.f) ? v : log1pf(__expf(v));
                if (addv) v += addv[cfo + (long)gm * ldadd + gn];
                if (Cf) Cf[cfo + (long)gm * ldcf + gn] = v;
                if (Cb) Cb[cbo + (long)gm * ldcb + gn] = __float2bfloat16(v);
            }
        }
    }
}

static inline void bgemm(int ACT, int BM, int BN, const bf16* A, const bf16* W, const float* bias,
                         const float* addv, float* Cf, bf16* Cb,
                         int M, int N, int Kd, int lda, int ldw, int ldcf, int ldcb, int ldadd,
                         int nz, int bdiv, long sA1, long sA2, long sW1, long sW2,
                         long sCf1, long sCf2, long sCb1, long sCb2, hipStream_t s)
{
    dim3 g((N + BN - 1) / BN, (M + BM - 1) / BM, nz), b(256);
#define BG_ARGS A, W, bias, addv, Cf, Cb, M, N, Kd, lda, ldw, ldcf, ldcb, ldadd, \
                bdiv, sA1, sA2, sW1, sW2, sCf1, sCf2, sCb1, sCb2
    if (BM == 128) {
        if (ACT == 1) bgemm_kernel<1, 128, 128><<<g, b, 0, s>>>(BG_ARGS);
        else          bgemm_kernel<0, 128, 128><<<g, b, 0, s>>>(BG_ARGS);
    } else if (BN == 128) {
        if (ACT == 1) bgemm_kernel<1, 64, 128><<<g, b, 0, s>>>(BG_ARGS);
        else          bgemm_kernel<0, 64, 128><<<g, b, 0, s>>>(BG_ARGS);
    } else {
        bgemm_kernel<0, 64, 64><<<g, b, 0, s>>>(BG_ARGS);
    }
#undef BG_ARGS
}

static inline void bgemm_plain(int ACT, int BM, int BN, const bf16* A, const bf16* W,
                               const float* bias, const float* addv, float* Cf, bf16* Cb,
                               int M, int N, int Kd, int lda, int ldw, int ldcf, int ldcb,
                               int ldadd, hipStream_t s)
{
    bgemm(ACT, BM, BN, A, W, bias, addv, Cf, Cb, M, N, Kd, lda, ldw, ldcf, ldcb, ldadd,
          1, 1, 0, 0, 0, 0, 0, 0, 0, 0, s);
}

// =====================================================================
// Fused flash cross-attention (unchanged from round 8; verified).
// =====================================================================
__global__ __launch_bounds__(128)
void flash_attn_kernel(const bf16* __restrict__ Qp, const bf16* __restrict__ Kp,
                       const bf16* __restrict__ VTp, bf16* __restrict__ Op, float scale)
{
    const int qt = blockIdx.x;            // 0..31
    const int bh = blockIdx.y;            // b*H + h
    const int b = bh >> 2, h = bh & 3;
    const int tid = threadIdx.x;
    const int w = tid >> 6;               // 0..1
    const int lane = tid & 63;
    const int rc = lane & 15, hi = lane >> 4;
    const int rlo = rc & 7;

    __shared__ bf16 Qs[32 * 128];
    __shared__ bf16 Ks[64 * 128];
    __shared__ bf16 Vs[128 * 64];
    __shared__ bf16 Ps[32 * 64];

    {
        const bf16* qb = Qp + ((long)(b * cL + qt * 32)) * cDM + h * cHD;
#pragma unroll
        for (int c = 0; c < 4; c++) {
            const int row = w * 16 + c * 4 + (lane >> 4);
            const int gc = (lane & 15) ^ (row & 7);
            GLL16(qb + (long)row * cDM + gc * 8, Qs + (w * 16 + c * 4) * 128);
        }
    }
    asm volatile("s_waitcnt vmcnt(0)" ::: "memory");
    __syncthreads();

    short8x aq[4];
#pragma unroll
    for (int kk = 0; kk < 4; kk++) {
        const int sc = (kk * 4 + hi) ^ rlo;
        aq[kk] = *(const short8x*)(Qs + (w * 16 + rc) * 128 + sc * 8);
    }

    float m_r[4], l_r[4];
#pragma unroll
    for (int r = 0; r < 4; r++) { m_r[r] = -1e30f; l_r[r] = 0.f; }
    f32x4 oacc[8] = {};

    const bf16* kb0 = Kp + ((long)(b * cLE)) * (2 * cDM) + h * cHD;
    const bf16* vb0 = VTp + ((long)(b * cDM + h * cHD)) * cLE;

    for (int kt = 0; kt < 16; kt++) {
        __syncthreads();
#pragma unroll
        for (int c = 0; c < 8; c++) {
            const int row = w * 32 + c * 4 + (lane >> 4);
            const int gc = (lane & 15) ^ (row & 7);
            GLL16(kb0 + ((long)(kt * 64 + row)) * (2 * cDM) + gc * 8,
                  Ks + (w * 32 + c * 4) * 128);
        }
#pragma unroll
        for (int c = 0; c < 8; c++) {
            const int row = w * 64 + c * 8 + (lane >> 3);
            const int gc = (lane & 7) ^ (row & 7);
            GLL16(vb0 + (long)row * cLE + kt * 64 + gc * 8,
                  Vs + (w * 64 + c * 8) * 64);
        }
        asm volatile("s_waitcnt vmcnt(0)" ::: "memory");
        __syncthreads();

        f32x4 s[4] = {};
#pragma unroll
        for (int kk = 0; kk < 4; kk++) {
            const int sc = (kk * 4 + hi) ^ rlo;
#pragma unroll
            for (int j = 0; j < 4; j++) {
                short8x bk = *(const short8x*)(Ks + (j * 16 + rc) * 128 + sc * 8);
                s[j] = __builtin_amdgcn_mfma_f32_16x16x32_bf16(aq[kk], bk, s[j], 0, 0, 0);
            }
        }

        float p[4][4];
        float esc[4];
#pragma unroll
        for (int r = 0; r < 4; r++) {
            const float v0 = s[0][r] * scale, v1 = s[1][r] * scale;
            const float v2 = s[2][r] * scale, v3 = s[3][r] * scale;
            float mx = fmaxf(fmaxf(v0, v1), fmaxf(v2, v3));
            mx = fmaxf(mx, __shfl_xor(mx, 1));
            mx = fmaxf(mx, __shfl_xor(mx, 2));
            mx = fmaxf(mx, __shfl_xor(mx, 4));
            mx = fmaxf(mx, __shfl_xor(mx, 8));
            const float mn = fmaxf(m_r[r], mx);
            p[0][r] = __expf(v0 - mn);
            p[1][r] = __expf(v1 - mn);
            p[2][r] = __expf(v2 - mn);
            p[3][r] = __expf(v3 - mn);
            float rs = (p[0][r] + p[1][r]) + (p[2][r] + p[3][r]);
            rs += __shfl_xor(rs, 1);
            rs += __shfl_xor(rs, 2);
            rs += __shfl_xor(rs, 4);
            rs += __shfl_xor(rs, 8);
            esc[r] = __expf(m_r[r] - mn);
            l_r[r] = l_r[r] * esc[r] + rs;
            m_r[r] = mn;
        }
#pragma unroll
        for (int j2 = 0; j2 < 8; j2++)
#pragma unroll
            for (int r = 0; r < 4; r++)
                oacc[j2][r] *= esc[r];
#pragma unroll
        for (int j = 0; j < 4; j++)
#pragma unroll
            for (int r = 0; r < 4; r++) {
                const int q = w * 16 + hi * 4 + r;
                const int cp = (j * 2 + (rc >> 3)) ^ (q & 7);
                Ps[q * 64 + cp * 8 + (rc & 7)] = __float2bfloat16(p[j][r]);
            }
        __syncthreads();
#pragma unroll
        for (int ks = 0; ks < 2; ks++) {
            const int sc = (ks * 4 + hi) ^ rlo;
            short8x ap = *(const short8x*)(Ps + (w * 16 + rc) * 64 + sc * 8);
#pragma unroll
            for (int j2 = 0; j2 < 8; j2++) {
                short8x bv = *(const short8x*)(Vs + (j2 * 16 + rc) * 64 + sc * 8);
                oacc[j2] = __builtin_amdgcn_mfma_f32_16x16x32_bf16(ap, bv, oacc[j2], 0, 0, 0);
            }
        }
    }

    float inv[4];
#pragma unroll
    for (int r = 0; r < 4; r++) inv[r] = 1.f / l_r[r];
    bf16* ob = Op + ((long)(b * cL + qt * 32)) * cDM + h * cHD;
#pragma unroll
    for (int j2 = 0; j2 < 8; j2++)
#pragma unroll
        for (int r = 0; r < 4; r++)
            ob[(long)(w * 16 + hi * 4 + r) * cDM + j2 * 16 + rc] =
                __float2bfloat16(oacc[j2][r] * inv[r]);
}

// =====================================================================
// split-K partial reduce:  out = sum_s parts[s]  (f32 + bf16 outputs)
// =====================================================================
__global__ void splitk_reduce_kernel(const float* __restrict__ parts, float* __restrict__ outf,
                                     bf16* __restrict__ outb, int n4, int sliceN4, int S)
{
    const int i = blockIdx.x * 256 + threadIdx.x;
    if (i >= n4) return;
    float4 a = ((const float4*)parts)[i];
    for (int s2 = 1; s2 < S; s2++) {
        float4 b2 = ((const float4*)parts)[i + (long)s2 * sliceN4];
        a.x += b2.x; a.y += b2.y; a.z += b2.z; a.w += b2.w;
    }
    ((float4*)outf)[i] = a;
    bf16 b0 = __float2bfloat16(a.x), b1 = __float2bfloat16(a.y);
    bf16 b2 = __float2bfloat16(a.z), b3 = __float2bfloat16(a.w);
    short4 pk = { *(short*)&b0, *(short*)&b1, *(short*)&b2, *(short*)&b3 };
    ((short4*)outb)[i] = pk;
}

// =====================================================================
// f32 -> bf16 flat convert
// =====================================================================
__global__ void f32_to_bf16_kernel(const float* __restrict__ in, bf16* __restrict__ out, long n)
{
    long i = ((long)blockIdx.x * 256 + threadIdx.x) * 4;
    if (i + 3 < n) {
        float4 v = *(const float4*)(in + i);
        out[i]     = __float2bfloat16(v.x);
        out[i + 1] = __float2bfloat16(v.y);
        out[i + 2] = __float2bfloat16(v.z);
        out[i + 3] = __float2bfloat16(v.w);
    } else {
        for (; i < n; i++) out[i] = __float2bfloat16(in[i]);
    }
}
static inline void cvt(const float* in, bf16* out, long n, hipStream_t s)
{
    int blocks = (int)((n / 4 + 255) / 256);
    f32_to_bf16_kernel<<<blocks, 256, 0, s>>>(in, out, n);
}

// f32 (rows x kin) -> bf16 (rows x kout), zero-padded beyond kin
__global__ void cvt_pad_kernel(const float* __restrict__ in, bf16* __restrict__ out,
                               int rows, int kin, int kout)
{
    const int idx = blockIdx.x * 256 + threadIdx.x;
    if (idx >= rows * kout) return;
    const int r = idx / kout, k = idx - r * kout;
    out[idx] = __float2bfloat16(k < kin ? in[(long)r * kin + k] : 0.f);
}

// =====================================================================
// bf16 transpose per batch:  in rows (b*LE+le) x ldin, cols [col0, col0+DM)
//   -> out b: DM x LE
// =====================================================================
__global__ void transpose_bf16_kernel(const bf16* __restrict__ in, bf16* __restrict__ out,
                                      int ldin, int col0)
{
    __shared__ bf16 t[32][33];
    const int b = blockIdx.z;
    const int le0 = blockIdx.x * 32, d0 = blockIdx.y * 32;
    const int tid = threadIdx.x;
    const int c = tid & 31, r = tid >> 5;
    for (int i = r; i < 32; i += 8)
        t[i][c] = in[((long)b * cLE + le0 + i) * ldin + col0 + d0 + c];
    __syncthreads();
    for (int i = r; i < 32; i += 8)
        out[((long)b * cDM + d0 + i) * cLE + le0 + c] = t[c][i];
}

// =====================================================================
// RMSNorm per row (optional f32 and bf16 outputs)
// =====================================================================
__global__ void rmsnorm_kernel(const float* __restrict__ x, const float* __restrict__ w,
                               float* __restrict__ outf, bf16* __restrict__ outb, int Dm)
{
    const int row = blockIdx.x;
    const float* xr = x + (long)row * Dm;
    float s = 0.f;
    for (int i = threadIdx.x; i < Dm; i += 256) { float v = xr[i]; s += v * v; }
    __shared__ float red[5];
    const int lane = threadIdx.x & 63, wv = threadIdx.x >> 6;
#pragma unroll
    for (int off = 1; off < 64; off <<= 1) s += __shfl_xor(s, off);
    if (lane == 0) red[wv] = s;
    __syncthreads();
    if (threadIdx.x == 0) {
        float t = red[0] + red[1] + red[2] + red[3];
        red[4] = rsqrtf(t / Dm + 1e-5f);
    }
    __syncthreads();
    const float scale = red[4];
    for (int i = threadIdx.x; i < Dm; i += 256) {
        float v = xr[i] * scale * w[i];
        if (outf) outf[(long)row * Dm + i] = v;
        if (outb) outb[(long)row * Dm + i] = __float2bfloat16(v);
    }
}

// =====================================================================
// LayerNorm per row -> f32 + bf16 outputs
// =====================================================================
__global__ void layernorm_kernel(const float* __restrict__ x, const float* __restrict__ w,
                                 const float* __restrict__ b, float* __restrict__ outf,
                                 bf16* __restrict__ outb, int Dm)
{
    const int row = blockIdx.x;
    const float* xr = x + (long)row * Dm;
    float s = 0.f, sq = 0.f;
    for (int i = threadIdx.x; i < Dm; i += 256) { float v = xr[i]; s += v; sq += v * v; }
    __shared__ float red[8];
    __shared__ float mv[2];
    const int lane = threadIdx.x & 63, wv = threadIdx.x >> 6;
#pragma unroll
    for (int off = 1; off < 64; off <<= 1) { s += __shfl_xor(s, off); sq += __shfl_xor(sq, off); }
    if (lane == 0) { red[wv] = s; red[4 + wv] = sq; }
    __syncthreads();
    if (threadIdx.x == 0) {
        float ts = red[0] + red[1] + red[2] + red[3];
        float tq = red[4] + red[5] + red[6] + red[7];
        float m = ts / Dm;
        float var = tq / Dm - m * m;
        mv[0] = m;
        mv[1] = rsqrtf(var + 1e-5f);
    }
    __syncthreads();
    const float m = mv[0], rs = mv[1];
    for (int i = threadIdx.x; i < Dm; i += 256) {
        float v = (xr[i] - m) * rs * w[i] + b[i];
        outf[(long)row * Dm + i] = v;
        outb[(long)row * Dm + i] = __float2bfloat16(v);
    }
}

// =====================================================================
// Causal depthwise conv (K=4) + bias + SiLU -> xm f32 + bf16
// =====================================================================
__global__ void conv_silu_kernel(const float* __restrict__ xr, const float* __restrict__ w,
                                 const float* __restrict__ bias, float* __restrict__ xm,
                                 bf16* __restrict__ xmb)
{
    const int idx = blockIdx.x * 256 + threadIdx.x;
    if (idx >= cB * cL * cDI) return;
    const int d = idx & (cDI - 1);
    const int l = (idx >> 10) & (cL - 1);
    const int b = idx >> 20;
    float s = bias[d];
#pragma unroll
    for (int j = 0; j < cKC; j++) {
        const int ls = l + j - (cKC - 1);
        if (ls >= 0) s += w[d * cKC + j] * xr[((long)(b * cL + ls)) * (2 * cDI) + d];
    }
    s = s / (1.f + __expf(-s));
    xm[(long)idx] = s;
    xmb[(long)idx] = __float2bfloat16(s);
}

// =====================================================================
// Chunk-parallel selective scan, 4 states (n) per thread, NCH=64 chunks.
// Summary layout: idx = ((b*NCH+ch)*DI+d)*DS+n
// Thread mapping idx4 bits: ng[1:0], d[11:2], ch[17:12], b[18]
// =====================================================================
__global__ void scan_phase1(const float* __restrict__ xm, const float* __restrict__ delta,
                            const float* __restrict__ xdbl, const float* __restrict__ Alog,
                            float* __restrict__ aprod_out, float* __restrict__ send_out)
{
    const int idx4 = blockIdx.x * 256 + threadIdx.x;   // cB*cNCH*cDI*4
    const int ng = idx4 & 3;
    const int d  = (idx4 >> 2) & (cDI - 1);
    const int ch = (idx4 >> 12) & (cNCH - 1);
    const int b  = idx4 >> 18;
    const float4 Al = *(const float4*)(Alog + d * cDS + 4 * ng);
    const float A0 = -__expf(Al.x), A1 = -__expf(Al.y), A2 = -__expf(Al.z), A3 = -__expf(Al.w);
    float s0 = 0.f, s1 = 0.f, s2 = 0.f, s3 = 0.f;
    float p0 = 1.f, p1 = 1.f, p2 = 1.f, p3 = 1.f;
    const int l0 = ch * cCHL;
    const float* dp = delta + (long)(b * cL + l0) * cDI + d;
    const float* up = xm    + (long)(b * cL + l0) * cDI + d;
    const float* xb = xdbl  + (long)(b * cL + l0) * 64 + cDTR + 4 * ng;
#pragma unroll
    for (int t = 0; t < cCHL; t++) {
        const float dl = dp[(long)t * cDI];
        const float du = dl * up[(long)t * cDI];
        const float4 Bv = *(const float4*)(xb + (long)t * 64);
        const float a0 = __expf(dl * A0), a1 = __expf(dl * A1);
        const float a2 = __expf(dl * A2), a3 = __expf(dl * A3);
        s0 = a0 * s0 + du * Bv.x; p0 *= a0;
        s1 = a1 * s1 + du * Bv.y; p1 *= a1;
        s2 = a2 * s2 + du * Bv.z; p2 *= a2;
        s3 = a3 * s3 + du * Bv.w; p3 *= a3;
    }
    const long base4 = (((long)(b * cNCH + ch) * cDI + d) * cDS) + 4 * ng;
    float4 pv = { p0, p1, p2, p3 };
    float4 sv = { s0, s1, s2, s3 };
    *(float4*)(aprod_out + base4) = pv;
    *(float4*)(send_out + base4)  = sv;
}

__global__ void scan_phase2(const float* __restrict__ aprod, const float* __restrict__ send,
                            float* __restrict__ sinit)
{
    const int j = blockIdx.x * 256 + threadIdx.x;   // cB*cDI*cDS
    const int n = j & (cDS - 1);
    const int d = (j >> 4) & (cDI - 1);
    const int b = j >> 14;
    float s = 0.f;
#pragma unroll
    for (int c = 0; c < cNCH; c++) {
        const long off = (((long)(b * cNCH + c) * cDI + d) * cDS) + n;
        sinit[off] = s;
        s = aprod[off] * s + send[off];
    }
}

__global__ void scan_phase3(const float* __restrict__ xm, const float* __restrict__ delta,
                            const float* __restrict__ xdbl, const float* __restrict__ Alog,
                            const float* __restrict__ Dv, const float* __restrict__ xr,
                            const float* __restrict__ sinit, bf16* __restrict__ y)
{
    const int idx4 = blockIdx.x * 256 + threadIdx.x;   // cB*cNCH*cDI*4
    const int ng = idx4 & 3;
    const int d  = (idx4 >> 2) & (cDI - 1);
    const int ch = (idx4 >> 12) & (cNCH - 1);
    const int b  = idx4 >> 18;
    const float4 Al = *(const float4*)(Alog + d * cDS + 4 * ng);
    const float A0 = -__expf(Al.x), A1 = -__expf(Al.y), A2 = -__expf(Al.z), A3 = -__expf(Al.w);
    const float Dval = Dv[d];
    const long base4 = (((long)(b * cNCH + ch) * cDI + d) * cDS) + 4 * ng;
    float4 st = *(const float4*)(sinit + base4);
    float s0 = st.x, s1 = st.y, s2 = st.z, s3 = st.w;
    const int l0 = ch * cCHL;
    const float* dp = delta + (long)(b * cL + l0) * cDI + d;
    const float* up = xm    + (long)(b * cL + l0) * cDI + d;
    const float* xb = xdbl  + (long)(b * cL + l0) * 64 + cDTR + 4 * ng;
    const float* xc = xb + cDS;
    const float* rp = xr + (long)(b * cL + l0) * (2 * cDI) + cDI + d;
    bf16* yp = y + (long)(b * cL + l0) * cDI + d;
#pragma unroll
    for (int t = 0; t < cCHL; t++) {
        const float dl = dp[(long)t * cDI];
        const float u  = up[(long)t * cDI];
        const float du = dl * u;
        const float4 Bv = *(const float4*)(xb + (long)t * 64);
        const float4 Cv = *(const float4*)(xc + (long)t * 64);
        const float a0 = __expf(dl * A0), a1 = __expf(dl * A1);
        const float a2 = __expf(dl * A2), a3 = __expf(dl * A3);
        s0 = a0 * s0 + du * Bv.x;
        s1 = a1 * s1 + du * Bv.y;
        s2 = a2 * s2 + du * Bv.z;
        s3 = a3 * s3 + du * Bv.w;
        float c = s0 * Cv.x;
        c = fmaf(s1, Cv.y, c);
        c = fmaf(s2, Cv.z, c);
        c = fmaf(s3, Cv.w, c);
        c += __shfl_xor(c, 1);
        c += __shfl_xor(c, 2);
        if (ng == 0) {
            const float res = rp[(long)t * 2 * cDI];
            const float sig = 1.f / (1.f + __expf(-res));
            yp[(long)t * cDI] = __float2bfloat16((c + u * Dval) * (res * sig));
        }
    }
}

// =====================================================================
extern "C" void kernel_launch(void* const* d_in, const int* in_sizes, int n_in,
                              void* d_out, int out_size, void* d_ws, size_t ws_size,
                              hipStream_t stream)
{
    const float* x       = (const float*)d_in[0];
    const float* enc     = (const float*)d_in[1];
    const float* W_in    = (const float*)d_in[2];
    const float* b_in    = (const float*)d_in[3];
    const float* m_norm_w= (const float*)d_in[4];
    const float* m_in_w  = (const float*)d_in[5];
    const float* m_conv_w= (const float*)d_in[6];
    const float* m_conv_b= (const float*)d_in[7];
    const float* m_xproj = (const float*)d_in[8];
    const float* m_dt_w  = (const float*)d_in[9];
    const float* m_dt_b  = (const float*)d_in[10];
    const float* m_Alog  = (const float*)d_in[11];
    const float* m_D     = (const float*)d_in[12];
    const float* m_out_w = (const float*)d_in[13];
    const float* a_in_w  = (const float*)d_in[14];
    const float* a_in_b  = (const float*)d_in[15];
    const float* a_out_w = (const float*)d_in[16];
    const float* a_out_b = (const float*)d_in[17];
    const float* a_ln_w  = (const float*)d_in[18];
    const float* a_ln_b  = (const float*)d_in[19];
    const float* normf_w = (const float*)d_in[20];
    const float* W_out   = (const float*)d_in[21];
    float* out = (float*)d_out;

    float* ws = (float*)d_ws;
    long off = 0;
    auto allocf = [&](long n) { float* p = ws + off; off += n; return p; };

    const long M1 = 1 << 20;
    float* bufH    = allocf(M1);
    float* bufPre  = allocf(M1);         // also xproj split-K partials
    float* bufXR   = allocf(4 * M1);
    float* bufXM   = allocf(2 * M1);
    float* bufDelta= allocf(2 * M1);
    float* bufXDBL = allocf(M1 / 8);
    bf16* bufU    = (bf16*)allocf(M1 / 2);      // 2048x512 bf16
    bf16* bufHb   = (bf16*)allocf(M1 / 2);
    bf16* bufXMb  = (bf16*)allocf(M1);          // 2048x1024 bf16
    bf16* bufXDBLb= (bf16*)allocf(M1 / 16);
    bf16* bufY    = (bf16*)allocf(M1);          // 2048x1024 bf16
    bf16* bufQ    = (bf16*)allocf(M1 / 2);
    bf16* bufKV   = (bf16*)allocf(M1);          // [K | V]
    bf16* bufVT   = (bf16*)allocf(M1 / 2);
    bf16* bufO    = (bf16*)allocf(M1 / 2);
    bf16* encb    = (bf16*)allocf(M1 / 2);
    bf16* w_in_b  = (bf16*)allocf(2 * M1);      // mamba in_w (4 layers)
    bf16* w_xp_b  = (bf16*)allocf(M1 / 8);
    bf16* w_dt_b  = (bf16*)allocf(M1 / 16);
    bf16* w_out_b = (bf16*)allocf(M1);
    bf16* w_ain_b = (bf16*)allocf(3 * M1 / 2);
    bf16* w_aout_b= (bf16*)allocf(M1 / 2);
    bf16* x_pad   = (bf16*)allocf(2048L * 96 / 2);   // x zero-padded K=96
    bf16* w_inp_b = (bf16*)allocf(512L * 96 / 2);    // W_in zero-padded K=96
    bf16* w_outf_b= (bf16*)allocf(80L * 512 / 2);    // W_out bf16
    // dedicated scan summaries at NCH=64: B*NCH*DI*DS = 2M floats each
    float* bufAP  = allocf(2 * M1);
    float* bufSE  = allocf(2 * M1);
    float* bufSI  = allocf(2 * M1);

    const int Mrows = cB * cL;   // 2048
    const long SUMSZ4 = (long)cB * cNCH * cDI * 4;   // scan threads (4 n each) = 524288

    // ---- one-time conversions (weights + enc + padded edges) ----
    cvt(enc,      encb,    (long)cB * cLE * cDM, stream);
    cvt(m_in_w,   w_in_b,  (long)cLAYERS * 2 * cDI * cDM, stream);
    cvt(m_xproj,  w_xp_b,  (long)cLAYERS * 64 * cDI, stream);
    cvt(m_dt_w,   w_dt_b,  (long)cLAYERS * cDI * cDTR, stream);
    cvt(m_out_w,  w_out_b, (long)cLAYERS * cDM * cDI, stream);
    cvt(a_in_w,   w_ain_b, (long)cLAYERS * 3 * cDM * cDM, stream);
    cvt(a_out_w,  w_aout_b,(long)cLAYERS * cDM * cDM, stream);
    cvt(W_out,    w_outf_b,(long)cNM * cDM, stream);
    cvt_pad_kernel<<<(Mrows * 96 + 255) / 256, 256, 0, stream>>>(x, x_pad, Mrows, cNM, 96);
    cvt_pad_kernel<<<(cDM * 96 + 255) / 256, 256, 0, stream>>>(W_in, w_inp_b, cDM, cNM, 96);

    // h = x @ W_in.T + b_in   (K padded 80->96, MFMA 64^2)
    bgemm_plain(0, 64, 64, x_pad, w_inp_b, b_in, nullptr, bufH, nullptr,
                Mrows, cDM, 96, 96, 96, cDM, 0, 0, stream);

    for (int i = 0; i < cLAYERS; i++) {
        const float* norm_w = m_norm_w + (long)i * cDM;
        const bf16*  in_w   = w_in_b   + (long)i * 2 * cDI * cDM;
        const float* conv_w = m_conv_w + (long)i * cDI * cKC;
        const float* conv_b = m_conv_b + (long)i * cDI;
        const bf16*  xproj  = w_xp_b   + (long)i * 64 * cDI;
        const bf16*  dt_w   = w_dt_b   + (long)i * cDI * cDTR;
        const float* dt_b   = m_dt_b   + (long)i * cDI;
        const float* Alog   = m_Alog   + (long)i * cDI * cDS;
        const float* Dv     = m_D      + (long)i * cDI;
        const bf16*  out_w  = w_out_b  + (long)i * cDM * cDI;
        const bf16*  ain_w  = w_ain_b  + (long)i * 3 * cDM * cDM;
        const float* ain_b  = a_in_b   + (long)i * 3 * cDM;
        const bf16*  aout_w = w_aout_b + (long)i * cDM * cDM;
        const float* aout_b = a_out_b  + (long)i * cDM;
        const float* ln_w   = a_ln_w   + (long)i * cDM;
        const float* ln_b   = a_ln_b   + (long)i * cDM;

        // ---- mamba ----
        rmsnorm_kernel<<<Mrows, 256, 0, stream>>>(bufH, norm_w, nullptr, bufU, cDM);
        bgemm_plain(0, 64, 128, bufU, in_w, nullptr, nullptr, bufXR, nullptr,
                    Mrows, 2 * cDI, cDM, cDM, cDM, 2 * cDI, 0, 0, stream);
        conv_silu_kernel<<<(cB * cL * cDI) / 256, 256, 0, stream>>>(bufXR, conv_w, conv_b, bufXM, bufXMb);
        // x_dbl = xm @ xproj.T : split-K x8
        bgemm(0, 64, 64, bufXMb, xproj, nullptr, nullptr, bufPre, nullptr,
              Mrows, 64, cDI / 8, cDI, cDI, 64, 0, 0,
              8, 1, 128, 0, 128, 0, (long)Mrows * 64, 0, 0, 0, stream);
        splitk_reduce_kernel<<<(Mrows * 64 / 4 + 255) / 256, 256, 0, stream>>>(
            bufPre, bufXDBL, bufXDBLb, Mrows * 64 / 4, Mrows * 64 / 4, 8);
        bgemm_plain(1, 64, 128, bufXDBLb, dt_w, dt_b, nullptr, bufDelta, nullptr,
                    Mrows, cDI, cDTR, 64, cDTR, cDI, 0, 0, stream);
        // chunk-parallel scan (NCH=64 -> 2048 blocks/phase, full occupancy)
        scan_phase1<<<(int)(SUMSZ4 / 256), 256, 0, stream>>>(bufXM, bufDelta, bufXDBL, Alog, bufAP, bufSE);
        scan_phase2<<<(cB * cDI * cDS) / 256, 256, 0, stream>>>(bufAP, bufSE, bufSI);
        scan_phase3<<<(int)(SUMSZ4 / 256), 256, 0, stream>>>(bufXM, bufDelta, bufXDBL, Alog, Dv, bufXR, bufSI, bufY);
        bgemm_plain(0, 64, 64, bufY, out_w, nullptr, bufH, bufH, bufHb,
                    Mrows, cDM, cDI, cDI, cDI, cDM, cDM, cDM, stream);

        // ---- cross attention ----
        bgemm_plain(0, 64, 64, bufHb, ain_w, ain_b, nullptr, nullptr, bufQ,
                    Mrows, cDM, cDM, cDM, cDM, 0, cDM, 0, stream);
        bgemm_plain(0, 64, 128, encb, ain_w + (long)cDM * cDM, ain_b + cDM, nullptr, nullptr, bufKV,
                    Mrows, 2 * cDM, cDM, cDM, cDM, 0, 2 * cDM, 0, stream);
        {
            dim3 g(cLE / 32, cDM / 32, cB);
            transpose_bf16_kernel<<<g, 256, 0, stream>>>(bufKV, bufVT, 2 * cDM, cDM);
        }
        {
            dim3 g(cL / 32, cB * cH);
            flash_attn_kernel<<<g, 128, 0, stream>>>(bufQ, bufKV, bufVT, bufO,
                                                     0.08838834764831845f);
        }
        // pre = o @ aout_w.T + aout_b + h ; h = LN(pre)
        bgemm_plain(0, 64, 64, bufO, aout_w, aout_b, bufH, bufPre, nullptr,
                    Mrows, cDM, cDM, cDM, cDM, cDM, 0, cDM, stream);
        layernorm_kernel<<<Mrows, 256, 0, stream>>>(bufPre, ln_w, ln_b, bufH, bufHb, cDM);
    }

    // final: out = rmsnorm(h) @ W_out.T   (MFMA, 64^2 tile, N=80 edge-clamped)
    rmsnorm_kernel<<<Mrows, 256, 0, stream>>>(bufH, normf_w, nullptr, bufU, cDM);
    bgemm_plain(0, 64, 64, bufU, w_outf_b, nullptr, nullptr, out, nullptr,
                Mrows, cNM, cDM, cDM, cDM, cNM, 0, 0, stream);
}

// Round 10
// 797.421 us; speedup vs baseline: 8.8722x; 1.0768x over previous
//
#include <hip/hip_runtime.h>
#include <hip/hip_bf16.h>
#include <math.h>

typedef __hip_bfloat16 bf16;
typedef __attribute__((ext_vector_type(8))) short short8x;
typedef __attribute__((ext_vector_type(4))) float f32x4;

// ---- problem constants ----
static constexpr int cB   = 2;
static constexpr int cL   = 1024;
static constexpr int cLE  = 1024;
static constexpr int cNM  = 80;
static constexpr int cDM  = 512;
static constexpr int cLAYERS = 4;
static constexpr int cDS  = 16;
static constexpr int cKC  = 4;     // conv taps
static constexpr int cH   = 4;     // heads
static constexpr int cDI  = 1024;  // EXP*DM
static constexpr int cDTR = 32;
static constexpr int cHD  = 128;   // head dim

static constexpr int cNCH = 64;    // scan chunks (bit extraction below assumes 64)
static constexpr int cCHL = cL / cNCH;  // 16 steps per chunk

#define GLL16(g, l) __builtin_amdgcn_global_load_lds( \
    (const __attribute__((address_space(1))) void*)(g), \
    (__attribute__((address_space(3))) void*)(l), 16, 0, 0)

// =====================================================================
// bf16 MFMA GEMM, BMxBN tile, 4 waves (2x2), K-step 32.
//   C = act( A @ W^T + bias ) + addv ; A: M x K bf16 (lda), W: N x K bf16 (ldw)
//   Writes f32 C (if Cf) and/or bf16 C (if Cb). Batched over blockIdx.z;
//   bias gets per-i1 stride sBias (for per-layer bias batching).
// =====================================================================
template<int ACT, int BM, int BN>
__global__ __launch_bounds__(256)
void bgemm_kernel(const bf16* __restrict__ A, const bf16* __restrict__ W,
                  const float* __restrict__ bias, const float* __restrict__ addv,
                  float* __restrict__ Cf, bf16* __restrict__ Cb,
                  int M, int N, int Kd, int lda, int ldw, int ldcf, int ldcb, int ldadd,
                  int bdiv, long sA1, long sA2, long sW1, long sW2,
                  long sCf1, long sCf2, long sCb1, long sCb2, long sBias)
{
    constexpr int RM = BM / 32;            // per-wave 16-row frag repeats
    constexpr int RN = BN / 32;
    const int z = blockIdx.z;
    const int i1 = z / bdiv, i2 = z % bdiv;
    A += i1 * sA1 + i2 * sA2;
    W += i1 * sW1 + i2 * sW2;
    if (bias) bias += i1 * sBias;

    const int bm = blockIdx.y * BM;
    const int bn = blockIdx.x * BN;
    const int tid = threadIdx.x;
    const int lane = tid & 63;
    const int wid = tid >> 6;              // 0..3
    const int wr = wid >> 1, wc = wid & 1; // 2x2 wave grid

    __shared__ bf16 As[BM * 32];
    __shared__ bf16 Bs[BN * 32];

    f32x4 acc[RM][RN] = {};

    const int r_in = lane >> 2;            // 0..15
    const int kb   = (lane & 3) * 8;       // k offset for staging
    const int hi   = lane >> 4;            // 0..3
    const int rc   = lane & 15;

    for (int k0 = 0; k0 < Kd; k0 += 32) {
#pragma unroll
        for (int iss = 0; iss < BM / 64; iss++) {
            const int row = wid * (BM / 4) + iss * 16 + r_in;
            int gm = bm + row; if (gm >= M) gm = M - 1;
            const bf16* ga = A + (long)gm * lda + k0 + kb;
            GLL16(ga, As + (wid * (BM / 4) + iss * 16) * 32);
        }
#pragma unroll
        for (int iss = 0; iss < BN / 64; iss++) {
            const int row = wid * (BN / 4) + iss * 16 + r_in;
            int gn = bn + row; if (gn >= N) gn = N - 1;
            const bf16* gb = W + (long)gn * ldw + k0 + kb;
            GLL16(gb, Bs + (wid * (BN / 4) + iss * 16) * 32);
        }
        asm volatile("s_waitcnt vmcnt(0)" ::: "memory");
        __syncthreads();

        short8x af[RM], bfv[RN];
#pragma unroll
        for (int i = 0; i < RM; i++)
            af[i] = *(const short8x*)(As + (wr * (BM / 2) + i * 16 + rc) * 32 + hi * 8);
#pragma unroll
        for (int j = 0; j < RN; j++)
            bfv[j] = *(const short8x*)(Bs + (wc * (BN / 2) + j * 16 + rc) * 32 + hi * 8);
#pragma unroll
        for (int i = 0; i < RM; i++)
#pragma unroll
            for (int j = 0; j < RN; j++)
                acc[i][j] = __builtin_amdgcn_mfma_f32_16x16x32_bf16(af[i], bfv[j], acc[i][j], 0, 0, 0);
        __syncthreads();
    }

    // epilogue: C/D frag mapping col=lane&15, row=(lane>>4)*4+r  [m89-verified]
    const long cfo = i1 * sCf1 + i2 * sCf2;
    const long cbo = i1 * sCb1 + i2 * sCb2;
#pragma unroll
    for (int i = 0; i < RM; i++) {
#pragma unroll
        for (int r = 0; r < 4; r++) {
            const int gm = bm + wr * (BM / 2) + i * 16 + hi * 4 + r;
            if (gm >= M) continue;
#pragma unroll
            for (int j = 0; j < RN; j++) {
                const int gn = bn + wc * (BN / 2) + j * 16 + rc;
                if (gn >= N) continue;
                float v = acc[i][j][r];
                if (bias) v += bias[gn];
                if (ACT == 1) v = (v > 20.f) ? v : log1pf(__expf(v));
                if (addv) v += addv[cfo + (long)gm * ldadd + gn];
                if (Cf) Cf[cfo + (long)gm * ldcf + gn] = v;
                if (Cb) Cb[cbo + (long)gm * ldcb + gn] = __float2bfloat16(v);
            }
        }
    }
}

static inline void bgemm(int ACT, int BM, int BN, const bf16* A, const bf16* W, const float* bias,
                         const float* addv, float* Cf, bf16* Cb,
                         int M, int N, int Kd, int lda, int ldw, int ldcf, int ldcb, int ldadd,
                         int nz, int bdiv, long sA1, long sA2, long sW1, long sW2,
                         long sCf1, long sCf2, long sCb1, long sCb2, long sBias, hipStream_t s)
{
    dim3 g((N + BN - 1) / BN, (M + BM - 1) / BM, nz), b(256);
#define BG_ARGS A, W, bias, addv, Cf, Cb, M, N, Kd, lda, ldw, ldcf, ldcb, ldadd, \
                bdiv, sA1, sA2, sW1, sW2, sCf1, sCf2, sCb1, sCb2, sBias
    if (BM == 128) {
        if (ACT == 1) bgemm_kernel<1, 128, 128><<<g, b, 0, s>>>(BG_ARGS);
        else          bgemm_kernel<0, 128, 128><<<g, b, 0, s>>>(BG_ARGS);
    } else if (BN == 128) {
        if (ACT == 1) bgemm_kernel<1, 64, 128><<<g, b, 0, s>>>(BG_ARGS);
        else          bgemm_kernel<0, 64, 128><<<g, b, 0, s>>>(BG_ARGS);
    } else {
        bgemm_kernel<0, 64, 64><<<g, b, 0, s>>>(BG_ARGS);
    }
#undef BG_ARGS
}

static inline void bgemm_plain(int ACT, int BM, int BN, const bf16* A, const bf16* W,
                               const float* bias, const float* addv, float* Cf, bf16* Cb,
                               int M, int N, int Kd, int lda, int ldw, int ldcf, int ldcb,
                               int ldadd, hipStream_t s)
{
    bgemm(ACT, BM, BN, A, W, bias, addv, Cf, Cb, M, N, Kd, lda, ldw, ldcf, ldcb, ldadd,
          1, 1, 0, 0, 0, 0, 0, 0, 0, 0, 0, s);
}

// =====================================================================
// Fused flash cross-attention (verified round 8).
// =====================================================================
__global__ __launch_bounds__(128)
void flash_attn_kernel(const bf16* __restrict__ Qp, const bf16* __restrict__ Kp,
                       const bf16* __restrict__ VTp, bf16* __restrict__ Op, float scale)
{
    const int qt = blockIdx.x;            // 0..31
    const int bh = blockIdx.y;            // b*H + h
    const int b = bh >> 2, h = bh & 3;
    const int tid = threadIdx.x;
    const int w = tid >> 6;               // 0..1
    const int lane = tid & 63;
    const int rc = lane & 15, hi = lane >> 4;
    const int rlo = rc & 7;

    __shared__ bf16 Qs[32 * 128];
    __shared__ bf16 Ks[64 * 128];
    __shared__ bf16 Vs[128 * 64];
    __shared__ bf16 Ps[32 * 64];

    {
        const bf16* qb = Qp + ((long)(b * cL + qt * 32)) * cDM + h * cHD;
#pragma unroll
        for (int c = 0; c < 4; c++) {
            const int row = w * 16 + c * 4 + (lane >> 4);
            const int gc = (lane & 15) ^ (row & 7);
            GLL16(qb + (long)row * cDM + gc * 8, Qs + (w * 16 + c * 4) * 128);
        }
    }
    asm volatile("s_waitcnt vmcnt(0)" ::: "memory");
    __syncthreads();

    short8x aq[4];
#pragma unroll
    for (int kk = 0; kk < 4; kk++) {
        const int sc = (kk * 4 + hi) ^ rlo;
        aq[kk] = *(const short8x*)(Qs + (w * 16 + rc) * 128 + sc * 8);
    }

    float m_r[4], l_r[4];
#pragma unroll
    for (int r = 0; r < 4; r++) { m_r[r] = -1e30f; l_r[r] = 0.f; }
    f32x4 oacc[8] = {};

    const bf16* kb0 = Kp + ((long)(b * cLE)) * (2 * cDM) + h * cHD;
    const bf16* vb0 = VTp + ((long)(b * cDM + h * cHD)) * cLE;

    for (int kt = 0; kt < 16; kt++) {
        __syncthreads();
#pragma unroll
        for (int c = 0; c < 8; c++) {
            const int row = w * 32 + c * 4 + (lane >> 4);
            const int gc = (lane & 15) ^ (row & 7);
            GLL16(kb0 + ((long)(kt * 64 + row)) * (2 * cDM) + gc * 8,
                  Ks + (w * 32 + c * 4) * 128);
        }
#pragma unroll
        for (int c = 0; c < 8; c++) {
            const int row = w * 64 + c * 8 + (lane >> 3);
            const int gc = (lane & 7) ^ (row & 7);
            GLL16(vb0 + (long)row * cLE + kt * 64 + gc * 8,
                  Vs + (w * 64 + c * 8) * 64);
        }
        asm volatile("s_waitcnt vmcnt(0)" ::: "memory");
        __syncthreads();

        f32x4 s[4] = {};
#pragma unroll
        for (int kk = 0; kk < 4; kk++) {
            const int sc = (kk * 4 + hi) ^ rlo;
#pragma unroll
            for (int j = 0; j < 4; j++) {
                short8x bk = *(const short8x*)(Ks + (j * 16 + rc) * 128 + sc * 8);
                s[j] = __builtin_amdgcn_mfma_f32_16x16x32_bf16(aq[kk], bk, s[j], 0, 0, 0);
            }
        }

        float p[4][4];
        float esc[4];
#pragma unroll
        for (int r = 0; r < 4; r++) {
            const float v0 = s[0][r] * scale, v1 = s[1][r] * scale;
            const float v2 = s[2][r] * scale, v3 = s[3][r] * scale;
            float mx = fmaxf(fmaxf(v0, v1), fmaxf(v2, v3));
            mx = fmaxf(mx, __shfl_xor(mx, 1));
            mx = fmaxf(mx, __shfl_xor(mx, 2));
            mx = fmaxf(mx, __shfl_xor(mx, 4));
            mx = fmaxf(mx, __shfl_xor(mx, 8));
            const float mn = fmaxf(m_r[r], mx);
            p[0][r] = __expf(v0 - mn);
            p[1][r] = __expf(v1 - mn);
            p[2][r] = __expf(v2 - mn);
            p[3][r] = __expf(v3 - mn);
            float rs = (p[0][r] + p[1][r]) + (p[2][r] + p[3][r]);
            rs += __shfl_xor(rs, 1);
            rs += __shfl_xor(rs, 2);
            rs += __shfl_xor(rs, 4);
            rs += __shfl_xor(rs, 8);
            esc[r] = __expf(m_r[r] - mn);
            l_r[r] = l_r[r] * esc[r] + rs;
            m_r[r] = mn;
        }
#pragma unroll
        for (int j2 = 0; j2 < 8; j2++)
#pragma unroll
            for (int r = 0; r < 4; r++)
                oacc[j2][r] *= esc[r];
#pragma unroll
        for (int j = 0; j < 4; j++)
#pragma unroll
            for (int r = 0; r < 4; r++) {
                const int q = w * 16 + hi * 4 + r;
                const int cp = (j * 2 + (rc >> 3)) ^ (q & 7);
                Ps[q * 64 + cp * 8 + (rc & 7)] = __float2bfloat16(p[j][r]);
            }
        __syncthreads();
#pragma unroll
        for (int ks = 0; ks < 2; ks++) {
            const int sc = (ks * 4 + hi) ^ rlo;
            short8x ap = *(const short8x*)(Ps + (w * 16 + rc) * 64 + sc * 8);
#pragma unroll
            for (int j2 = 0; j2 < 8; j2++) {
                short8x bv = *(const short8x*)(Vs + (j2 * 16 + rc) * 64 + sc * 8);
                oacc[j2] = __builtin_amdgcn_mfma_f32_16x16x32_bf16(ap, bv, oacc[j2], 0, 0, 0);
            }
        }
    }

    float inv[4];
#pragma unroll
    for (int r = 0; r < 4; r++) inv[r] = 1.f / l_r[r];
    bf16* ob = Op + ((long)(b * cL + qt * 32)) * cDM + h * cHD;
#pragma unroll
    for (int j2 = 0; j2 < 8; j2++)
#pragma unroll
        for (int r = 0; r < 4; r++)
            ob[(long)(w * 16 + hi * 4 + r) * cDM + j2 * 16 + rc] =
                __float2bfloat16(oacc[j2][r] * inv[r]);
}

// =====================================================================
// split-K partial reduce:  out = sum_s parts[s]  (f32 + bf16 outputs)
// =====================================================================
__global__ void splitk_reduce_kernel(const float* __restrict__ parts, float* __restrict__ outf,
                                     bf16* __restrict__ outb, int n4, int sliceN4, int S)
{
    const int i = blockIdx.x * 256 + threadIdx.x;
    if (i >= n4) return;
    float4 a = ((const float4*)parts)[i];
    for (int s2 = 1; s2 < S; s2++) {
        float4 b2 = ((const float4*)parts)[i + (long)s2 * sliceN4];
        a.x += b2.x; a.y += b2.y; a.z += b2.z; a.w += b2.w;
    }
    ((float4*)outf)[i] = a;
    bf16 b0 = __float2bfloat16(a.x), b1 = __float2bfloat16(a.y);
    bf16 b2 = __float2bfloat16(a.z), b3 = __float2bfloat16(a.w);
    short4 pk = { *(short*)&b0, *(short*)&b1, *(short*)&b2, *(short*)&b3 };
    ((short4*)outb)[i] = pk;
}

// =====================================================================
// One-shot fused f32->bf16 conversion of all weight tensors + enc.
// Ranges are compile-time constants (elements, all %4==0).
// =====================================================================
__global__ void cvt_all_kernel(
    const float* __restrict__ s0, bf16* __restrict__ d0,   // enc
    const float* __restrict__ s1, bf16* __restrict__ d1,   // m_in_w
    const float* __restrict__ s2, bf16* __restrict__ d2,   // m_xproj
    const float* __restrict__ s3, bf16* __restrict__ d3,   // m_dt_w
    const float* __restrict__ s4, bf16* __restrict__ d4,   // m_out_w
    const float* __restrict__ s5, bf16* __restrict__ d5,   // a_in_w
    const float* __restrict__ s6, bf16* __restrict__ d6,   // a_out_w
    const float* __restrict__ s7, bf16* __restrict__ d7)   // W_out
{
    constexpr long E0 = 1048576, E1 = 4194304, E2 = 262144, E3 = 131072;
    constexpr long E4 = 2097152, E5 = 3145728, E6 = 1048576, E7 = 40960;
    constexpr long C0 = E0, C1 = C0 + E1, C2 = C1 + E2, C3 = C2 + E3;
    constexpr long C4 = C3 + E4, C5 = C4 + E5, C6 = C5 + E6, C7 = C6 + E7;
    long i = ((long)blockIdx.x * 256 + threadIdx.x) * 4;
    if (i >= C7) return;
    const float* s; bf16* d;
    if      (i < C0) { s = s0; d = d0; }
    else if (i < C1) { s = s1; d = d1; i -= C0; }
    else if (i < C2) { s = s2; d = d2; i -= C1; }
    else if (i < C3) { s = s3; d = d3; i -= C2; }
    else if (i < C4) { s = s4; d = d4; i -= C3; }
    else if (i < C5) { s = s5; d = d5; i -= C4; }
    else if (i < C6) { s = s6; d = d6; i -= C5; }
    else             { s = s7; d = d7; i -= C6; }
    float4 v = *(const float4*)(s + i);
    d[i]     = __float2bfloat16(v.x);
    d[i + 1] = __float2bfloat16(v.y);
    d[i + 2] = __float2bfloat16(v.z);
    d[i + 3] = __float2bfloat16(v.w);
}

// f32 (rows x kin) -> bf16 (rows x kout), zero-padded beyond kin
__global__ void cvt_pad_kernel(const float* __restrict__ in, bf16* __restrict__ out,
                               int rows, int kin, int kout)
{
    const int idx = blockIdx.x * 256 + threadIdx.x;
    if (idx >= rows * kout) return;
    const int r = idx / kout, k = idx - r * kout;
    out[idx] = __float2bfloat16(k < kin ? in[(long)r * kin + k] : 0.f);
}

// =====================================================================
// bf16 transpose, batched over (layer, batch):  z = lay*cB + b.
//   in rows (b*LE+le) x ldin (+ lay*inLS), cols [col0, col0+DM) -> out b: DM x LE (+ lay*outLS)
// =====================================================================
__global__ void transpose_bf16_kernel(const bf16* __restrict__ in, bf16* __restrict__ out,
                                      int ldin, int col0, long inLS, long outLS)
{
    __shared__ bf16 t[32][33];
    const int z = blockIdx.z;
    const int lay = z >> 1, b = z & 1;
    in  += (long)lay * inLS;
    out += (long)lay * outLS;
    const int le0 = blockIdx.x * 32, d0 = blockIdx.y * 32;
    const int tid = threadIdx.x;
    const int c = tid & 31, r = tid >> 5;
    for (int i = r; i < 32; i += 8)
        t[i][c] = in[((long)b * cLE + le0 + i) * ldin + col0 + d0 + c];
    __syncthreads();
    for (int i = r; i < 32; i += 8)
        out[((long)b * cDM + d0 + i) * cLE + le0 + c] = t[c][i];
}

// =====================================================================
// RMSNorm per row (optional f32 and bf16 outputs)
// =====================================================================
__global__ void rmsnorm_kernel(const float* __restrict__ x, const float* __restrict__ w,
                               float* __restrict__ outf, bf16* __restrict__ outb, int Dm)
{
    const int row = blockIdx.x;
    const float* xr = x + (long)row * Dm;
    float s = 0.f;
    for (int i = threadIdx.x; i < Dm; i += 256) { float v = xr[i]; s += v * v; }
    __shared__ float red[5];
    const int lane = threadIdx.x & 63, wv = threadIdx.x >> 6;
#pragma unroll
    for (int off = 1; off < 64; off <<= 1) s += __shfl_xor(s, off);
    if (lane == 0) red[wv] = s;
    __syncthreads();
    if (threadIdx.x == 0) {
        float t = red[0] + red[1] + red[2] + red[3];
        red[4] = rsqrtf(t / Dm + 1e-5f);
    }
    __syncthreads();
    const float scale = red[4];
    for (int i = threadIdx.x; i < Dm; i += 256) {
        float v = xr[i] * scale * w[i];
        if (outf) outf[(long)row * Dm + i] = v;
        if (outb) outb[(long)row * Dm + i] = __float2bfloat16(v);
    }
}

// =====================================================================
// LayerNorm per row -> f32 + bf16 outputs
// =====================================================================
__global__ void layernorm_kernel(const float* __restrict__ x, const float* __restrict__ w,
                                 const float* __restrict__ b, float* __restrict__ outf,
                                 bf16* __restrict__ outb, int Dm)
{
    const int row = blockIdx.x;
    const float* xr = x + (long)row * Dm;
    float s = 0.f, sq = 0.f;
    for (int i = threadIdx.x; i < Dm; i += 256) { float v = xr[i]; s += v; sq += v * v; }
    __shared__ float red[8];
    __shared__ float mv[2];
    const int lane = threadIdx.x & 63, wv = threadIdx.x >> 6;
#pragma unroll
    for (int off = 1; off < 64; off <<= 1) { s += __shfl_xor(s, off); sq += __shfl_xor(sq, off); }
    if (lane == 0) { red[wv] = s; red[4 + wv] = sq; }
    __syncthreads();
    if (threadIdx.x == 0) {
        float ts = red[0] + red[1] + red[2] + red[3];
        float tq = red[4] + red[5] + red[6] + red[7];
        float m = ts / Dm;
        float var = tq / Dm - m * m;
        mv[0] = m;
        mv[1] = rsqrtf(var + 1e-5f);
    }
    __syncthreads();
    const float m = mv[0], rs = mv[1];
    for (int i = threadIdx.x; i < Dm; i += 256) {
        float v = (xr[i] - m) * rs * w[i] + b[i];
        outf[(long)row * Dm + i] = v;
        outb[(long)row * Dm + i] = __float2bfloat16(v);
    }
}

// =====================================================================
// Causal depthwise conv (K=4) + bias + SiLU -> xm f32 + bf16
// =====================================================================
__global__ void conv_silu_kernel(const float* __restrict__ xr, const float* __restrict__ w,
                                 const float* __restrict__ bias, float* __restrict__ xm,
                                 bf16* __restrict__ xmb)
{
    const int idx = blockIdx.x * 256 + threadIdx.x;
    if (idx >= cB * cL * cDI) return;
    const int d = idx & (cDI - 1);
    const int l = (idx >> 10) & (cL - 1);
    const int b = idx >> 20;
    float s = bias[d];
#pragma unroll
    for (int j = 0; j < cKC; j++) {
        const int ls = l + j - (cKC - 1);
        if (ls >= 0) s += w[d * cKC + j] * xr[((long)(b * cL + ls)) * (2 * cDI) + d];
    }
    s = s / (1.f + __expf(-s));
    xm[(long)idx] = s;
    xmb[(long)idx] = __float2bfloat16(s);
}

// =====================================================================
// Chunk-parallel selective scan, 4 states (n) per thread, NCH=64 chunks.
// Summary layout: idx = ((b*NCH+ch)*DI+d)*DS+n
// Thread mapping idx4 bits: ng[1:0], d[11:2], ch[17:12], b[18]
// =====================================================================
__global__ void scan_phase1(const float* __restrict__ xm, const float* __restrict__ delta,
                            const float* __restrict__ xdbl, const float* __restrict__ Alog,
                            float* __restrict__ aprod_out, float* __restrict__ send_out)
{
    const int idx4 = blockIdx.x * 256 + threadIdx.x;   // cB*cNCH*cDI*4
    const int ng = idx4 & 3;
    const int d  = (idx4 >> 2) & (cDI - 1);
    const int ch = (idx4 >> 12) & (cNCH - 1);
    const int b  = idx4 >> 18;
    const float4 Al = *(const float4*)(Alog + d * cDS + 4 * ng);
    const float A0 = -__expf(Al.x), A1 = -__expf(Al.y), A2 = -__expf(Al.z), A3 = -__expf(Al.w);
    float s0 = 0.f, s1 = 0.f, s2 = 0.f, s3 = 0.f;
    float p0 = 1.f, p1 = 1.f, p2 = 1.f, p3 = 1.f;
    const int l0 = ch * cCHL;
    const float* dp = delta + (long)(b * cL + l0) * cDI + d;
    const float* up = xm    + (long)(b * cL + l0) * cDI + d;
    const float* xb = xdbl  + (long)(b * cL + l0) * 64 + cDTR + 4 * ng;
#pragma unroll
    for (int t = 0; t < cCHL; t++) {
        const float dl = dp[(long)t * cDI];
        const float du = dl * up[(long)t * cDI];
        const float4 Bv = *(const float4*)(xb + (long)t * 64);
        const float a0 = __expf(dl * A0), a1 = __expf(dl * A1);
        const float a2 = __expf(dl * A2), a3 = __expf(dl * A3);
        s0 = a0 * s0 + du * Bv.x; p0 *= a0;
        s1 = a1 * s1 + du * Bv.y; p1 *= a1;
        s2 = a2 * s2 + du * Bv.z; p2 *= a2;
        s3 = a3 * s3 + du * Bv.w; p3 *= a3;
    }
    const long base4 = (((long)(b * cNCH + ch) * cDI + d) * cDS) + 4 * ng;
    float4 pv = { p0, p1, p2, p3 };
    float4 sv = { s0, s1, s2, s3 };
    *(float4*)(aprod_out + base4) = pv;
    *(float4*)(send_out + base4)  = sv;
}

__global__ void scan_phase2(const float* __restrict__ aprod, const float* __restrict__ send,
                            float* __restrict__ sinit)
{
    const int j = blockIdx.x * 256 + threadIdx.x;   // cB*cDI*cDS
    const int n = j & (cDS - 1);
    const int d = (j >> 4) & (cDI - 1);
    const int b = j >> 14;
    float s = 0.f;
#pragma unroll
    for (int c = 0; c < cNCH; c++) {
        const long off = (((long)(b * cNCH + c) * cDI + d) * cDS) + n;
        sinit[off] = s;
        s = aprod[off] * s + send[off];
    }
}

__global__ void scan_phase3(const float* __restrict__ xm, const float* __restrict__ delta,
                            const float* __restrict__ xdbl, const float* __restrict__ Alog,
                            const float* __restrict__ Dv, const float* __restrict__ xr,
                            const float* __restrict__ sinit, bf16* __restrict__ y)
{
    const int idx4 = blockIdx.x * 256 + threadIdx.x;   // cB*cNCH*cDI*4
    const int ng = idx4 & 3;
    const int d  = (idx4 >> 2) & (cDI - 1);
    const int ch = (idx4 >> 12) & (cNCH - 1);
    const int b  = idx4 >> 18;
    const float4 Al = *(const float4*)(Alog + d * cDS + 4 * ng);
    const float A0 = -__expf(Al.x), A1 = -__expf(Al.y), A2 = -__expf(Al.z), A3 = -__expf(Al.w);
    const float Dval = Dv[d];
    const long base4 = (((long)(b * cNCH + ch) * cDI + d) * cDS) + 4 * ng;
    float4 st = *(const float4*)(sinit + base4);
    float s0 = st.x, s1 = st.y, s2 = st.z, s3 = st.w;
    const int l0 = ch * cCHL;
    const float* dp = delta + (long)(b * cL + l0) * cDI + d;
    const float* up = xm    + (long)(b * cL + l0) * cDI + d;
    const float* xb = xdbl  + (long)(b * cL + l0) * 64 + cDTR + 4 * ng;
    const float* xc = xb + cDS;
    const float* rp = xr + (long)(b * cL + l0) * (2 * cDI) + cDI + d;
    bf16* yp = y + (long)(b * cL + l0) * cDI + d;
#pragma unroll
    for (int t = 0; t < cCHL; t++) {
        const float dl = dp[(long)t * cDI];
        const float u  = up[(long)t * cDI];
        const float du = dl * u;
        const float4 Bv = *(const float4*)(xb + (long)t * 64);
        const float4 Cv = *(const float4*)(xc + (long)t * 64);
        const float a0 = __expf(dl * A0), a1 = __expf(dl * A1);
        const float a2 = __expf(dl * A2), a3 = __expf(dl * A3);
        s0 = a0 * s0 + du * Bv.x;
        s1 = a1 * s1 + du * Bv.y;
        s2 = a2 * s2 + du * Bv.z;
        s3 = a3 * s3 + du * Bv.w;
        float c = s0 * Cv.x;
        c = fmaf(s1, Cv.y, c);
        c = fmaf(s2, Cv.z, c);
        c = fmaf(s3, Cv.w, c);
        c += __shfl_xor(c, 1);
        c += __shfl_xor(c, 2);
        if (ng == 0) {
            const float res = rp[(long)t * 2 * cDI];
            const float sig = 1.f / (1.f + __expf(-res));
            yp[(long)t * cDI] = __float2bfloat16((c + u * Dval) * (res * sig));
        }
    }
}

// =====================================================================
extern "C" void kernel_launch(void* const* d_in, const int* in_sizes, int n_in,
                              void* d_out, int out_size, void* d_ws, size_t ws_size,
                              hipStream_t stream)
{
    const float* x       = (const float*)d_in[0];
    const float* enc     = (const float*)d_in[1];
    const float* W_in    = (const float*)d_in[2];
    const float* b_in    = (const float*)d_in[3];
    const float* m_norm_w= (const float*)d_in[4];
    const float* m_in_w  = (const float*)d_in[5];
    const float* m_conv_w= (const float*)d_in[6];
    const float* m_conv_b= (const float*)d_in[7];
    const float* m_xproj = (const float*)d_in[8];
    const float* m_dt_w  = (const float*)d_in[9];
    const float* m_dt_b  = (const float*)d_in[10];
    const float* m_Alog  = (const float*)d_in[11];
    const float* m_D     = (const float*)d_in[12];
    const float* m_out_w = (const float*)d_in[13];
    const float* a_in_w  = (const float*)d_in[14];
    const float* a_in_b  = (const float*)d_in[15];
    const float* a_out_w = (const float*)d_in[16];
    const float* a_out_b = (const float*)d_in[17];
    const float* a_ln_w  = (const float*)d_in[18];
    const float* a_ln_b  = (const float*)d_in[19];
    const float* normf_w = (const float*)d_in[20];
    const float* W_out   = (const float*)d_in[21];
    float* out = (float*)d_out;

    float* ws = (float*)d_ws;
    long off = 0;
    auto allocf = [&](long n) { float* p = ws + off; off += n; return p; };

    const long M1 = 1 << 20;
    float* bufH    = allocf(M1);
    float* bufPre  = allocf(M1);         // also xproj split-K partials
    float* bufXR   = allocf(4 * M1);
    float* bufXM   = allocf(2 * M1);
    float* bufDelta= allocf(2 * M1);
    float* bufXDBL = allocf(M1 / 8);
    bf16* bufU    = (bf16*)allocf(M1 / 2);      // 2048x512 bf16
    bf16* bufHb   = (bf16*)allocf(M1 / 2);
    bf16* bufXMb  = (bf16*)allocf(M1);          // 2048x1024 bf16
    bf16* bufXDBLb= (bf16*)allocf(M1 / 16);
    bf16* bufY    = (bf16*)allocf(M1);          // 2048x1024 bf16
    bf16* bufQ    = (bf16*)allocf(M1 / 2);
    bf16* bufO    = (bf16*)allocf(M1 / 2);
    bf16* encb    = (bf16*)allocf(M1 / 2);
    bf16* w_in_b  = (bf16*)allocf(2 * M1);      // mamba in_w (4 layers)
    bf16* w_xp_b  = (bf16*)allocf(M1 / 8);
    bf16* w_dt_b  = (bf16*)allocf(M1 / 16);
    bf16* w_out_b = (bf16*)allocf(M1);
    bf16* w_ain_b = (bf16*)allocf(3 * M1 / 2);
    bf16* w_aout_b= (bf16*)allocf(M1 / 2);
    bf16* x_pad   = (bf16*)allocf(2048L * 96 / 2);   // x zero-padded K=96
    bf16* w_inp_b = (bf16*)allocf(512L * 96 / 2);    // W_in zero-padded K=96
    bf16* w_outf_b= (bf16*)allocf(80L * 512 / 2);    // W_out bf16
    // dedicated scan summaries at NCH=64: B*NCH*DI*DS = 2M floats each
    float* bufAP  = allocf(2 * M1);
    float* bufSE  = allocf(2 * M1);
    float* bufSI  = allocf(2 * M1);
    // all-layer K|V (2048x1024 bf16 per layer) and V^T (2x512x1024 bf16 per layer)
    bf16* bufKV4  = (bf16*)allocf(4 * M1);      // 4 layers x 2M bf16
    bf16* bufVT4  = (bf16*)allocf(2 * M1);      // 4 layers x 1M bf16

    const int Mrows = cB * cL;   // 2048
    const long SUMSZ4 = (long)cB * cNCH * cDI * 4;   // scan threads (4 n each) = 524288
    const long kvLS = (long)Mrows * 2 * cDM;         // per-layer KV stride (bf16 elems)
    const long vtLS = (long)cB * cDM * cLE;          // per-layer VT stride

    // ---- one-time conversions (single fused kernel + 2 pads) ----
    cvt_all_kernel<<<11688, 256, 0, stream>>>(
        enc, encb, m_in_w, w_in_b, m_xproj, w_xp_b, m_dt_w, w_dt_b,
        m_out_w, w_out_b, a_in_w, w_ain_b, a_out_w, w_aout_b, W_out, w_outf_b);
    cvt_pad_kernel<<<(Mrows * 96 + 255) / 256, 256, 0, stream>>>(x, x_pad, Mrows, cNM, 96);
    cvt_pad_kernel<<<(cDM * 96 + 255) / 256, 256, 0, stream>>>(W_in, w_inp_b, cDM, cNM, 96);

    // ---- all-layer K|V projection from enc (z-batched over layers) ----
    bgemm(0, 64, 128, encb, w_ain_b + (long)cDM * cDM, a_in_b + cDM, nullptr, nullptr, bufKV4,
          Mrows, 2 * cDM, cDM, cDM, cDM, 0, 2 * cDM, 0,
          cLAYERS, 1,
          0, 0,                                  // A shared
          (long)3 * cDM * cDM, 0,                // W per layer
          0, 0, kvLS, 0,                         // Cb per layer
          (long)3 * cDM,                         // bias per layer
          stream);
    // ---- all-layer V^T (z = layer*cB + b) ----
    {
        dim3 g(cLE / 32, cDM / 32, cLAYERS * cB);
        transpose_bf16_kernel<<<g, 256, 0, stream>>>(bufKV4, bufVT4, 2 * cDM, cDM, kvLS, vtLS);
    }

    // h = x @ W_in.T + b_in   (K padded 80->96, MFMA 64^2)
    bgemm_plain(0, 64, 64, x_pad, w_inp_b, b_in, nullptr, bufH, nullptr,
                Mrows, cDM, 96, 96, 96, cDM, 0, 0, stream);

    for (int i = 0; i < cLAYERS; i++) {
        const float* norm_w = m_norm_w + (long)i * cDM;
        const bf16*  in_w   = w_in_b   + (long)i * 2 * cDI * cDM;
        const float* conv_w = m_conv_w + (long)i * cDI * cKC;
        const float* conv_b = m_conv_b + (long)i * cDI;
        const bf16*  xproj  = w_xp_b   + (long)i * 64 * cDI;
        const bf16*  dt_w   = w_dt_b   + (long)i * cDI * cDTR;
        const float* dt_b   = m_dt_b   + (long)i * cDI;
        const float* Alog   = m_Alog   + (long)i * cDI * cDS;
        const float* Dv     = m_D      + (long)i * cDI;
        const bf16*  out_w  = w_out_b  + (long)i * cDM * cDI;
        const bf16*  ain_w  = w_ain_b  + (long)i * 3 * cDM * cDM;
        const float* ain_b  = a_in_b   + (long)i * 3 * cDM;
        const bf16*  aout_w = w_aout_b + (long)i * cDM * cDM;
        const float* aout_b = a_out_b  + (long)i * cDM;
        const float* ln_w   = a_ln_w   + (long)i * cDM;
        const float* ln_b   = a_ln_b   + (long)i * cDM;
        const bf16*  kv_l   = bufKV4 + (long)i * kvLS;
        const bf16*  vt_l   = bufVT4 + (long)i * vtLS;

        // ---- mamba ----
        rmsnorm_kernel<<<Mrows, 256, 0, stream>>>(bufH, norm_w, nullptr, bufU, cDM);
        bgemm_plain(0, 64, 128, bufU, in_w, nullptr, nullptr, bufXR, nullptr,
                    Mrows, 2 * cDI, cDM, cDM, cDM, 2 * cDI, 0, 0, stream);
        conv_silu_kernel<<<(cB * cL * cDI) / 256, 256, 0, stream>>>(bufXR, conv_w, conv_b, bufXM, bufXMb);
        // x_dbl = xm @ xproj.T : split-K x8
        bgemm(0, 64, 64, bufXMb, xproj, nullptr, nullptr, bufPre, nullptr,
              Mrows, 64, cDI / 8, cDI, cDI, 64, 0, 0,
              8, 1, 128, 0, 128, 0, (long)Mrows * 64, 0, 0, 0, 0, stream);
        splitk_reduce_kernel<<<(Mrows * 64 / 4 + 255) / 256, 256, 0, stream>>>(
            bufPre, bufXDBL, bufXDBLb, Mrows * 64 / 4, Mrows * 64 / 4, 8);
        bgemm_plain(1, 64, 128, bufXDBLb, dt_w, dt_b, nullptr, bufDelta, nullptr,
                    Mrows, cDI, cDTR, 64, cDTR, cDI, 0, 0, stream);
        // chunk-parallel scan (NCH=64 -> 2048 blocks/phase)
        scan_phase1<<<(int)(SUMSZ4 / 256), 256, 0, stream>>>(bufXM, bufDelta, bufXDBL, Alog, bufAP, bufSE);
        scan_phase2<<<(cB * cDI * cDS) / 256, 256, 0, stream>>>(bufAP, bufSE, bufSI);
        scan_phase3<<<(int)(SUMSZ4 / 256), 256, 0, stream>>>(bufXM, bufDelta, bufXDBL, Alog, Dv, bufXR, bufSI, bufY);
        bgemm_plain(0, 64, 64, bufY, out_w, nullptr, bufH, bufH, bufHb,
                    Mrows, cDM, cDI, cDI, cDI, cDM, cDM, cDM, stream);

        // ---- cross attention (KV/VT precomputed) ----
        bgemm_plain(0, 64, 64, bufHb, ain_w, ain_b, nullptr, nullptr, bufQ,
                    Mrows, cDM, cDM, cDM, cDM, 0, cDM, 0, stream);
        {
            dim3 g(cL / 32, cB * cH);
            flash_attn_kernel<<<g, 128, 0, stream>>>(bufQ, kv_l, vt_l, bufO,
                                                     0.08838834764831845f);
        }
        // pre = o @ aout_w.T + aout_b + h ; h = LN(pre)
        bgemm_plain(0, 64, 64, bufO, aout_w, aout_b, bufH, bufPre, nullptr,
                    Mrows, cDM, cDM, cDM, cDM, cDM, 0, cDM, stream);
        layernorm_kernel<<<Mrows, 256, 0, stream>>>(bufPre, ln_w, ln_b, bufH, bufHb, cDM);
    }

    // final: out = rmsnorm(h) @ W_out.T   (MFMA, 64^2 tile, N=80 edge-clamped)
    rmsnorm_kernel<<<Mrows, 256, 0, stream>>>(bufH, normf_w, nullptr, bufU, cDM);
    bgemm_plain(0, 64, 64, bufU, w_outf_b, nullptr, nullptr, out, nullptr,
                Mrows, cNM, cDM, cDM, cDM, cNM, 0, 0, stream);
}

// Round 11
// 770.262 us; speedup vs baseline: 9.1851x; 1.0353x over previous
//
#include <hip/hip_runtime.h>
#include <hip/hip_bf16.h>
#include <math.h>

typedef __hip_bfloat16 bf16;
typedef __attribute__((ext_vector_type(8))) short short8x;
typedef __attribute__((ext_vector_type(4))) float f32x4;

// ---- problem constants ----
static constexpr int cB   = 2;
static constexpr int cL   = 1024;
static constexpr int cLE  = 1024;
static constexpr int cNM  = 80;
static constexpr int cDM  = 512;
static constexpr int cLAYERS = 4;
static constexpr int cDS  = 16;
static constexpr int cKC  = 4;     // conv taps
static constexpr int cH   = 4;     // heads
static constexpr int cDI  = 1024;  // EXP*DM
static constexpr int cDTR = 32;
static constexpr int cHD  = 128;   // head dim

static constexpr int cNCH = 64;    // scan chunks (bit extraction below assumes 64)
static constexpr int cCHL = cL / cNCH;  // 16 steps per chunk

#define GLL16(g, l) __builtin_amdgcn_global_load_lds( \
    (const __attribute__((address_space(1))) void*)(g), \
    (__attribute__((address_space(3))) void*)(l), 16, 0, 0)

// =====================================================================
// bf16 MFMA GEMM, BMxBN tile, 4 waves (2x2), K-step 32.
// =====================================================================
template<int ACT, int BM, int BN>
__global__ __launch_bounds__(256)
void bgemm_kernel(const bf16* __restrict__ A, const bf16* __restrict__ W,
                  const float* __restrict__ bias, const float* __restrict__ addv,
                  float* __restrict__ Cf, bf16* __restrict__ Cb,
                  int M, int N, int Kd, int lda, int ldw, int ldcf, int ldcb, int ldadd,
                  int bdiv, long sA1, long sA2, long sW1, long sW2,
                  long sCf1, long sCf2, long sCb1, long sCb2, long sBias)
{
    constexpr int RM = BM / 32;
    constexpr int RN = BN / 32;
    const int z = blockIdx.z;
    const int i1 = z / bdiv, i2 = z % bdiv;
    A += i1 * sA1 + i2 * sA2;
    W += i1 * sW1 + i2 * sW2;
    if (bias) bias += i1 * sBias;

    const int bm = blockIdx.y * BM;
    const int bn = blockIdx.x * BN;
    const int tid = threadIdx.x;
    const int lane = tid & 63;
    const int wid = tid >> 6;
    const int wr = wid >> 1, wc = wid & 1;

    __shared__ bf16 As[BM * 32];
    __shared__ bf16 Bs[BN * 32];

    f32x4 acc[RM][RN] = {};

    const int r_in = lane >> 2;
    const int kb   = (lane & 3) * 8;
    const int hi   = lane >> 4;
    const int rc   = lane & 15;

    for (int k0 = 0; k0 < Kd; k0 += 32) {
#pragma unroll
        for (int iss = 0; iss < BM / 64; iss++) {
            const int row = wid * (BM / 4) + iss * 16 + r_in;
            int gm = bm + row; if (gm >= M) gm = M - 1;
            const bf16* ga = A + (long)gm * lda + k0 + kb;
            GLL16(ga, As + (wid * (BM / 4) + iss * 16) * 32);
        }
#pragma unroll
        for (int iss = 0; iss < BN / 64; iss++) {
            const int row = wid * (BN / 4) + iss * 16 + r_in;
            int gn = bn + row; if (gn >= N) gn = N - 1;
            const bf16* gb = W + (long)gn * ldw + k0 + kb;
            GLL16(gb, Bs + (wid * (BN / 4) + iss * 16) * 32);
        }
        asm volatile("s_waitcnt vmcnt(0)" ::: "memory");
        __syncthreads();

        short8x af[RM], bfv[RN];
#pragma unroll
        for (int i = 0; i < RM; i++)
            af[i] = *(const short8x*)(As + (wr * (BM / 2) + i * 16 + rc) * 32 + hi * 8);
#pragma unroll
        for (int j = 0; j < RN; j++)
            bfv[j] = *(const short8x*)(Bs + (wc * (BN / 2) + j * 16 + rc) * 32 + hi * 8);
#pragma unroll
        for (int i = 0; i < RM; i++)
#pragma unroll
            for (int j = 0; j < RN; j++)
                acc[i][j] = __builtin_amdgcn_mfma_f32_16x16x32_bf16(af[i], bfv[j], acc[i][j], 0, 0, 0);
        __syncthreads();
    }

    const long cfo = i1 * sCf1 + i2 * sCf2;
    const long cbo = i1 * sCb1 + i2 * sCb2;
#pragma unroll
    for (int i = 0; i < RM; i++) {
#pragma unroll
        for (int r = 0; r < 4; r++) {
            const int gm = bm + wr * (BM / 2) + i * 16 + hi * 4 + r;
            if (gm >= M) continue;
#pragma unroll
            for (int j = 0; j < RN; j++) {
                const int gn = bn + wc * (BN / 2) + j * 16 + rc;
                if (gn >= N) continue;
                float v = acc[i][j][r];
                if (bias) v += bias[gn];
                if (ACT == 1) v = (v > 20.f) ? v : log1pf(__expf(v));
                if (addv) v += addv[cfo + (long)gm * ldadd + gn];
                if (Cf) Cf[cfo + (long)gm * ldcf + gn] = v;
                if (Cb) Cb[cbo + (long)gm * ldcb + gn] = __float2bfloat16(v);
            }
        }
    }
}

static inline void bgemm(int ACT, int BM, int BN, const bf16* A, const bf16* W, const float* bias,
                         const float* addv, float* Cf, bf16* Cb,
                         int M, int N, int Kd, int lda, int ldw, int ldcf, int ldcb, int ldadd,
                         int nz, int bdiv, long sA1, long sA2, long sW1, long sW2,
                         long sCf1, long sCf2, long sCb1, long sCb2, long sBias, hipStream_t s)
{
    dim3 g((N + BN - 1) / BN, (M + BM - 1) / BM, nz), b(256);
#define BG_ARGS A, W, bias, addv, Cf, Cb, M, N, Kd, lda, ldw, ldcf, ldcb, ldadd, \
                bdiv, sA1, sA2, sW1, sW2, sCf1, sCf2, sCb1, sCb2, sBias
    if (BM == 128) {
        if (ACT == 1) bgemm_kernel<1, 128, 128><<<g, b, 0, s>>>(BG_ARGS);
        else          bgemm_kernel<0, 128, 128><<<g, b, 0, s>>>(BG_ARGS);
    } else if (BN == 128) {
        if (ACT == 1) bgemm_kernel<1, 64, 128><<<g, b, 0, s>>>(BG_ARGS);
        else          bgemm_kernel<0, 64, 128><<<g, b, 0, s>>>(BG_ARGS);
    } else {
        bgemm_kernel<0, 64, 64><<<g, b, 0, s>>>(BG_ARGS);
    }
#undef BG_ARGS
}

static inline void bgemm_plain(int ACT, int BM, int BN, const bf16* A, const bf16* W,
                               const float* bias, const float* addv, float* Cf, bf16* Cb,
                               int M, int N, int Kd, int lda, int ldw, int ldcf, int ldcb,
                               int ldadd, hipStream_t s)
{
    bgemm(ACT, BM, BN, A, W, bias, addv, Cf, Cb, M, N, Kd, lda, ldw, ldcf, ldcb, ldadd,
          1, 1, 0, 0, 0, 0, 0, 0, 0, 0, 0, s);
}

// =====================================================================
// Fused flash cross-attention WITH in-kernel Q projection.
//   Hb: [B*L][DM] bf16 (LN output);  Wq = ain_w rows 0..DM-1 (N x K bf16);
//   bq = ain_b[0..DM).  K: bufKV [B*LE][2*DM] (K cols 0..511);
//   VT: [B*DM][LE] bf16;  O: [B*L][DM] bf16.
// =====================================================================
__global__ __launch_bounds__(128)
void flash_attn_kernel(const bf16* __restrict__ Hb, const bf16* __restrict__ Wq,
                       const float* __restrict__ bq,
                       const bf16* __restrict__ Kp, const bf16* __restrict__ VTp,
                       bf16* __restrict__ Op, float scale)
{
    const int qt = blockIdx.x;            // 0..31
    const int bh = blockIdx.y;            // b*H + h
    const int b = bh >> 2, h = bh & 3;
    const int tid = threadIdx.x;
    const int w = tid >> 6;               // 0..1
    const int lane = tid & 63;
    const int rc = lane & 15, hi = lane >> 4;
    const int rlo = rc & 7;
    const int r_in = lane >> 2;           // staging row
    const int kb   = (lane & 3) * 8;      // staging k offset

    __shared__ bf16 Qs[32 * 128];
    __shared__ bf16 Ks[64 * 128];
    __shared__ bf16 Vs[128 * 64];
    __shared__ bf16 Ps[32 * 64];

    // ---- Q projection: Q[32][128] = Hb tile @ Wq(head h)^T + bq ----
    {
        bf16* HsT = Vs;                    // [32][32] scratch
        bf16* WsT = Ks;                    // [128][32] scratch
        const bf16* hb0 = Hb + ((long)(b * cL + qt * 32)) * cDM;
        const bf16* wq0 = Wq + (long)h * cHD * cDM;
        f32x4 qacc[8] = {};
        for (int k0 = 0; k0 < cDM; k0 += 32) {
            __syncthreads();
            GLL16(hb0 + (long)(w * 16 + r_in) * cDM + k0 + kb, HsT + (w * 16) * 32);
#pragma unroll
            for (int iss = 0; iss < 4; iss++)
                GLL16(wq0 + (long)(iss * 32 + w * 16 + r_in) * cDM + k0 + kb,
                      WsT + (iss * 32 + w * 16) * 32);
            asm volatile("s_waitcnt vmcnt(0)" ::: "memory");
            __syncthreads();
            short8x aH = *(const short8x*)(HsT + (w * 16 + rc) * 32 + hi * 8);
#pragma unroll
            for (int j = 0; j < 8; j++) {
                short8x bW = *(const short8x*)(WsT + (j * 16 + rc) * 32 + hi * 8);
                qacc[j] = __builtin_amdgcn_mfma_f32_16x16x32_bf16(aH, bW, qacc[j], 0, 0, 0);
            }
        }
        __syncthreads();
        // write Q tile swizzled (same scheme as K/Q loads: chunk ^= row&7)
#pragma unroll
        for (int j2 = 0; j2 < 8; j2++)
#pragma unroll
            for (int r = 0; r < 4; r++) {
                const int qrow = w * 16 + hi * 4 + r;
                const int col = j2 * 16 + rc;
                const float qv = qacc[j2][r] + bq[h * cHD + col];
                Qs[qrow * 128 + (((col >> 3) ^ (qrow & 7)) << 3) + (col & 7)] =
                    __float2bfloat16(qv);
            }
    }
    __syncthreads();

    // hoist Q A-fragments
    short8x aq[4];
#pragma unroll
    for (int kk = 0; kk < 4; kk++) {
        const int sc = (kk * 4 + hi) ^ rlo;
        aq[kk] = *(const short8x*)(Qs + (w * 16 + rc) * 128 + sc * 8);
    }

    float m_r[4], l_r[4];
#pragma unroll
    for (int r = 0; r < 4; r++) { m_r[r] = -1e30f; l_r[r] = 0.f; }
    f32x4 oacc[8] = {};

    const bf16* kb0 = Kp + ((long)(b * cLE)) * (2 * cDM) + h * cHD;
    const bf16* vb0 = VTp + ((long)(b * cDM + h * cHD)) * cLE;

    for (int kt = 0; kt < 16; kt++) {
        __syncthreads();
#pragma unroll
        for (int c = 0; c < 8; c++) {
            const int row = w * 32 + c * 4 + (lane >> 4);
            const int gc = (lane & 15) ^ (row & 7);
            GLL16(kb0 + ((long)(kt * 64 + row)) * (2 * cDM) + gc * 8,
                  Ks + (w * 32 + c * 4) * 128);
        }
#pragma unroll
        for (int c = 0; c < 8; c++) {
            const int row = w * 64 + c * 8 + (lane >> 3);
            const int gc = (lane & 7) ^ (row & 7);
            GLL16(vb0 + (long)row * cLE + kt * 64 + gc * 8,
                  Vs + (w * 64 + c * 8) * 64);
        }
        asm volatile("s_waitcnt vmcnt(0)" ::: "memory");
        __syncthreads();

        f32x4 s[4] = {};
#pragma unroll
        for (int kk = 0; kk < 4; kk++) {
            const int sc = (kk * 4 + hi) ^ rlo;
#pragma unroll
            for (int j = 0; j < 4; j++) {
                short8x bk = *(const short8x*)(Ks + (j * 16 + rc) * 128 + sc * 8);
                s[j] = __builtin_amdgcn_mfma_f32_16x16x32_bf16(aq[kk], bk, s[j], 0, 0, 0);
            }
        }

        float p[4][4];
        float esc[4];
#pragma unroll
        for (int r = 0; r < 4; r++) {
            const float v0 = s[0][r] * scale, v1 = s[1][r] * scale;
            const float v2 = s[2][r] * scale, v3 = s[3][r] * scale;
            float mx = fmaxf(fmaxf(v0, v1), fmaxf(v2, v3));
            mx = fmaxf(mx, __shfl_xor(mx, 1));
            mx = fmaxf(mx, __shfl_xor(mx, 2));
            mx = fmaxf(mx, __shfl_xor(mx, 4));
            mx = fmaxf(mx, __shfl_xor(mx, 8));
            const float mn = fmaxf(m_r[r], mx);
            p[0][r] = __expf(v0 - mn);
            p[1][r] = __expf(v1 - mn);
            p[2][r] = __expf(v2 - mn);
            p[3][r] = __expf(v3 - mn);
            float rs = (p[0][r] + p[1][r]) + (p[2][r] + p[3][r]);
            rs += __shfl_xor(rs, 1);
            rs += __shfl_xor(rs, 2);
            rs += __shfl_xor(rs, 4);
            rs += __shfl_xor(rs, 8);
            esc[r] = __expf(m_r[r] - mn);
            l_r[r] = l_r[r] * esc[r] + rs;
            m_r[r] = mn;
        }
#pragma unroll
        for (int j2 = 0; j2 < 8; j2++)
#pragma unroll
            for (int r = 0; r < 4; r++)
                oacc[j2][r] *= esc[r];
#pragma unroll
        for (int j = 0; j < 4; j++)
#pragma unroll
            for (int r = 0; r < 4; r++) {
                const int q = w * 16 + hi * 4 + r;
                const int cp = (j * 2 + (rc >> 3)) ^ (q & 7);
                Ps[q * 64 + cp * 8 + (rc & 7)] = __float2bfloat16(p[j][r]);
            }
        __syncthreads();
#pragma unroll
        for (int ks = 0; ks < 2; ks++) {
            const int sc = (ks * 4 + hi) ^ rlo;
            short8x ap = *(const short8x*)(Ps + (w * 16 + rc) * 64 + sc * 8);
#pragma unroll
            for (int j2 = 0; j2 < 8; j2++) {
                short8x bv = *(const short8x*)(Vs + (j2 * 16 + rc) * 64 + sc * 8);
                oacc[j2] = __builtin_amdgcn_mfma_f32_16x16x32_bf16(ap, bv, oacc[j2], 0, 0, 0);
            }
        }
    }

    float inv[4];
#pragma unroll
    for (int r = 0; r < 4; r++) inv[r] = 1.f / l_r[r];
    bf16* ob = Op + ((long)(b * cL + qt * 32)) * cDM + h * cHD;
#pragma unroll
    for (int j2 = 0; j2 < 8; j2++)
#pragma unroll
        for (int r = 0; r < 4; r++)
            ob[(long)(w * 16 + hi * 4 + r) * cDM + j2 * 16 + rc] =
                __float2bfloat16(oacc[j2][r] * inv[r]);
}

// =====================================================================
// split-K partial reduce:  out = sum_s parts[s]  (f32 + bf16 outputs)
// =====================================================================
__global__ void splitk_reduce_kernel(const float* __restrict__ parts, float* __restrict__ outf,
                                     bf16* __restrict__ outb, int n4, int sliceN4, int S)
{
    const int i = blockIdx.x * 256 + threadIdx.x;
    if (i >= n4) return;
    float4 a = ((const float4*)parts)[i];
    for (int s2 = 1; s2 < S; s2++) {
        float4 b2 = ((const float4*)parts)[i + (long)s2 * sliceN4];
        a.x += b2.x; a.y += b2.y; a.z += b2.z; a.w += b2.w;
    }
    ((float4*)outf)[i] = a;
    bf16 b0 = __float2bfloat16(a.x), b1 = __float2bfloat16(a.y);
    bf16 b2 = __float2bfloat16(a.z), b3 = __float2bfloat16(a.w);
    short4 pk = { *(short*)&b0, *(short*)&b1, *(short*)&b2, *(short*)&b3 };
    ((short4*)outb)[i] = pk;
}

// =====================================================================
// One-shot fused f32->bf16 conversion of all weight tensors + enc.
// =====================================================================
__global__ void cvt_all_kernel(
    const float* __restrict__ s0, bf16* __restrict__ d0,   // enc
    const float* __restrict__ s1, bf16* __restrict__ d1,   // m_in_w
    const float* __restrict__ s2, bf16* __restrict__ d2,   // m_xproj
    const float* __restrict__ s3, bf16* __restrict__ d3,   // m_dt_w
    const float* __restrict__ s4, bf16* __restrict__ d4,   // m_out_w
    const float* __restrict__ s5, bf16* __restrict__ d5,   // a_in_w
    const float* __restrict__ s6, bf16* __restrict__ d6,   // a_out_w
    const float* __restrict__ s7, bf16* __restrict__ d7)   // W_out
{
    constexpr long E0 = 1048576, E1 = 4194304, E2 = 262144, E3 = 131072;
    constexpr long E4 = 2097152, E5 = 3145728, E6 = 1048576, E7 = 40960;
    constexpr long C0 = E0, C1 = C0 + E1, C2 = C1 + E2, C3 = C2 + E3;
    constexpr long C4 = C3 + E4, C5 = C4 + E5, C6 = C5 + E6, C7 = C6 + E7;
    long i = ((long)blockIdx.x * 256 + threadIdx.x) * 4;
    if (i >= C7) return;
    const float* s; bf16* d;
    if      (i < C0) { s = s0; d = d0; }
    else if (i < C1) { s = s1; d = d1; i -= C0; }
    else if (i < C2) { s = s2; d = d2; i -= C1; }
    else if (i < C3) { s = s3; d = d3; i -= C2; }
    else if (i < C4) { s = s4; d = d4; i -= C3; }
    else if (i < C5) { s = s5; d = d5; i -= C4; }
    else if (i < C6) { s = s6; d = d6; i -= C5; }
    else             { s = s7; d = d7; i -= C6; }
    float4 v = *(const float4*)(s + i);
    d[i]     = __float2bfloat16(v.x);
    d[i + 1] = __float2bfloat16(v.y);
    d[i + 2] = __float2bfloat16(v.z);
    d[i + 3] = __float2bfloat16(v.w);
}

// f32 (rows x kin) -> bf16 (rows x kout), zero-padded beyond kin
__global__ void cvt_pad_kernel(const float* __restrict__ in, bf16* __restrict__ out,
                               int rows, int kin, int kout)
{
    const int idx = blockIdx.x * 256 + threadIdx.x;
    if (idx >= rows * kout) return;
    const int r = idx / kout, k = idx - r * kout;
    out[idx] = __float2bfloat16(k < kin ? in[(long)r * kin + k] : 0.f);
}

// =====================================================================
// bf16 transpose, batched over (layer, batch):  z = lay*cB + b.
// =====================================================================
__global__ void transpose_bf16_kernel(const bf16* __restrict__ in, bf16* __restrict__ out,
                                      int ldin, int col0, long inLS, long outLS)
{
    __shared__ bf16 t[32][33];
    const int z = blockIdx.z;
    const int lay = z >> 1, b = z & 1;
    in  += (long)lay * inLS;
    out += (long)lay * outLS;
    const int le0 = blockIdx.x * 32, d0 = blockIdx.y * 32;
    const int tid = threadIdx.x;
    const int c = tid & 31, r = tid >> 5;
    for (int i = r; i < 32; i += 8)
        t[i][c] = in[((long)b * cLE + le0 + i) * ldin + col0 + d0 + c];
    __syncthreads();
    for (int i = r; i < 32; i += 8)
        out[((long)b * cDM + d0 + i) * cLE + le0 + c] = t[c][i];
}

// =====================================================================
// RMSNorm per row (optional f32 and bf16 outputs) — layer-0 entry + misc
// =====================================================================
__global__ void rmsnorm_kernel(const float* __restrict__ x, const float* __restrict__ w,
                               float* __restrict__ outf, bf16* __restrict__ outb, int Dm)
{
    const int row = blockIdx.x;
    const float* xr = x + (long)row * Dm;
    float s = 0.f;
    for (int i = threadIdx.x; i < Dm; i += 256) { float v = xr[i]; s += v * v; }
    __shared__ float red[5];
    const int lane = threadIdx.x & 63, wv = threadIdx.x >> 6;
#pragma unroll
    for (int off = 1; off < 64; off <<= 1) s += __shfl_xor(s, off);
    if (lane == 0) red[wv] = s;
    __syncthreads();
    if (threadIdx.x == 0) {
        float t = red[0] + red[1] + red[2] + red[3];
        red[4] = rsqrtf(t / Dm + 1e-5f);
    }
    __syncthreads();
    const float scale = red[4];
    for (int i = threadIdx.x; i < Dm; i += 256) {
        float v = xr[i] * scale * w[i];
        if (outf) outf[(long)row * Dm + i] = v;
        if (outb) outb[(long)row * Dm + i] = __float2bfloat16(v);
    }
}

// =====================================================================
// LayerNorm per row (Dm=512 fixed, 2 elems/thread) -> f32 + bf16 outputs,
// PLUS fused RMSNorm of the LN output with rms_w -> rms_out (bf16).
// =====================================================================
__global__ void layernorm_kernel(const float* __restrict__ x, const float* __restrict__ w,
                                 const float* __restrict__ b, float* __restrict__ outf,
                                 bf16* __restrict__ outb,
                                 const float* __restrict__ rms_w, bf16* __restrict__ rms_out)
{
    const int row = blockIdx.x;
    const float* xr = x + (long)row * 512;
    const int t = threadIdx.x;
    const int i0 = t, i1 = t + 256;
    float x0 = xr[i0], x1 = xr[i1];
    float s = x0 + x1, sq = x0 * x0 + x1 * x1;
    __shared__ float red[8];
    __shared__ float mv[2];
    const int lane = t & 63, wv = t >> 6;
#pragma unroll
    for (int off = 1; off < 64; off <<= 1) { s += __shfl_xor(s, off); sq += __shfl_xor(sq, off); }
    if (lane == 0) { red[wv] = s; red[4 + wv] = sq; }
    __syncthreads();
    if (t == 0) {
        float ts = red[0] + red[1] + red[2] + red[3];
        float tq = red[4] + red[5] + red[6] + red[7];
        float m = ts / 512.f;
        float var = tq / 512.f - m * m;
        mv[0] = m;
        mv[1] = rsqrtf(var + 1e-5f);
    }
    __syncthreads();
    const float m = mv[0], rs = mv[1];
    const float v0 = (x0 - m) * rs * w[i0] + b[i0];
    const float v1 = (x1 - m) * rs * w[i1] + b[i1];
    outf[(long)row * 512 + i0] = v0;
    outf[(long)row * 512 + i1] = v1;
    outb[(long)row * 512 + i0] = __float2bfloat16(v0);
    outb[(long)row * 512 + i1] = __float2bfloat16(v1);
    // fused RMS of v
    float s2 = v0 * v0 + v1 * v1;
#pragma unroll
    for (int off = 1; off < 64; off <<= 1) s2 += __shfl_xor(s2, off);
    if (lane == 0) red[wv] = s2;
    __syncthreads();
    if (t == 0) mv[0] = rsqrtf((red[0] + red[1] + red[2] + red[3]) / 512.f + 1e-5f);
    __syncthreads();
    const float rsc = mv[0];
    rms_out[(long)row * 512 + i0] = __float2bfloat16(v0 * rsc * rms_w[i0]);
    rms_out[(long)row * 512 + i1] = __float2bfloat16(v1 * rsc * rms_w[i1]);
}

// =====================================================================
// Causal depthwise conv (K=4) + bias + SiLU -> xm f32 + bf16
// =====================================================================
__global__ void conv_silu_kernel(const float* __restrict__ xr, const float* __restrict__ w,
                                 const float* __restrict__ bias, float* __restrict__ xm,
                                 bf16* __restrict__ xmb)
{
    const int idx = blockIdx.x * 256 + threadIdx.x;
    if (idx >= cB * cL * cDI) return;
    const int d = idx & (cDI - 1);
    const int l = (idx >> 10) & (cL - 1);
    const int b = idx >> 20;
    float s = bias[d];
#pragma unroll
    for (int j = 0; j < cKC; j++) {
        const int ls = l + j - (cKC - 1);
        if (ls >= 0) s += w[d * cKC + j] * xr[((long)(b * cL + ls)) * (2 * cDI) + d];
    }
    s = s / (1.f + __expf(-s));
    xm[(long)idx] = s;
    xmb[(long)idx] = __float2bfloat16(s);
}

// =====================================================================
// Chunk-parallel selective scan, 4 states (n) per thread, NCH=64 chunks.
// =====================================================================
__global__ void scan_phase1(const float* __restrict__ xm, const float* __restrict__ delta,
                            const float* __restrict__ xdbl, const float* __restrict__ Alog,
                            float* __restrict__ aprod_out, float* __restrict__ send_out)
{
    const int idx4 = blockIdx.x * 256 + threadIdx.x;   // cB*cNCH*cDI*4
    const int ng = idx4 & 3;
    const int d  = (idx4 >> 2) & (cDI - 1);
    const int ch = (idx4 >> 12) & (cNCH - 1);
    const int b  = idx4 >> 18;
    const float4 Al = *(const float4*)(Alog + d * cDS + 4 * ng);
    const float A0 = -__expf(Al.x), A1 = -__expf(Al.y), A2 = -__expf(Al.z), A3 = -__expf(Al.w);
    float s0 = 0.f, s1 = 0.f, s2 = 0.f, s3 = 0.f;
    float p0 = 1.f, p1 = 1.f, p2 = 1.f, p3 = 1.f;
    const int l0 = ch * cCHL;
    const float* dp = delta + (long)(b * cL + l0) * cDI + d;
    const float* up = xm    + (long)(b * cL + l0) * cDI + d;
    const float* xb = xdbl  + (long)(b * cL + l0) * 64 + cDTR + 4 * ng;
#pragma unroll
    for (int t = 0; t < cCHL; t++) {
        const float dl = dp[(long)t * cDI];
        const float du = dl * up[(long)t * cDI];
        const float4 Bv = *(const float4*)(xb + (long)t * 64);
        const float a0 = __expf(dl * A0), a1 = __expf(dl * A1);
        const float a2 = __expf(dl * A2), a3 = __expf(dl * A3);
        s0 = a0 * s0 + du * Bv.x; p0 *= a0;
        s1 = a1 * s1 + du * Bv.y; p1 *= a1;
        s2 = a2 * s2 + du * Bv.z; p2 *= a2;
        s3 = a3 * s3 + du * Bv.w; p3 *= a3;
    }
    const long base4 = (((long)(b * cNCH + ch) * cDI + d) * cDS) + 4 * ng;
    float4 pv = { p0, p1, p2, p3 };
    float4 sv = { s0, s1, s2, s3 };
    *(float4*)(aprod_out + base4) = pv;
    *(float4*)(send_out + base4)  = sv;
}

__global__ void scan_phase2(const float* __restrict__ aprod, const float* __restrict__ send,
                            float* __restrict__ sinit)
{
    const int j = blockIdx.x * 64 + threadIdx.x;    // cB*cDI*cDS, 64-thr blocks
    const int n = j & (cDS - 1);
    const int d = (j >> 4) & (cDI - 1);
    const int b = j >> 14;
    float s = 0.f;
#pragma unroll
    for (int c = 0; c < cNCH; c++) {
        const long off = (((long)(b * cNCH + c) * cDI + d) * cDS) + n;
        sinit[off] = s;
        s = aprod[off] * s + send[off];
    }
}

__global__ void scan_phase3(const float* __restrict__ xm, const float* __restrict__ delta,
                            const float* __restrict__ xdbl, const float* __restrict__ Alog,
                            const float* __restrict__ Dv, const float* __restrict__ xr,
                            const float* __restrict__ sinit, bf16* __restrict__ y)
{
    const int idx4 = blockIdx.x * 256 + threadIdx.x;   // cB*cNCH*cDI*4
    const int ng = idx4 & 3;
    const int d  = (idx4 >> 2) & (cDI - 1);
    const int ch = (idx4 >> 12) & (cNCH - 1);
    const int b  = idx4 >> 18;
    const float4 Al = *(const float4*)(Alog + d * cDS + 4 * ng);
    const float A0 = -__expf(Al.x), A1 = -__expf(Al.y), A2 = -__expf(Al.z), A3 = -__expf(Al.w);
    const float Dval = Dv[d];
    const long base4 = (((long)(b * cNCH + ch) * cDI + d) * cDS) + 4 * ng;
    float4 st = *(const float4*)(sinit + base4);
    float s0 = st.x, s1 = st.y, s2 = st.z, s3 = st.w;
    const int l0 = ch * cCHL;
    const float* dp = delta + (long)(b * cL + l0) * cDI + d;
    const float* up = xm    + (long)(b * cL + l0) * cDI + d;
    const float* xb = xdbl  + (long)(b * cL + l0) * 64 + cDTR + 4 * ng;
    const float* xc = xb + cDS;
    const float* rp = xr + (long)(b * cL + l0) * (2 * cDI) + cDI + d;
    bf16* yp = y + (long)(b * cL + l0) * cDI + d;
#pragma unroll
    for (int t = 0; t < cCHL; t++) {
        const float dl = dp[(long)t * cDI];
        const float u  = up[(long)t * cDI];
        const float du = dl * u;
        const float4 Bv = *(const float4*)(xb + (long)t * 64);
        const float4 Cv = *(const float4*)(xc + (long)t * 64);
        const float a0 = __expf(dl * A0), a1 = __expf(dl * A1);
        const float a2 = __expf(dl * A2), a3 = __expf(dl * A3);
        s0 = a0 * s0 + du * Bv.x;
        s1 = a1 * s1 + du * Bv.y;
        s2 = a2 * s2 + du * Bv.z;
        s3 = a3 * s3 + du * Bv.w;
        float c = s0 * Cv.x;
        c = fmaf(s1, Cv.y, c);
        c = fmaf(s2, Cv.z, c);
        c = fmaf(s3, Cv.w, c);
        c += __shfl_xor(c, 1);
        c += __shfl_xor(c, 2);
        if (ng == 0) {
            const float res = rp[(long)t * 2 * cDI];
            const float sig = 1.f / (1.f + __expf(-res));
            yp[(long)t * cDI] = __float2bfloat16((c + u * Dval) * (res * sig));
        }
    }
}

// =====================================================================
extern "C" void kernel_launch(void* const* d_in, const int* in_sizes, int n_in,
                              void* d_out, int out_size, void* d_ws, size_t ws_size,
                              hipStream_t stream)
{
    const float* x       = (const float*)d_in[0];
    const float* enc     = (const float*)d_in[1];
    const float* W_in    = (const float*)d_in[2];
    const float* b_in    = (const float*)d_in[3];
    const float* m_norm_w= (const float*)d_in[4];
    const float* m_in_w  = (const float*)d_in[5];
    const float* m_conv_w= (const float*)d_in[6];
    const float* m_conv_b= (const float*)d_in[7];
    const float* m_xproj = (const float*)d_in[8];
    const float* m_dt_w  = (const float*)d_in[9];
    const float* m_dt_b  = (const float*)d_in[10];
    const float* m_Alog  = (const float*)d_in[11];
    const float* m_D     = (const float*)d_in[12];
    const float* m_out_w = (const float*)d_in[13];
    const float* a_in_w  = (const float*)d_in[14];
    const float* a_in_b  = (const float*)d_in[15];
    const float* a_out_w = (const float*)d_in[16];
    const float* a_out_b = (const float*)d_in[17];
    const float* a_ln_w  = (const float*)d_in[18];
    const float* a_ln_b  = (const float*)d_in[19];
    const float* normf_w = (const float*)d_in[20];
    const float* W_out   = (const float*)d_in[21];
    float* out = (float*)d_out;

    float* ws = (float*)d_ws;
    long off = 0;
    auto allocf = [&](long n) { float* p = ws + off; off += n; return p; };

    const long M1 = 1 << 20;
    float* bufH    = allocf(M1);
    float* bufPre  = allocf(M1);         // also xproj split-K partials
    float* bufXR   = allocf(4 * M1);
    float* bufXM   = allocf(2 * M1);
    float* bufDelta= allocf(2 * M1);
    float* bufXDBL = allocf(M1 / 8);
    bf16* bufU    = (bf16*)allocf(M1 / 2);      // 2048x512 bf16 (rms output)
    bf16* bufHb   = (bf16*)allocf(M1 / 2);
    bf16* bufXMb  = (bf16*)allocf(M1);          // 2048x1024 bf16
    bf16* bufXDBLb= (bf16*)allocf(M1 / 16);
    bf16* bufY    = (bf16*)allocf(M1);          // 2048x1024 bf16
    bf16* bufO    = (bf16*)allocf(M1 / 2);
    bf16* encb    = (bf16*)allocf(M1 / 2);
    bf16* w_in_b  = (bf16*)allocf(2 * M1);      // mamba in_w (4 layers)
    bf16* w_xp_b  = (bf16*)allocf(M1 / 8);
    bf16* w_dt_b  = (bf16*)allocf(M1 / 16);
    bf16* w_out_b = (bf16*)allocf(M1);
    bf16* w_ain_b = (bf16*)allocf(3 * M1 / 2);
    bf16* w_aout_b= (bf16*)allocf(M1 / 2);
    bf16* x_pad   = (bf16*)allocf(2048L * 96 / 2);   // x zero-padded K=96
    bf16* w_inp_b = (bf16*)allocf(512L * 96 / 2);    // W_in zero-padded K=96
    bf16* w_outf_b= (bf16*)allocf(80L * 512 / 2);    // W_out bf16
    // dedicated scan summaries at NCH=64: B*NCH*DI*DS = 2M floats each
    float* bufAP  = allocf(2 * M1);
    float* bufSE  = allocf(2 * M1);
    float* bufSI  = allocf(2 * M1);
    // all-layer K|V and V^T
    bf16* bufKV4  = (bf16*)allocf(4 * M1);      // 4 layers x 2M bf16
    bf16* bufVT4  = (bf16*)allocf(2 * M1);      // 4 layers x 1M bf16

    const int Mrows = cB * cL;   // 2048
    const long SUMSZ4 = (long)cB * cNCH * cDI * 4;   // 524288
    const long kvLS = (long)Mrows * 2 * cDM;
    const long vtLS = (long)cB * cDM * cLE;

    // ---- one-time conversions ----
    cvt_all_kernel<<<11688, 256, 0, stream>>>(
        enc, encb, m_in_w, w_in_b, m_xproj, w_xp_b, m_dt_w, w_dt_b,
        m_out_w, w_out_b, a_in_w, w_ain_b, a_out_w, w_aout_b, W_out, w_outf_b);
    cvt_pad_kernel<<<(Mrows * 96 + 255) / 256, 256, 0, stream>>>(x, x_pad, Mrows, cNM, 96);
    cvt_pad_kernel<<<(cDM * 96 + 255) / 256, 256, 0, stream>>>(W_in, w_inp_b, cDM, cNM, 96);

    // ---- all-layer K|V projection + V^T ----
    bgemm(0, 64, 128, encb, w_ain_b + (long)cDM * cDM, a_in_b + cDM, nullptr, nullptr, bufKV4,
          Mrows, 2 * cDM, cDM, cDM, cDM, 0, 2 * cDM, 0,
          cLAYERS, 1,
          0, 0,
          (long)3 * cDM * cDM, 0,
          0, 0, kvLS, 0,
          (long)3 * cDM,
          stream);
    {
        dim3 g(cLE / 32, cDM / 32, cLAYERS * cB);
        transpose_bf16_kernel<<<g, 256, 0, stream>>>(bufKV4, bufVT4, 2 * cDM, cDM, kvLS, vtLS);
    }

    // h = x @ W_in.T + b_in ; then layer-0 rmsnorm -> bufU
    bgemm_plain(0, 64, 64, x_pad, w_inp_b, b_in, nullptr, bufH, nullptr,
                Mrows, cDM, 96, 96, 96, cDM, 0, 0, stream);
    rmsnorm_kernel<<<Mrows, 256, 0, stream>>>(bufH, m_norm_w, nullptr, bufU, cDM);

    for (int i = 0; i < cLAYERS; i++) {
        const bf16*  in_w   = w_in_b   + (long)i * 2 * cDI * cDM;
        const float* conv_w = m_conv_w + (long)i * cDI * cKC;
        const float* conv_b = m_conv_b + (long)i * cDI;
        const bf16*  xproj  = w_xp_b   + (long)i * 64 * cDI;
        const bf16*  dt_w   = w_dt_b   + (long)i * cDI * cDTR;
        const float* dt_b   = m_dt_b   + (long)i * cDI;
        const float* Alog   = m_Alog   + (long)i * cDI * cDS;
        const float* Dv     = m_D      + (long)i * cDI;
        const bf16*  out_w  = w_out_b  + (long)i * cDM * cDI;
        const bf16*  ain_w  = w_ain_b  + (long)i * 3 * cDM * cDM;
        const float* ain_b  = a_in_b   + (long)i * 3 * cDM;
        const bf16*  aout_w = w_aout_b + (long)i * cDM * cDM;
        const float* aout_b = a_out_b  + (long)i * cDM;
        const float* ln_w   = a_ln_w   + (long)i * cDM;
        const float* ln_b   = a_ln_b   + (long)i * cDM;
        const bf16*  kv_l   = bufKV4 + (long)i * kvLS;
        const bf16*  vt_l   = bufVT4 + (long)i * vtLS;
        // weight for the RMS that follows this layer's LN (next layer's norm, or final)
        const float* next_rms_w = (i + 1 < cLAYERS) ? (m_norm_w + (long)(i + 1) * cDM) : normf_w;

        // ---- mamba (bufU holds rmsnorm(h) bf16) ----
        bgemm_plain(0, 64, 128, bufU, in_w, nullptr, nullptr, bufXR, nullptr,
                    Mrows, 2 * cDI, cDM, cDM, cDM, 2 * cDI, 0, 0, stream);
        conv_silu_kernel<<<(cB * cL * cDI) / 256, 256, 0, stream>>>(bufXR, conv_w, conv_b, bufXM, bufXMb);
        bgemm(0, 64, 64, bufXMb, xproj, nullptr, nullptr, bufPre, nullptr,
              Mrows, 64, cDI / 8, cDI, cDI, 64, 0, 0,
              8, 1, 128, 0, 128, 0, (long)Mrows * 64, 0, 0, 0, 0, stream);
        splitk_reduce_kernel<<<(Mrows * 64 / 4 + 255) / 256, 256, 0, stream>>>(
            bufPre, bufXDBL, bufXDBLb, Mrows * 64 / 4, Mrows * 64 / 4, 8);
        bgemm_plain(1, 64, 128, bufXDBLb, dt_w, dt_b, nullptr, bufDelta, nullptr,
                    Mrows, cDI, cDTR, 64, cDTR, cDI, 0, 0, stream);
        scan_phase1<<<(int)(SUMSZ4 / 256), 256, 0, stream>>>(bufXM, bufDelta, bufXDBL, Alog, bufAP, bufSE);
        scan_phase2<<<(cB * cDI * cDS) / 64, 64, 0, stream>>>(bufAP, bufSE, bufSI);
        scan_phase3<<<(int)(SUMSZ4 / 256), 256, 0, stream>>>(bufXM, bufDelta, bufXDBL, Alog, Dv, bufXR, bufSI, bufY);
        bgemm_plain(0, 64, 64, bufY, out_w, nullptr, bufH, bufH, bufHb,
                    Mrows, cDM, cDI, cDI, cDI, cDM, cDM, cDM, stream);

        // ---- cross attention (Q computed in-kernel; KV/VT precomputed) ----
        {
            dim3 g(cL / 32, cB * cH);
            flash_attn_kernel<<<g, 128, 0, stream>>>(bufHb, ain_w, ain_b, kv_l, vt_l, bufO,
                                                     0.08838834764831845f);
        }
        // pre = o @ aout_w.T + aout_b + h ; h = LN(pre) (+ fused next-RMS -> bufU)
        bgemm_plain(0, 64, 64, bufO, aout_w, aout_b, bufH, bufPre, nullptr,
                    Mrows, cDM, cDM, cDM, cDM, cDM, 0, cDM, stream);
        layernorm_kernel<<<Mrows, 256, 0, stream>>>(bufPre, ln_w, ln_b, bufH, bufHb,
                                                    next_rms_w, bufU);
    }

    // final: out = bufU(= rms(h, normf_w)) @ W_out.T
    bgemm_plain(0, 64, 64, bufU, w_outf_b, nullptr, nullptr, out, nullptr,
                Mrows, cNM, cDM, cDM, cDM, cNM, 0, 0, stream);
}

// Round 12
// 739.579 us; speedup vs baseline: 9.5661x; 1.0415x over previous
//
#include <hip/hip_runtime.h>
#include <hip/hip_bf16.h>
#include <math.h>

typedef __hip_bfloat16 bf16;
typedef __attribute__((ext_vector_type(8))) short short8x;
typedef __attribute__((ext_vector_type(4))) float f32x4;

// ---- problem constants ----
static constexpr int cB   = 2;
static constexpr int cL   = 1024;
static constexpr int cLE  = 1024;
static constexpr int cNM  = 80;
static constexpr int cDM  = 512;
static constexpr int cLAYERS = 4;
static constexpr int cDS  = 16;
static constexpr int cKC  = 4;     // conv taps
static constexpr int cH   = 4;     // heads
static constexpr int cDI  = 1024;  // EXP*DM
static constexpr int cDTR = 32;
static constexpr int cHD  = 128;   // head dim

static constexpr int cNCH = 64;    // scan chunks (bit extraction below assumes 64)
static constexpr int cCHL = cL / cNCH;  // 16 steps per chunk
static constexpr int cSPL = 4;     // flash KV splits

#define GLL16(g, l) __builtin_amdgcn_global_load_lds( \
    (const __attribute__((address_space(1))) void*)(g), \
    (__attribute__((address_space(3))) void*)(l), 16, 0, 0)

// =====================================================================
// bf16 MFMA GEMM, BMxBN tile, 4 waves (2x2), K-step 32.
// =====================================================================
template<int ACT, int BM, int BN>
__global__ __launch_bounds__(256)
void bgemm_kernel(const bf16* __restrict__ A, const bf16* __restrict__ W,
                  const float* __restrict__ bias, const float* __restrict__ addv,
                  float* __restrict__ Cf, bf16* __restrict__ Cb,
                  int M, int N, int Kd, int lda, int ldw, int ldcf, int ldcb, int ldadd,
                  int bdiv, long sA1, long sA2, long sW1, long sW2,
                  long sCf1, long sCf2, long sCb1, long sCb2, long sBias)
{
    constexpr int RM = BM / 32;
    constexpr int RN = BN / 32;
    const int z = blockIdx.z;
    const int i1 = z / bdiv, i2 = z % bdiv;
    A += i1 * sA1 + i2 * sA2;
    W += i1 * sW1 + i2 * sW2;
    if (bias) bias += i1 * sBias;

    const int bm = blockIdx.y * BM;
    const int bn = blockIdx.x * BN;
    const int tid = threadIdx.x;
    const int lane = tid & 63;
    const int wid = tid >> 6;
    const int wr = wid >> 1, wc = wid & 1;

    __shared__ bf16 As[BM * 32];
    __shared__ bf16 Bs[BN * 32];

    f32x4 acc[RM][RN] = {};

    const int r_in = lane >> 2;
    const int kb   = (lane & 3) * 8;
    const int hi   = lane >> 4;
    const int rc   = lane & 15;

    for (int k0 = 0; k0 < Kd; k0 += 32) {
#pragma unroll
        for (int iss = 0; iss < BM / 64; iss++) {
            const int row = wid * (BM / 4) + iss * 16 + r_in;
            int gm = bm + row; if (gm >= M) gm = M - 1;
            const bf16* ga = A + (long)gm * lda + k0 + kb;
            GLL16(ga, As + (wid * (BM / 4) + iss * 16) * 32);
        }
#pragma unroll
        for (int iss = 0; iss < BN / 64; iss++) {
            const int row = wid * (BN / 4) + iss * 16 + r_in;
            int gn = bn + row; if (gn >= N) gn = N - 1;
            const bf16* gb = W + (long)gn * ldw + k0 + kb;
            GLL16(gb, Bs + (wid * (BN / 4) + iss * 16) * 32);
        }
        asm volatile("s_waitcnt vmcnt(0)" ::: "memory");
        __syncthreads();

        short8x af[RM], bfv[RN];
#pragma unroll
        for (int i = 0; i < RM; i++)
            af[i] = *(const short8x*)(As + (wr * (BM / 2) + i * 16 + rc) * 32 + hi * 8);
#pragma unroll
        for (int j = 0; j < RN; j++)
            bfv[j] = *(const short8x*)(Bs + (wc * (BN / 2) + j * 16 + rc) * 32 + hi * 8);
#pragma unroll
        for (int i = 0; i < RM; i++)
#pragma unroll
            for (int j = 0; j < RN; j++)
                acc[i][j] = __builtin_amdgcn_mfma_f32_16x16x32_bf16(af[i], bfv[j], acc[i][j], 0, 0, 0);
        __syncthreads();
    }

    const long cfo = i1 * sCf1 + i2 * sCf2;
    const long cbo = i1 * sCb1 + i2 * sCb2;
#pragma unroll
    for (int i = 0; i < RM; i++) {
#pragma unroll
        for (int r = 0; r < 4; r++) {
            const int gm = bm + wr * (BM / 2) + i * 16 + hi * 4 + r;
            if (gm >= M) continue;
#pragma unroll
            for (int j = 0; j < RN; j++) {
                const int gn = bn + wc * (BN / 2) + j * 16 + rc;
                if (gn >= N) continue;
                float v = acc[i][j][r];
                if (bias) v += bias[gn];
                if (ACT == 1) v = (v > 20.f) ? v : log1pf(__expf(v));
                if (addv) v += addv[cfo + (long)gm * ldadd + gn];
                if (Cf) Cf[cfo + (long)gm * ldcf + gn] = v;
                if (Cb) Cb[cbo + (long)gm * ldcb + gn] = __float2bfloat16(v);
            }
        }
    }
}

static inline void bgemm(int ACT, int BM, int BN, const bf16* A, const bf16* W, const float* bias,
                         const float* addv, float* Cf, bf16* Cb,
                         int M, int N, int Kd, int lda, int ldw, int ldcf, int ldcb, int ldadd,
                         int nz, int bdiv, long sA1, long sA2, long sW1, long sW2,
                         long sCf1, long sCf2, long sCb1, long sCb2, long sBias, hipStream_t s)
{
    dim3 g((N + BN - 1) / BN, (M + BM - 1) / BM, nz), b(256);
#define BG_ARGS A, W, bias, addv, Cf, Cb, M, N, Kd, lda, ldw, ldcf, ldcb, ldadd, \
                bdiv, sA1, sA2, sW1, sW2, sCf1, sCf2, sCb1, sCb2, sBias
    if (BM == 128) {
        if (ACT == 1) bgemm_kernel<1, 128, 128><<<g, b, 0, s>>>(BG_ARGS);
        else          bgemm_kernel<0, 128, 128><<<g, b, 0, s>>>(BG_ARGS);
    } else if (BN == 128) {
        if (ACT == 1) bgemm_kernel<1, 64, 128><<<g, b, 0, s>>>(BG_ARGS);
        else          bgemm_kernel<0, 64, 128><<<g, b, 0, s>>>(BG_ARGS);
    } else {
        bgemm_kernel<0, 64, 64><<<g, b, 0, s>>>(BG_ARGS);
    }
#undef BG_ARGS
}

static inline void bgemm_plain(int ACT, int BM, int BN, const bf16* A, const bf16* W,
                               const float* bias, const float* addv, float* Cf, bf16* Cb,
                               int M, int N, int Kd, int lda, int ldw, int ldcf, int ldcb,
                               int ldadd, hipStream_t s)
{
    bgemm(ACT, BM, BN, A, W, bias, addv, Cf, Cb, M, N, Kd, lda, ldw, ldcf, ldcb, ldadd,
          1, 1, 0, 0, 0, 0, 0, 0, 0, 0, 0, s);
}

// =====================================================================
// Flash cross-attention, KV-split (flash-decoding).  Grid (qt, bh, split).
// Each block: 32 q-rows, KV range [split*256, split*256+256) as 4 tiles
// of 64.  Emits partial O (f32, unnormalized), and (m, l) per row.
//   Qp: [B*L][DM] bf16;  Kp: bufKV [B*LE][2*DM] (K cols 0..511);
//   VT: [B*DM][LE] bf16;  OP: [SPL][B*L][DM] f32;  ML: [SPL][B][H][L] float2.
// =====================================================================
__global__ __launch_bounds__(128)
void flash_split_kernel(const bf16* __restrict__ Qp, const bf16* __restrict__ Kp,
                        const bf16* __restrict__ VTp, float* __restrict__ OP,
                        float2* __restrict__ ML, float scale)
{
    const int qt = blockIdx.x;            // 0..31
    const int bh = blockIdx.y;            // b*H + h
    const int sp = blockIdx.z;            // 0..3
    const int b = bh >> 2, h = bh & 3;
    const int tid = threadIdx.x;
    const int w = tid >> 6;               // 0..1
    const int lane = tid & 63;
    const int rc = lane & 15, hi = lane >> 4;
    const int rlo = rc & 7;

    __shared__ bf16 Ks[64 * 128];
    __shared__ bf16 Vs[128 * 64];
    __shared__ bf16 Ps[32 * 64];

    // ---- stage Q tile (32x128) into Ks, hoist fragments, then free Ks ----
    {
        const bf16* qb = Qp + ((long)(b * cL + qt * 32)) * cDM + h * cHD;
#pragma unroll
        for (int c = 0; c < 4; c++) {
            const int row = w * 16 + c * 4 + (lane >> 4);
            const int gc = (lane & 15) ^ (row & 7);
            GLL16(qb + (long)row * cDM + gc * 8, Ks + (w * 16 + c * 4) * 128);
        }
    }
    asm volatile("s_waitcnt vmcnt(0)" ::: "memory");
    __syncthreads();
    short8x aq[4];
#pragma unroll
    for (int kk = 0; kk < 4; kk++) {
        const int sc = (kk * 4 + hi) ^ rlo;
        aq[kk] = *(const short8x*)(Ks + (w * 16 + rc) * 128 + sc * 8);
    }
    __syncthreads();   // Ks free for K tiles

    float m_r[4], l_r[4];
#pragma unroll
    for (int r = 0; r < 4; r++) { m_r[r] = -1e30f; l_r[r] = 0.f; }
    f32x4 oacc[8] = {};

    const bf16* kb0 = Kp + ((long)(b * cLE)) * (2 * cDM) + h * cHD;
    const bf16* vb0 = VTp + ((long)(b * cDM + h * cHD)) * cLE;

    for (int t = 0; t < 4; t++) {
        const int kt = sp * 4 + t;
        __syncthreads();
#pragma unroll
        for (int c = 0; c < 8; c++) {
            const int row = w * 32 + c * 4 + (lane >> 4);
            const int gc = (lane & 15) ^ (row & 7);
            GLL16(kb0 + ((long)(kt * 64 + row)) * (2 * cDM) + gc * 8,
                  Ks + (w * 32 + c * 4) * 128);
        }
#pragma unroll
        for (int c = 0; c < 8; c++) {
            const int row = w * 64 + c * 8 + (lane >> 3);
            const int gc = (lane & 7) ^ (row & 7);
            GLL16(vb0 + (long)row * cLE + kt * 64 + gc * 8,
                  Vs + (w * 64 + c * 8) * 64);
        }
        asm volatile("s_waitcnt vmcnt(0)" ::: "memory");
        __syncthreads();

        f32x4 s[4] = {};
#pragma unroll
        for (int kk = 0; kk < 4; kk++) {
            const int sc = (kk * 4 + hi) ^ rlo;
#pragma unroll
            for (int j = 0; j < 4; j++) {
                short8x bk = *(const short8x*)(Ks + (j * 16 + rc) * 128 + sc * 8);
                s[j] = __builtin_amdgcn_mfma_f32_16x16x32_bf16(aq[kk], bk, s[j], 0, 0, 0);
            }
        }

        float p[4][4];
        float esc[4];
#pragma unroll
        for (int r = 0; r < 4; r++) {
            const float v0 = s[0][r] * scale, v1 = s[1][r] * scale;
            const float v2 = s[2][r] * scale, v3 = s[3][r] * scale;
            float mx = fmaxf(fmaxf(v0, v1), fmaxf(v2, v3));
            mx = fmaxf(mx, __shfl_xor(mx, 1));
            mx = fmaxf(mx, __shfl_xor(mx, 2));
            mx = fmaxf(mx, __shfl_xor(mx, 4));
            mx = fmaxf(mx, __shfl_xor(mx, 8));
            const float mn = fmaxf(m_r[r], mx);
            p[0][r] = __expf(v0 - mn);
            p[1][r] = __expf(v1 - mn);
            p[2][r] = __expf(v2 - mn);
            p[3][r] = __expf(v3 - mn);
            float rs = (p[0][r] + p[1][r]) + (p[2][r] + p[3][r]);
            rs += __shfl_xor(rs, 1);
            rs += __shfl_xor(rs, 2);
            rs += __shfl_xor(rs, 4);
            rs += __shfl_xor(rs, 8);
            esc[r] = __expf(m_r[r] - mn);
            l_r[r] = l_r[r] * esc[r] + rs;
            m_r[r] = mn;
        }
#pragma unroll
        for (int j2 = 0; j2 < 8; j2++)
#pragma unroll
            for (int r = 0; r < 4; r++)
                oacc[j2][r] *= esc[r];
#pragma unroll
        for (int j = 0; j < 4; j++)
#pragma unroll
            for (int r = 0; r < 4; r++) {
                const int q = w * 16 + hi * 4 + r;
                const int cp = (j * 2 + (rc >> 3)) ^ (q & 7);
                Ps[q * 64 + cp * 8 + (rc & 7)] = __float2bfloat16(p[j][r]);
            }
        __syncthreads();
#pragma unroll
        for (int ks = 0; ks < 2; ks++) {
            const int sc = (ks * 4 + hi) ^ rlo;
            short8x ap = *(const short8x*)(Ps + (w * 16 + rc) * 64 + sc * 8);
#pragma unroll
            for (int j2 = 0; j2 < 8; j2++) {
                short8x bv = *(const short8x*)(Vs + (j2 * 16 + rc) * 64 + sc * 8);
                oacc[j2] = __builtin_amdgcn_mfma_f32_16x16x32_bf16(ap, bv, oacc[j2], 0, 0, 0);
            }
        }
    }

    // partial outputs (unnormalized) + (m,l)
    float* ob = OP + (((long)sp * (cB * cL) + b * cL + qt * 32)) * cDM + h * cHD;
#pragma unroll
    for (int j2 = 0; j2 < 8; j2++)
#pragma unroll
        for (int r = 0; r < 4; r++)
            ob[(long)(w * 16 + hi * 4 + r) * cDM + j2 * 16 + rc] = oacc[j2][r];
    if (rc == 0) {
#pragma unroll
        for (int r = 0; r < 4; r++) {
            const int row = qt * 32 + w * 16 + hi * 4 + r;
            ML[(((long)sp * cB + b) * cH + h) * cL + row] = make_float2(m_r[r], l_r[r]);
        }
    }
}

// =====================================================================
// Combine flash splits:  O = (sum_s e^{m_s-M} O_s) / (sum_s e^{m_s-M} l_s)
// One block per global row (2048); 256 threads, 2 cols each.
// =====================================================================
__global__ __launch_bounds__(256)
void flash_combine_kernel(const float* __restrict__ OP, const float2* __restrict__ ML,
                          bf16* __restrict__ Op)
{
    const int row = blockIdx.x;        // 0..2047
    const int b = row >> 10, lr = row & 1023;
    const int t = threadIdx.x;
    __shared__ float ms[cSPL][cH], ls[cSPL][cH];
    __shared__ float wgt[cSPL][cH], linv[cH];
    if (t < cSPL * cH) {
        const int s = t >> 2, h = t & 3;
        float2 v = ML[(((long)s * cB + b) * cH + h) * cL + lr];
        ms[s][h] = v.x; ls[s][h] = v.y;
    }
    __syncthreads();
    if (t < cH) {
        const int h = t;
        float M = fmaxf(fmaxf(ms[0][h], ms[1][h]), fmaxf(ms[2][h], ms[3][h]));
        float L = 0.f;
#pragma unroll
        for (int s = 0; s < cSPL; s++) {
            const float e = __expf(ms[s][h] - M);
            wgt[s][h] = e;
            L += e * ls[s][h];
        }
        linv[h] = 1.f / L;
    }
    __syncthreads();
#pragma unroll
    for (int c0 = 0; c0 < 2; c0++) {
        const int col = t + c0 * 256;
        const int h = col >> 7;
        float o = 0.f;
#pragma unroll
        for (int s = 0; s < cSPL; s++)
            o += wgt[s][h] * OP[((long)s * (cB * cL) + row) * cDM + col];
        Op[(long)row * cDM + col] = __float2bfloat16(o * linv[h]);
    }
}

// =====================================================================
// split-K partial reduce:  out = sum_s parts[s]  (f32 + bf16 outputs)
// =====================================================================
__global__ void splitk_reduce_kernel(const float* __restrict__ parts, float* __restrict__ outf,
                                     bf16* __restrict__ outb, int n4, int sliceN4, int S)
{
    const int i = blockIdx.x * 256 + threadIdx.x;
    if (i >= n4) return;
    float4 a = ((const float4*)parts)[i];
    for (int s2 = 1; s2 < S; s2++) {
        float4 b2 = ((const float4*)parts)[i + (long)s2 * sliceN4];
        a.x += b2.x; a.y += b2.y; a.z += b2.z; a.w += b2.w;
    }
    ((float4*)outf)[i] = a;
    bf16 b0 = __float2bfloat16(a.x), b1 = __float2bfloat16(a.y);
    bf16 b2 = __float2bfloat16(a.z), b3 = __float2bfloat16(a.w);
    short4 pk = { *(short*)&b0, *(short*)&b1, *(short*)&b2, *(short*)&b3 };
    ((short4*)outb)[i] = pk;
}

// =====================================================================
// One-shot fused f32->bf16 conversion of all weight tensors + enc.
// =====================================================================
__global__ void cvt_all_kernel(
    const float* __restrict__ s0, bf16* __restrict__ d0,   // enc
    const float* __restrict__ s1, bf16* __restrict__ d1,   // m_in_w
    const float* __restrict__ s2, bf16* __restrict__ d2,   // m_xproj
    const float* __restrict__ s3, bf16* __restrict__ d3,   // m_dt_w
    const float* __restrict__ s4, bf16* __restrict__ d4,   // m_out_w
    const float* __restrict__ s5, bf16* __restrict__ d5,   // a_in_w
    const float* __restrict__ s6, bf16* __restrict__ d6,   // a_out_w
    const float* __restrict__ s7, bf16* __restrict__ d7)   // W_out
{
    constexpr long E0 = 1048576, E1 = 4194304, E2 = 262144, E3 = 131072;
    constexpr long E4 = 2097152, E5 = 3145728, E6 = 1048576, E7 = 40960;
    constexpr long C0 = E0, C1 = C0 + E1, C2 = C1 + E2, C3 = C2 + E3;
    constexpr long C4 = C3 + E4, C5 = C4 + E5, C6 = C5 + E6, C7 = C6 + E7;
    long i = ((long)blockIdx.x * 256 + threadIdx.x) * 4;
    if (i >= C7) return;
    const float* s; bf16* d;
    if      (i < C0) { s = s0; d = d0; }
    else if (i < C1) { s = s1; d = d1; i -= C0; }
    else if (i < C2) { s = s2; d = d2; i -= C1; }
    else if (i < C3) { s = s3; d = d3; i -= C2; }
    else if (i < C4) { s = s4; d = d4; i -= C3; }
    else if (i < C5) { s = s5; d = d5; i -= C4; }
    else if (i < C6) { s = s6; d = d6; i -= C5; }
    else             { s = s7; d = d7; i -= C6; }
    float4 v = *(const float4*)(s + i);
    d[i]     = __float2bfloat16(v.x);
    d[i + 1] = __float2bfloat16(v.y);
    d[i + 2] = __float2bfloat16(v.z);
    d[i + 3] = __float2bfloat16(v.w);
}

// f32 (rows x kin) -> bf16 (rows x kout), zero-padded beyond kin
__global__ void cvt_pad_kernel(const float* __restrict__ in, bf16* __restrict__ out,
                               int rows, int kin, int kout)
{
    const int idx = blockIdx.x * 256 + threadIdx.x;
    if (idx >= rows * kout) return;
    const int r = idx / kout, k = idx - r * kout;
    out[idx] = __float2bfloat16(k < kin ? in[(long)r * kin + k] : 0.f);
}

// =====================================================================
// bf16 transpose, batched over (layer, batch):  z = lay*cB + b.
// =====================================================================
__global__ void transpose_bf16_kernel(const bf16* __restrict__ in, bf16* __restrict__ out,
                                      int ldin, int col0, long inLS, long outLS)
{
    __shared__ bf16 t[32][33];
    const int z = blockIdx.z;
    const int lay = z >> 1, b = z & 1;
    in  += (long)lay * inLS;
    out += (long)lay * outLS;
    const int le0 = blockIdx.x * 32, d0 = blockIdx.y * 32;
    const int tid = threadIdx.x;
    const int c = tid & 31, r = tid >> 5;
    for (int i = r; i < 32; i += 8)
        t[i][c] = in[((long)b * cLE + le0 + i) * ldin + col0 + d0 + c];
    __syncthreads();
    for (int i = r; i < 32; i += 8)
        out[((long)b * cDM + d0 + i) * cLE + le0 + c] = t[c][i];
}

// =====================================================================
// RMSNorm per row (optional f32 and bf16 outputs) — layer-0 entry
// =====================================================================
__global__ void rmsnorm_kernel(const float* __restrict__ x, const float* __restrict__ w,
                               float* __restrict__ outf, bf16* __restrict__ outb, int Dm)
{
    const int row = blockIdx.x;
    const float* xr = x + (long)row * Dm;
    float s = 0.f;
    for (int i = threadIdx.x; i < Dm; i += 256) { float v = xr[i]; s += v * v; }
    __shared__ float red[5];
    const int lane = threadIdx.x & 63, wv = threadIdx.x >> 6;
#pragma unroll
    for (int off = 1; off < 64; off <<= 1) s += __shfl_xor(s, off);
    if (lane == 0) red[wv] = s;
    __syncthreads();
    if (threadIdx.x == 0) {
        float t = red[0] + red[1] + red[2] + red[3];
        red[4] = rsqrtf(t / Dm + 1e-5f);
    }
    __syncthreads();
    const float scale = red[4];
    for (int i = threadIdx.x; i < Dm; i += 256) {
        float v = xr[i] * scale * w[i];
        if (outf) outf[(long)row * Dm + i] = v;
        if (outb) outb[(long)row * Dm + i] = __float2bfloat16(v);
    }
}

// =====================================================================
// LayerNorm per row (Dm=512, 2 elems/thread) -> f32 + bf16 outputs,
// PLUS fused RMSNorm of the LN output with rms_w -> rms_out (bf16).
// =====================================================================
__global__ void layernorm_kernel(const float* __restrict__ x, const float* __restrict__ w,
                                 const float* __restrict__ b, float* __restrict__ outf,
                                 bf16* __restrict__ outb,
                                 const float* __restrict__ rms_w, bf16* __restrict__ rms_out)
{
    const int row = blockIdx.x;
    const float* xr = x + (long)row * 512;
    const int t = threadIdx.x;
    const int i0 = t, i1 = t + 256;
    float x0 = xr[i0], x1 = xr[i1];
    float s = x0 + x1, sq = x0 * x0 + x1 * x1;
    __shared__ float red[8];
    __shared__ float mv[2];
    const int lane = t & 63, wv = t >> 6;
#pragma unroll
    for (int off = 1; off < 64; off <<= 1) { s += __shfl_xor(s, off); sq += __shfl_xor(sq, off); }
    if (lane == 0) { red[wv] = s; red[4 + wv] = sq; }
    __syncthreads();
    if (t == 0) {
        float ts = red[0] + red[1] + red[2] + red[3];
        float tq = red[4] + red[5] + red[6] + red[7];
        float m = ts / 512.f;
        float var = tq / 512.f - m * m;
        mv[0] = m;
        mv[1] = rsqrtf(var + 1e-5f);
    }
    __syncthreads();
    const float m = mv[0], rs = mv[1];
    const float v0 = (x0 - m) * rs * w[i0] + b[i0];
    const float v1 = (x1 - m) * rs * w[i1] + b[i1];
    outf[(long)row * 512 + i0] = v0;
    outf[(long)row * 512 + i1] = v1;
    outb[(long)row * 512 + i0] = __float2bfloat16(v0);
    outb[(long)row * 512 + i1] = __float2bfloat16(v1);
    float s2 = v0 * v0 + v1 * v1;
#pragma unroll
    for (int off = 1; off < 64; off <<= 1) s2 += __shfl_xor(s2, off);
    if (lane == 0) red[wv] = s2;
    __syncthreads();
    if (t == 0) mv[0] = rsqrtf((red[0] + red[1] + red[2] + red[3]) / 512.f + 1e-5f);
    __syncthreads();
    const float rsc = mv[0];
    rms_out[(long)row * 512 + i0] = __float2bfloat16(v0 * rsc * rms_w[i0]);
    rms_out[(long)row * 512 + i1] = __float2bfloat16(v1 * rsc * rms_w[i1]);
}

// =====================================================================
// Causal depthwise conv (K=4) + bias + SiLU -> xm f32 + bf16
// =====================================================================
__global__ void conv_silu_kernel(const float* __restrict__ xr, const float* __restrict__ w,
                                 const float* __restrict__ bias, float* __restrict__ xm,
                                 bf16* __restrict__ xmb)
{
    const int idx = blockIdx.x * 256 + threadIdx.x;
    if (idx >= cB * cL * cDI) return;
    const int d = idx & (cDI - 1);
    const int l = (idx >> 10) & (cL - 1);
    const int b = idx >> 20;
    float s = bias[d];
#pragma unroll
    for (int j = 0; j < cKC; j++) {
        const int ls = l + j - (cKC - 1);
        if (ls >= 0) s += w[d * cKC + j] * xr[((long)(b * cL + ls)) * (2 * cDI) + d];
    }
    s = s / (1.f + __expf(-s));
    xm[(long)idx] = s;
    xmb[(long)idx] = __float2bfloat16(s);
}

// =====================================================================
// Chunk-parallel selective scan, 4 states (n) per thread, NCH=64 chunks.
// =====================================================================
__global__ void scan_phase1(const float* __restrict__ xm, const float* __restrict__ delta,
                            const float* __restrict__ xdbl, const float* __restrict__ Alog,
                            float* __restrict__ aprod_out, float* __restrict__ send_out)
{
    const int idx4 = blockIdx.x * 256 + threadIdx.x;   // cB*cNCH*cDI*4
    const int ng = idx4 & 3;
    const int d  = (idx4 >> 2) & (cDI - 1);
    const int ch = (idx4 >> 12) & (cNCH - 1);
    const int b  = idx4 >> 18;
    const float4 Al = *(const float4*)(Alog + d * cDS + 4 * ng);
    const float A0 = -__expf(Al.x), A1 = -__expf(Al.y), A2 = -__expf(Al.z), A3 = -__expf(Al.w);
    float s0 = 0.f, s1 = 0.f, s2 = 0.f, s3 = 0.f;
    float p0 = 1.f, p1 = 1.f, p2 = 1.f, p3 = 1.f;
    const int l0 = ch * cCHL;
    const float* dp = delta + (long)(b * cL + l0) * cDI + d;
    const float* up = xm    + (long)(b * cL + l0) * cDI + d;
    const float* xb = xdbl  + (long)(b * cL + l0) * 64 + cDTR + 4 * ng;
#pragma unroll
    for (int t = 0; t < cCHL; t++) {
        const float dl = dp[(long)t * cDI];
        const float du = dl * up[(long)t * cDI];
        const float4 Bv = *(const float4*)(xb + (long)t * 64);
        const float a0 = __expf(dl * A0), a1 = __expf(dl * A1);
        const float a2 = __expf(dl * A2), a3 = __expf(dl * A3);
        s0 = a0 * s0 + du * Bv.x; p0 *= a0;
        s1 = a1 * s1 + du * Bv.y; p1 *= a1;
        s2 = a2 * s2 + du * Bv.z; p2 *= a2;
        s3 = a3 * s3 + du * Bv.w; p3 *= a3;
    }
    const long base4 = (((long)(b * cNCH + ch) * cDI + d) * cDS) + 4 * ng;
    float4 pv = { p0, p1, p2, p3 };
    float4 sv = { s0, s1, s2, s3 };
    *(float4*)(aprod_out + base4) = pv;
    *(float4*)(send_out + base4)  = sv;
}

__global__ void scan_phase2(const float* __restrict__ aprod, const float* __restrict__ send,
                            float* __restrict__ sinit)
{
    const int j = blockIdx.x * 64 + threadIdx.x;    // cB*cDI*cDS, 64-thr blocks
    const int n = j & (cDS - 1);
    const int d = (j >> 4) & (cDI - 1);
    const int b = j >> 14;
    float s = 0.f;
#pragma unroll
    for (int c = 0; c < cNCH; c++) {
        const long off = (((long)(b * cNCH + c) * cDI + d) * cDS) + n;
        sinit[off] = s;
        s = aprod[off] * s + send[off];
    }
}

__global__ void scan_phase3(const float* __restrict__ xm, const float* __restrict__ delta,
                            const float* __restrict__ xdbl, const float* __restrict__ Alog,
                            const float* __restrict__ Dv, const float* __restrict__ xr,
                            const float* __restrict__ sinit, bf16* __restrict__ y)
{
    const int idx4 = blockIdx.x * 256 + threadIdx.x;   // cB*cNCH*cDI*4
    const int ng = idx4 & 3;
    const int d  = (idx4 >> 2) & (cDI - 1);
    const int ch = (idx4 >> 12) & (cNCH - 1);
    const int b  = idx4 >> 18;
    const float4 Al = *(const float4*)(Alog + d * cDS + 4 * ng);
    const float A0 = -__expf(Al.x), A1 = -__expf(Al.y), A2 = -__expf(Al.z), A3 = -__expf(Al.w);
    const float Dval = Dv[d];
    const long base4 = (((long)(b * cNCH + ch) * cDI + d) * cDS) + 4 * ng;
    float4 st = *(const float4*)(sinit + base4);
    float s0 = st.x, s1 = st.y, s2 = st.z, s3 = st.w;
    const int l0 = ch * cCHL;
    const float* dp = delta + (long)(b * cL + l0) * cDI + d;
    const float* up = xm    + (long)(b * cL + l0) * cDI + d;
    const float* xb = xdbl  + (long)(b * cL + l0) * 64 + cDTR + 4 * ng;
    const float* xc = xb + cDS;
    const float* rp = xr + (long)(b * cL + l0) * (2 * cDI) + cDI + d;
    bf16* yp = y + (long)(b * cL + l0) * cDI + d;
#pragma unroll
    for (int t = 0; t < cCHL; t++) {
        const float dl = dp[(long)t * cDI];
        const float u  = up[(long)t * cDI];
        const float du = dl * u;
        const float4 Bv = *(const float4*)(xb + (long)t * 64);
        const float4 Cv = *(const float4*)(xc + (long)t * 64);
        const float a0 = __expf(dl * A0), a1 = __expf(dl * A1);
        const float a2 = __expf(dl * A2), a3 = __expf(dl * A3);
        s0 = a0 * s0 + du * Bv.x;
        s1 = a1 * s1 + du * Bv.y;
        s2 = a2 * s2 + du * Bv.z;
        s3 = a3 * s3 + du * Bv.w;
        float c = s0 * Cv.x;
        c = fmaf(s1, Cv.y, c);
        c = fmaf(s2, Cv.z, c);
        c = fmaf(s3, Cv.w, c);
        c += __shfl_xor(c, 1);
        c += __shfl_xor(c, 2);
        if (ng == 0) {
            const float res = rp[(long)t * 2 * cDI];
            const float sig = 1.f / (1.f + __expf(-res));
            yp[(long)t * cDI] = __float2bfloat16((c + u * Dval) * (res * sig));
        }
    }
}

// =====================================================================
extern "C" void kernel_launch(void* const* d_in, const int* in_sizes, int n_in,
                              void* d_out, int out_size, void* d_ws, size_t ws_size,
                              hipStream_t stream)
{
    const float* x       = (const float*)d_in[0];
    const float* enc     = (const float*)d_in[1];
    const float* W_in    = (const float*)d_in[2];
    const float* b_in    = (const float*)d_in[3];
    const float* m_norm_w= (const float*)d_in[4];
    const float* m_in_w  = (const float*)d_in[5];
    const float* m_conv_w= (const float*)d_in[6];
    const float* m_conv_b= (const float*)d_in[7];
    const float* m_xproj = (const float*)d_in[8];
    const float* m_dt_w  = (const float*)d_in[9];
    const float* m_dt_b  = (const float*)d_in[10];
    const float* m_Alog  = (const float*)d_in[11];
    const float* m_D     = (const float*)d_in[12];
    const float* m_out_w = (const float*)d_in[13];
    const float* a_in_w  = (const float*)d_in[14];
    const float* a_in_b  = (const float*)d_in[15];
    const float* a_out_w = (const float*)d_in[16];
    const float* a_out_b = (const float*)d_in[17];
    const float* a_ln_w  = (const float*)d_in[18];
    const float* a_ln_b  = (const float*)d_in[19];
    const float* normf_w = (const float*)d_in[20];
    const float* W_out   = (const float*)d_in[21];
    float* out = (float*)d_out;

    float* ws = (float*)d_ws;
    long off = 0;
    auto allocf = [&](long n) { float* p = ws + off; off += n; return p; };

    const long M1 = 1 << 20;
    float* bufH    = allocf(M1);
    float* bufPre  = allocf(M1);         // also xproj split-K partials
    float* bufXR   = allocf(4 * M1);
    float* bufXM   = allocf(2 * M1);
    float* bufDelta= allocf(2 * M1);
    float* bufXDBL = allocf(M1 / 8);
    bf16* bufU    = (bf16*)allocf(M1 / 2);      // 2048x512 bf16 (rms output)
    bf16* bufHb   = (bf16*)allocf(M1 / 2);
    bf16* bufXMb  = (bf16*)allocf(M1);          // 2048x1024 bf16
    bf16* bufXDBLb= (bf16*)allocf(M1 / 16);
    bf16* bufY    = (bf16*)allocf(M1);          // 2048x1024 bf16
    bf16* bufQ    = (bf16*)allocf(M1 / 2);
    bf16* bufO    = (bf16*)allocf(M1 / 2);
    bf16* encb    = (bf16*)allocf(M1 / 2);
    bf16* w_in_b  = (bf16*)allocf(2 * M1);
    bf16* w_xp_b  = (bf16*)allocf(M1 / 8);
    bf16* w_dt_b  = (bf16*)allocf(M1 / 16);
    bf16* w_out_b = (bf16*)allocf(M1);
    bf16* w_ain_b = (bf16*)allocf(3 * M1 / 2);
    bf16* w_aout_b= (bf16*)allocf(M1 / 2);
    bf16* x_pad   = (bf16*)allocf(2048L * 96 / 2);
    bf16* w_inp_b = (bf16*)allocf(512L * 96 / 2);
    bf16* w_outf_b= (bf16*)allocf(80L * 512 / 2);
    float* bufAP  = allocf(2 * M1);
    float* bufSE  = allocf(2 * M1);
    float* bufSI  = allocf(2 * M1);
    bf16* bufKV4  = (bf16*)allocf(4 * M1);      // 4 layers x 2M bf16
    bf16* bufVT4  = (bf16*)allocf(2 * M1);      // 4 layers x 1M bf16
    float* bufOP  = allocf(4 * M1);             // flash partials [4][2048][512] f32
    float2* bufML = (float2*)allocf(M1 / 16);   // [4][2][4][1024] float2 = 64K f32

    const int Mrows = cB * cL;   // 2048
    const long SUMSZ4 = (long)cB * cNCH * cDI * 4;
    const long kvLS = (long)Mrows * 2 * cDM;
    const long vtLS = (long)cB * cDM * cLE;

    // ---- one-time conversions ----
    cvt_all_kernel<<<11688, 256, 0, stream>>>(
        enc, encb, m_in_w, w_in_b, m_xproj, w_xp_b, m_dt_w, w_dt_b,
        m_out_w, w_out_b, a_in_w, w_ain_b, a_out_w, w_aout_b, W_out, w_outf_b);
    cvt_pad_kernel<<<(Mrows * 96 + 255) / 256, 256, 0, stream>>>(x, x_pad, Mrows, cNM, 96);
    cvt_pad_kernel<<<(cDM * 96 + 255) / 256, 256, 0, stream>>>(W_in, w_inp_b, cDM, cNM, 96);

    // ---- all-layer K|V projection + V^T ----
    bgemm(0, 64, 128, encb, w_ain_b + (long)cDM * cDM, a_in_b + cDM, nullptr, nullptr, bufKV4,
          Mrows, 2 * cDM, cDM, cDM, cDM, 0, 2 * cDM, 0,
          cLAYERS, 1,
          0, 0,
          (long)3 * cDM * cDM, 0,
          0, 0, kvLS, 0,
          (long)3 * cDM,
          stream);
    {
        dim3 g(cLE / 32, cDM / 32, cLAYERS * cB);
        transpose_bf16_kernel<<<g, 256, 0, stream>>>(bufKV4, bufVT4, 2 * cDM, cDM, kvLS, vtLS);
    }

    // h = x @ W_in.T + b_in ; layer-0 rmsnorm -> bufU
    bgemm_plain(0, 64, 64, x_pad, w_inp_b, b_in, nullptr, bufH, nullptr,
                Mrows, cDM, 96, 96, 96, cDM, 0, 0, stream);
    rmsnorm_kernel<<<Mrows, 256, 0, stream>>>(bufH, m_norm_w, nullptr, bufU, cDM);

    for (int i = 0; i < cLAYERS; i++) {
        const bf16*  in_w   = w_in_b   + (long)i * 2 * cDI * cDM;
        const float* conv_w = m_conv_w + (long)i * cDI * cKC;
        const float* conv_b = m_conv_b + (long)i * cDI;
        const bf16*  xproj  = w_xp_b   + (long)i * 64 * cDI;
        const bf16*  dt_w   = w_dt_b   + (long)i * cDI * cDTR;
        const float* dt_b   = m_dt_b   + (long)i * cDI;
        const float* Alog   = m_Alog   + (long)i * cDI * cDS;
        const float* Dv     = m_D      + (long)i * cDI;
        const bf16*  out_w  = w_out_b  + (long)i * cDM * cDI;
        const bf16*  ain_w  = w_ain_b  + (long)i * 3 * cDM * cDM;
        const float* ain_b  = a_in_b   + (long)i * 3 * cDM;
        const bf16*  aout_w = w_aout_b + (long)i * cDM * cDM;
        const float* aout_b = a_out_b  + (long)i * cDM;
        const float* ln_w   = a_ln_w   + (long)i * cDM;
        const float* ln_b   = a_ln_b   + (long)i * cDM;
        const bf16*  kv_l   = bufKV4 + (long)i * kvLS;
        const bf16*  vt_l   = bufVT4 + (long)i * vtLS;
        const float* next_rms_w = (i + 1 < cLAYERS) ? (m_norm_w + (long)(i + 1) * cDM) : normf_w;

        // ---- mamba (bufU holds rmsnorm(h) bf16) ----
        bgemm_plain(0, 64, 128, bufU, in_w, nullptr, nullptr, bufXR, nullptr,
                    Mrows, 2 * cDI, cDM, cDM, cDM, 2 * cDI, 0, 0, stream);
        conv_silu_kernel<<<(cB * cL * cDI) / 256, 256, 0, stream>>>(bufXR, conv_w, conv_b, bufXM, bufXMb);
        bgemm(0, 64, 64, bufXMb, xproj, nullptr, nullptr, bufPre, nullptr,
              Mrows, 64, cDI / 8, cDI, cDI, 64, 0, 0,
              8, 1, 128, 0, 128, 0, (long)Mrows * 64, 0, 0, 0, 0, stream);
        splitk_reduce_kernel<<<(Mrows * 64 / 4 + 255) / 256, 256, 0, stream>>>(
            bufPre, bufXDBL, bufXDBLb, Mrows * 64 / 4, Mrows * 64 / 4, 8);
        bgemm_plain(1, 64, 128, bufXDBLb, dt_w, dt_b, nullptr, bufDelta, nullptr,
                    Mrows, cDI, cDTR, 64, cDTR, cDI, 0, 0, stream);
        scan_phase1<<<(int)(SUMSZ4 / 256), 256, 0, stream>>>(bufXM, bufDelta, bufXDBL, Alog, bufAP, bufSE);
        scan_phase2<<<(cB * cDI * cDS) / 64, 64, 0, stream>>>(bufAP, bufSE, bufSI);
        scan_phase3<<<(int)(SUMSZ4 / 256), 256, 0, stream>>>(bufXM, bufDelta, bufXDBL, Alog, Dv, bufXR, bufSI, bufY);
        bgemm_plain(0, 64, 64, bufY, out_w, nullptr, bufH, bufH, bufHb,
                    Mrows, cDM, cDI, cDI, cDI, cDM, cDM, cDM, stream);

        // ---- cross attention: Q gemm -> split flash -> combine ----
        bgemm_plain(0, 64, 64, bufHb, ain_w, ain_b, nullptr, nullptr, bufQ,
                    Mrows, cDM, cDM, cDM, cDM, 0, cDM, 0, stream);
        {
            dim3 g(cL / 32, cB * cH, cSPL);
            flash_split_kernel<<<g, 128, 0, stream>>>(bufQ, kv_l, vt_l, bufOP, bufML,
                                                      0.08838834764831845f);
        }
        flash_combine_kernel<<<Mrows, 256, 0, stream>>>(bufOP, bufML, bufO);
        // pre = o @ aout_w.T + aout_b + h ; h = LN(pre) (+ fused next-RMS -> bufU)
        bgemm_plain(0, 64, 64, bufO, aout_w, aout_b, bufH, bufPre, nullptr,
                    Mrows, cDM, cDM, cDM, cDM, cDM, 0, cDM, stream);
        layernorm_kernel<<<Mrows, 256, 0, stream>>>(bufPre, ln_w, ln_b, bufH, bufHb,
                                                    next_rms_w, bufU);
    }

    // final: out = bufU(= rms(h, normf_w)) @ W_out.T
    bgemm_plain(0, 64, 64, bufU, w_outf_b, nullptr, nullptr, out, nullptr,
                Mrows, cNM, cDM, cDM, cDM, cNM, 0, 0, stream);
}